// Round 1
// baseline (1174.017 us; speedup 1.0000x reference)
//
#include <hip/hip_runtime.h>
#include <hip/hip_bf16.h>
#include <math.h>

// Problem constants
#define L_SEQ   2048
#define DMODEL  1024
#define DINNER  2048
#define DSTATE  16
#define DCONV   4
#define DTRANK  64
#define NXDBL   96   // DT_RANK + 2*D_STATE

// ---------------------------------------------------------------------------
// Generic fp32 tiled GEMM: C[M,N] = A[M,K] @ B[K,N], row-major, M%64==0, K%16==0,
// N arbitrary (bounds-checked on B loads and C stores).
// 64x64 tile, BK=16, 256 threads, 4x4 micro-tile per thread.
// ---------------------------------------------------------------------------
__global__ __launch_bounds__(256) void gemm_f32(
    const float* __restrict__ A, const float* __restrict__ B, float* __restrict__ C,
    int M, int N, int K)
{
    __shared__ float As[16][68];   // [k][m], padded (68*4=272B rows, 16B aligned)
    __shared__ float Bs[16][68];   // [k][n], padded

    const int tid = threadIdx.x;
    const int bm = blockIdx.y * 64;
    const int bn = blockIdx.x * 64;
    const int tx = tid & 15;   // n-group
    const int ty = tid >> 4;   // m-group

    float acc[4][4];
#pragma unroll
    for (int i = 0; i < 4; ++i)
#pragma unroll
        for (int j = 0; j < 4; ++j) acc[i][j] = 0.f;

    const int arow = tid >> 2, akq = tid & 3;       // A tile: 64 rows x 16 k
    const int brow = tid >> 4, bcq = tid & 15;      // B tile: 16 rows x 64 n

    for (int k0 = 0; k0 < K; k0 += 16) {
        // --- load A tile (no bounds: M%64==0, K%16==0)
        {
            const float4 a4 = *(const float4*)(A + (size_t)(bm + arow) * K + k0 + 4 * akq);
            As[4 * akq + 0][arow] = a4.x;
            As[4 * akq + 1][arow] = a4.y;
            As[4 * akq + 2][arow] = a4.z;
            As[4 * akq + 3][arow] = a4.w;
        }
        // --- load B tile (N bounds-checked)
        {
            const int n = bn + 4 * bcq;
            float4 b4;
            if (n + 3 < N) {
                b4 = *(const float4*)(B + (size_t)(k0 + brow) * N + n);
            } else {
                float v0 = (n + 0 < N) ? B[(size_t)(k0 + brow) * N + n + 0] : 0.f;
                float v1 = (n + 1 < N) ? B[(size_t)(k0 + brow) * N + n + 1] : 0.f;
                float v2 = (n + 2 < N) ? B[(size_t)(k0 + brow) * N + n + 2] : 0.f;
                float v3 = (n + 3 < N) ? B[(size_t)(k0 + brow) * N + n + 3] : 0.f;
                b4 = make_float4(v0, v1, v2, v3);
            }
            *(float4*)&Bs[brow][4 * bcq] = b4;
        }
        __syncthreads();
#pragma unroll
        for (int k = 0; k < 16; ++k) {
            float a[4], b[4];
            *(float4*)a = *(const float4*)&As[k][4 * ty];
            *(float4*)b = *(const float4*)&Bs[k][4 * tx];
#pragma unroll
            for (int i = 0; i < 4; ++i)
#pragma unroll
                for (int j = 0; j < 4; ++j) acc[i][j] = fmaf(a[i], b[j], acc[i][j]);
        }
        __syncthreads();
    }

    // --- store
#pragma unroll
    for (int i = 0; i < 4; ++i) {
        const int m = bm + 4 * ty + i;
        const int n = bn + 4 * tx;
        if (n + 3 < N) {
            *(float4*)(C + (size_t)m * N + n) = make_float4(acc[i][0], acc[i][1], acc[i][2], acc[i][3]);
        } else {
#pragma unroll
            for (int j = 0; j < 4; ++j)
                if (n + j < N) C[(size_t)m * N + n + j] = acc[i][j];
        }
    }
}

// ---------------------------------------------------------------------------
// Depthwise causal conv (D_CONV=4) + SiLU.  xc = xz[:, :2048].
// u[t,d] = silu(conv_b[d] + sum_j xc[t-3+j, d] * conv_w[d, j])
// ---------------------------------------------------------------------------
__global__ __launch_bounds__(256) void conv_silu_kernel(
    const float* __restrict__ xz, const float* __restrict__ conv_w,
    const float* __restrict__ conv_b, float* __restrict__ u)
{
    const int d = blockIdx.x * 256 + threadIdx.x;   // 0..2047
    const int t = blockIdx.y;                       // 0..2047
    float acc = conv_b[d];
#pragma unroll
    for (int j = 0; j < DCONV; ++j) {
        const int tt = t - (DCONV - 1) + j;
        if (tt >= 0) acc = fmaf(xz[(size_t)tt * (2 * DINNER) + d], conv_w[d * DCONV + j], acc);
    }
    const float s = acc / (1.f + __expf(-acc));
    u[(size_t)t * DINNER + d] = s;
}

// ---------------------------------------------------------------------------
// delta = softplus(dlt @ W_dt + b_dt);  dlt = x_dbl[:, :64] (row stride 96)
// Block: 256 threads (d), 16 timesteps per block. K=64 via LDS broadcast.
// ---------------------------------------------------------------------------
__global__ __launch_bounds__(256) void delta_kernel(
    const float* __restrict__ x_dbl, const float* __restrict__ W_dt,
    const float* __restrict__ b_dt, float* __restrict__ delta)
{
    __shared__ float dl[16][64];
    const int tid = threadIdx.x;
    const int d = blockIdx.x * 256 + tid;
    const int t0 = blockIdx.y * 16;

    for (int i = tid; i < 16 * 64; i += 256) {
        const int tt = i >> 6, k = i & 63;
        dl[tt][k] = x_dbl[(size_t)(t0 + tt) * NXDBL + k];
    }
    __syncthreads();

    const float bb = b_dt[d];
    float acc[16];
#pragma unroll
    for (int tt = 0; tt < 16; ++tt) acc[tt] = bb;

    for (int k = 0; k < 64; ++k) {
        const float w = W_dt[(size_t)k * DINNER + d];
#pragma unroll
        for (int tt = 0; tt < 16; ++tt) acc[tt] = fmaf(dl[tt][k], w, acc[tt]);
    }
#pragma unroll
    for (int tt = 0; tt < 16; ++tt) {
        const float x = acc[tt];
        const float sp = (x > 20.f) ? x : log1pf(__expf(x));
        delta[(size_t)(t0 + tt) * DINNER + d] = sp;
    }
}

// ---------------------------------------------------------------------------
// Selective scan + gating.  One lane per (d, n); 16 channels per block.
// Chunks of TCH timesteps staged through LDS.  Writes g = y * silu(z).
// ---------------------------------------------------------------------------
#define TCH 64
__global__ __launch_bounds__(256) void scan_kernel(
    const float* __restrict__ xz,      // z at [t*4096 + 2048 + d]
    const float* __restrict__ u,
    const float* __restrict__ delta,
    const float* __restrict__ x_dbl,   // B at [t*96+64+n], C at [t*96+80+n]
    const float* __restrict__ A_log,
    const float* __restrict__ D_param,
    float* __restrict__ g)
{
    __shared__ float sDelta[TCH][16];
    __shared__ float sU[TCH][16];
    __shared__ float sZ[TCH][16];
    __shared__ float sB[TCH][16];
    __shared__ float sC[TCH][16];

    const int tid = threadIdx.x;
    const int lane = tid & 63;
    const int wave = tid >> 6;
    const int c = lane >> 4;   // sub-channel 0..3
    const int n = lane & 15;   // state index
    const int d0 = blockIdx.x * 16;
    const int dd = wave * 4 + c;
    const int d = d0 + dd;

    const float A = -__expf(A_log[d * DSTATE + n]);
    const float Dp = D_param[d];
    float h = 0.f;

    for (int t0 = 0; t0 < L_SEQ; t0 += TCH) {
        __syncthreads();
        for (int i = tid; i < TCH * 16; i += 256) {
            const int tt = i >> 4, q = i & 15;
            const int t = t0 + tt;
            sDelta[tt][q] = delta[(size_t)t * DINNER + d0 + q];
            sU[tt][q]     = u[(size_t)t * DINNER + d0 + q];
            sZ[tt][q]     = xz[(size_t)t * (2 * DINNER) + DINNER + d0 + q];
            sB[tt][q]     = x_dbl[(size_t)t * NXDBL + DTRANK + q];
            sC[tt][q]     = x_dbl[(size_t)t * NXDBL + DTRANK + DSTATE + q];
        }
        __syncthreads();

        for (int tt = 0; tt < TCH; ++tt) {
            const float dt = sDelta[tt][dd];
            const float uu = sU[tt][dd];
            const float Bv = sB[tt][n];
            const float Cv = sC[tt][n];
            h = fmaf(__expf(dt * A), h, dt * uu * Bv);
            float p = h * Cv;
            p += __shfl_xor(p, 1);
            p += __shfl_xor(p, 2);
            p += __shfl_xor(p, 4);
            p += __shfl_xor(p, 8);
            if (n == 0) {
                const float y = p + Dp * uu;
                const float z = sZ[tt][dd];
                const float gate = z / (1.f + __expf(-z));
                g[(size_t)(t0 + tt) * DINNER + d] = y * gate;
            }
        }
    }
}

// ---------------------------------------------------------------------------
extern "C" void kernel_launch(void* const* d_in, const int* in_sizes, int n_in,
                              void* d_out, int out_size, void* d_ws, size_t ws_size,
                              hipStream_t stream)
{
    const float* x      = (const float*)d_in[0];
    const float* W_in   = (const float*)d_in[1];
    const float* conv_w = (const float*)d_in[2];
    const float* conv_b = (const float*)d_in[3];
    const float* W_x    = (const float*)d_in[4];
    const float* W_dt   = (const float*)d_in[5];
    const float* b_dt   = (const float*)d_in[6];
    const float* A_log  = (const float*)d_in[7];
    const float* D_par  = (const float*)d_in[8];
    const float* W_out  = (const float*)d_in[9];
    float* out = (float*)d_out;

    float* ws    = (float*)d_ws;
    float* xz    = ws;                                  // 2048*4096
    float* u     = xz + (size_t)L_SEQ * 2 * DINNER;     // 2048*2048
    float* x_dbl = u + (size_t)L_SEQ * DINNER;          // 2048*96
    float* delta = x_dbl + (size_t)L_SEQ * NXDBL;       // 2048*2048
    float* g     = u;  // alias: scan reads u[t-chunk] into LDS before writing g there,
                       // and each block owns a disjoint d-slice -> safe.

    // 1) xz = x @ W_in   (2048x1024 @ 1024x4096)
    gemm_f32<<<dim3(2 * DINNER / 64, L_SEQ / 64), 256, 0, stream>>>(x, W_in, xz, L_SEQ, 2 * DINNER, DMODEL);
    // 2) u = silu(conv(xc))
    conv_silu_kernel<<<dim3(DINNER / 256, L_SEQ), 256, 0, stream>>>(xz, conv_w, conv_b, u);
    // 3) x_dbl = u @ W_x   (2048x2048 @ 2048x96)
    gemm_f32<<<dim3((NXDBL + 63) / 64, L_SEQ / 64), 256, 0, stream>>>(u, W_x, x_dbl, L_SEQ, NXDBL, DINNER);
    // 4) delta = softplus(dlt @ W_dt + b_dt)
    delta_kernel<<<dim3(DINNER / 256, L_SEQ / 16), 256, 0, stream>>>(x_dbl, W_dt, b_dt, delta);
    // 5) scan + gate -> g
    scan_kernel<<<dim3(DINNER / 16), 256, 0, stream>>>(xz, u, delta, x_dbl, A_log, D_par, g);
    // 6) out = g @ W_out   (2048x2048 @ 2048x1024)
    gemm_f32<<<dim3(DMODEL / 64, L_SEQ / 64), 256, 0, stream>>>(g, W_out, out, L_SEQ, DMODEL, DINNER);
}

// Round 2
// 742.198 us; speedup vs baseline: 1.5818x; 1.5818x over previous
//
#include <hip/hip_runtime.h>
#include <hip/hip_bf16.h>
#include <math.h>

// Problem constants
#define L_SEQ   2048
#define DMODEL  1024
#define DINNER  2048
#define DSTATE  16
#define DCONV   4
#define DTRANK  64
#define NXDBL   96   // DT_RANK + 2*D_STATE

#define CCH 32   // time chunks for parallel scan
#define TC  64   // timesteps per chunk (CCH*TC == L_SEQ)

// ---------------------------------------------------------------------------
// Generic fp32 tiled GEMM: C[M,N] = A[M,K] @ B[K,N], row-major, M%64==0, K%16==0,
// N arbitrary (bounds-checked on B loads and C stores).
// 64x64 tile, BK=16, 256 threads, 4x4 micro-tile per thread.
// ---------------------------------------------------------------------------
__global__ __launch_bounds__(256) void gemm_f32(
    const float* __restrict__ A, const float* __restrict__ B, float* __restrict__ C,
    int M, int N, int K)
{
    __shared__ float As[16][68];   // [k][m], padded
    __shared__ float Bs[16][68];   // [k][n], padded

    const int tid = threadIdx.x;
    const int bm = blockIdx.y * 64;
    const int bn = blockIdx.x * 64;
    const int tx = tid & 15;   // n-group
    const int ty = tid >> 4;   // m-group

    float acc[4][4];
#pragma unroll
    for (int i = 0; i < 4; ++i)
#pragma unroll
        for (int j = 0; j < 4; ++j) acc[i][j] = 0.f;

    const int arow = tid >> 2, akq = tid & 3;       // A tile: 64 rows x 16 k
    const int brow = tid >> 4, bcq = tid & 15;      // B tile: 16 rows x 64 n

    for (int k0 = 0; k0 < K; k0 += 16) {
        {
            const float4 a4 = *(const float4*)(A + (size_t)(bm + arow) * K + k0 + 4 * akq);
            As[4 * akq + 0][arow] = a4.x;
            As[4 * akq + 1][arow] = a4.y;
            As[4 * akq + 2][arow] = a4.z;
            As[4 * akq + 3][arow] = a4.w;
        }
        {
            const int n = bn + 4 * bcq;
            float4 b4;
            if (n + 3 < N) {
                b4 = *(const float4*)(B + (size_t)(k0 + brow) * N + n);
            } else {
                float v0 = (n + 0 < N) ? B[(size_t)(k0 + brow) * N + n + 0] : 0.f;
                float v1 = (n + 1 < N) ? B[(size_t)(k0 + brow) * N + n + 1] : 0.f;
                float v2 = (n + 2 < N) ? B[(size_t)(k0 + brow) * N + n + 2] : 0.f;
                float v3 = (n + 3 < N) ? B[(size_t)(k0 + brow) * N + n + 3] : 0.f;
                b4 = make_float4(v0, v1, v2, v3);
            }
            *(float4*)&Bs[brow][4 * bcq] = b4;
        }
        __syncthreads();
#pragma unroll
        for (int k = 0; k < 16; ++k) {
            float a[4], b[4];
            *(float4*)a = *(const float4*)&As[k][4 * ty];
            *(float4*)b = *(const float4*)&Bs[k][4 * tx];
#pragma unroll
            for (int i = 0; i < 4; ++i)
#pragma unroll
                for (int j = 0; j < 4; ++j) acc[i][j] = fmaf(a[i], b[j], acc[i][j]);
        }
        __syncthreads();
    }

#pragma unroll
    for (int i = 0; i < 4; ++i) {
        const int m = bm + 4 * ty + i;
        const int n = bn + 4 * tx;
        if (n + 3 < N) {
            *(float4*)(C + (size_t)m * N + n) = make_float4(acc[i][0], acc[i][1], acc[i][2], acc[i][3]);
        } else {
#pragma unroll
            for (int j = 0; j < 4; ++j)
                if (n + j < N) C[(size_t)m * N + n + j] = acc[i][j];
        }
    }
}

// ---------------------------------------------------------------------------
// Depthwise causal conv (D_CONV=4) + SiLU.
// ---------------------------------------------------------------------------
__global__ __launch_bounds__(256) void conv_silu_kernel(
    const float* __restrict__ xz, const float* __restrict__ conv_w,
    const float* __restrict__ conv_b, float* __restrict__ u)
{
    const int d = blockIdx.x * 256 + threadIdx.x;   // 0..2047
    const int t = blockIdx.y;                       // 0..2047
    float acc = conv_b[d];
#pragma unroll
    for (int j = 0; j < DCONV; ++j) {
        const int tt = t - (DCONV - 1) + j;
        if (tt >= 0) acc = fmaf(xz[(size_t)tt * (2 * DINNER) + d], conv_w[d * DCONV + j], acc);
    }
    const float s = acc / (1.f + __expf(-acc));
    u[(size_t)t * DINNER + d] = s;
}

// ---------------------------------------------------------------------------
// delta = softplus(dlt @ W_dt + b_dt)
// ---------------------------------------------------------------------------
__global__ __launch_bounds__(256) void delta_kernel(
    const float* __restrict__ x_dbl, const float* __restrict__ W_dt,
    const float* __restrict__ b_dt, float* __restrict__ delta)
{
    __shared__ float dl[16][64];
    const int tid = threadIdx.x;
    const int d = blockIdx.x * 256 + tid;
    const int t0 = blockIdx.y * 16;

    for (int i = tid; i < 16 * 64; i += 256) {
        const int tt = i >> 6, k = i & 63;
        dl[tt][k] = x_dbl[(size_t)(t0 + tt) * NXDBL + k];
    }
    __syncthreads();

    const float bb = b_dt[d];
    float acc[16];
#pragma unroll
    for (int tt = 0; tt < 16; ++tt) acc[tt] = bb;

    for (int k = 0; k < 64; ++k) {
        const float w = W_dt[(size_t)k * DINNER + d];
#pragma unroll
        for (int tt = 0; tt < 16; ++tt) acc[tt] = fmaf(dl[tt][k], w, acc[tt]);
    }
#pragma unroll
    for (int tt = 0; tt < 16; ++tt) {
        const float x = acc[tt];
        const float sp = (x > 20.f) ? x : log1pf(__expf(x));
        delta[(size_t)(t0 + tt) * DINNER + d] = sp;
    }
}

// ---------------------------------------------------------------------------
// Parallel scan, phase 1: per-(d,n,chunk) compute Pi(a) and h-from-zero.
// Block = 16 d-channels x 16 n, grid = (DINNER/16, CCH).
// ---------------------------------------------------------------------------
__global__ __launch_bounds__(256) void scan_phase1(
    const float* __restrict__ u, const float* __restrict__ delta,
    const float* __restrict__ x_dbl, const float* __restrict__ A_log,
    float* __restrict__ aprod,   // [CCH][DINNER][DSTATE]
    float* __restrict__ hacc)    // [CCH][DINNER][DSTATE]
{
    __shared__ float sDelta[TC][16];
    __shared__ float sU[TC][16];
    __shared__ float sB[TC][16];

    const int tid = threadIdx.x;
    const int lane = tid & 63;
    const int wave = tid >> 6;
    const int cc = lane >> 4;
    const int n = lane & 15;
    const int dd = wave * 4 + cc;
    const int d0 = blockIdx.x * 16;
    const int d = d0 + dd;
    const int ch = blockIdx.y;
    const int t0 = ch * TC;

    const float A = -__expf(A_log[d * DSTATE + n]);

    for (int i = tid; i < TC * 16; i += 256) {
        const int tt = i >> 4, q = i & 15;
        const int t = t0 + tt;
        sDelta[tt][q] = delta[(size_t)t * DINNER + d0 + q];
        sU[tt][q]     = u[(size_t)t * DINNER + d0 + q];
        sB[tt][q]     = x_dbl[(size_t)t * NXDBL + DTRANK + q];
    }
    __syncthreads();

    float h = 0.f, ap = 1.f;
#pragma unroll 4
    for (int tt = 0; tt < TC; ++tt) {
        const float dt = sDelta[tt][dd];
        const float a = __expf(dt * A);
        h = fmaf(a, h, dt * sU[tt][dd] * sB[tt][n]);
        ap *= a;
    }
    const size_t idx = (size_t)ch * DINNER * DSTATE + (size_t)d * DSTATE + n;
    aprod[idx] = ap;
    hacc[idx]  = h;
}

// ---------------------------------------------------------------------------
// Phase 2: exclusive scan over chunk summaries, in place (hacc -> hinit).
// One thread per (d,n).
// ---------------------------------------------------------------------------
__global__ __launch_bounds__(256) void scan_phase2(
    const float* __restrict__ aprod, float* __restrict__ hacc)
{
    const int i = blockIdx.x * 256 + threadIdx.x;   // d*16+n
    float h0 = 0.f;
#pragma unroll 4
    for (int c = 0; c < CCH; ++c) {
        const size_t idx = (size_t)c * DINNER * DSTATE + i;
        const float a  = aprod[idx];
        const float hc = hacc[idx];
        hacc[idx] = h0;            // init state for chunk c
        h0 = fmaf(a, h0, hc);
    }
}

// ---------------------------------------------------------------------------
// Phase 3: replay chunks from corrected init, reduce over n, gate, write g.
// ---------------------------------------------------------------------------
__global__ __launch_bounds__(256) void scan_phase3(
    const float* __restrict__ xz,      // z at [t*4096 + 2048 + d]
    const float* __restrict__ u,
    const float* __restrict__ delta,
    const float* __restrict__ x_dbl,
    const float* __restrict__ A_log,
    const float* __restrict__ D_param,
    const float* __restrict__ hinit,   // [CCH][DINNER][DSTATE]
    float* __restrict__ g)
{
    __shared__ float sDelta[TC][16];
    __shared__ float sU[TC][16];
    __shared__ float sZ[TC][16];
    __shared__ float sB[TC][16];
    __shared__ float sC[TC][16];

    const int tid = threadIdx.x;
    const int lane = tid & 63;
    const int wave = tid >> 6;
    const int cc = lane >> 4;
    const int n = lane & 15;
    const int dd = wave * 4 + cc;
    const int d0 = blockIdx.x * 16;
    const int d = d0 + dd;
    const int ch = blockIdx.y;
    const int t0 = ch * TC;

    const float A = -__expf(A_log[d * DSTATE + n]);
    const float Dp = D_param[d];
    float h = hinit[(size_t)ch * DINNER * DSTATE + (size_t)d * DSTATE + n];

    for (int i = tid; i < TC * 16; i += 256) {
        const int tt = i >> 4, q = i & 15;
        const int t = t0 + tt;
        sDelta[tt][q] = delta[(size_t)t * DINNER + d0 + q];
        sU[tt][q]     = u[(size_t)t * DINNER + d0 + q];
        sZ[tt][q]     = xz[(size_t)t * (2 * DINNER) + DINNER + d0 + q];
        sB[tt][q]     = x_dbl[(size_t)t * NXDBL + DTRANK + q];
        sC[tt][q]     = x_dbl[(size_t)t * NXDBL + DTRANK + DSTATE + q];
    }
    __syncthreads();

#pragma unroll 4
    for (int tt = 0; tt < TC; ++tt) {
        const float dt = sDelta[tt][dd];
        const float uu = sU[tt][dd];
        h = fmaf(__expf(dt * A), h, dt * uu * sB[tt][n]);
        float p = h * sC[tt][n];
        p += __shfl_xor(p, 1);
        p += __shfl_xor(p, 2);
        p += __shfl_xor(p, 4);
        p += __shfl_xor(p, 8);
        if (n == 0) {
            const float y = p + Dp * uu;
            const float z = sZ[tt][dd];
            const float gate = z / (1.f + __expf(-z));
            g[(size_t)(t0 + tt) * DINNER + d] = y * gate;
        }
    }
}

// ---------------------------------------------------------------------------
extern "C" void kernel_launch(void* const* d_in, const int* in_sizes, int n_in,
                              void* d_out, int out_size, void* d_ws, size_t ws_size,
                              hipStream_t stream)
{
    const float* x      = (const float*)d_in[0];
    const float* W_in   = (const float*)d_in[1];
    const float* conv_w = (const float*)d_in[2];
    const float* conv_b = (const float*)d_in[3];
    const float* W_x    = (const float*)d_in[4];
    const float* W_dt   = (const float*)d_in[5];
    const float* b_dt   = (const float*)d_in[6];
    const float* A_log  = (const float*)d_in[7];
    const float* D_par  = (const float*)d_in[8];
    const float* W_out  = (const float*)d_in[9];
    float* out = (float*)d_out;

    float* ws    = (float*)d_ws;
    float* xz    = ws;                                  // 2048*4096
    float* u     = xz + (size_t)L_SEQ * 2 * DINNER;     // 2048*2048
    float* x_dbl = u + (size_t)L_SEQ * DINNER;          // 2048*96
    float* delta = x_dbl + (size_t)L_SEQ * NXDBL;       // 2048*2048
    float* aprod = delta + (size_t)L_SEQ * DINNER;      // 32*2048*16
    float* hacc  = aprod + (size_t)CCH * DINNER * DSTATE; // 32*2048*16 (becomes hinit)
    float* g     = u;  // alias: each phase-3 block stages its u tile into LDS
                       // before overwriting with g; disjoint (t,d) ownership.

    // 1) xz = x @ W_in   (2048x1024 @ 1024x4096)
    gemm_f32<<<dim3(2 * DINNER / 64, L_SEQ / 64), 256, 0, stream>>>(x, W_in, xz, L_SEQ, 2 * DINNER, DMODEL);
    // 2) u = silu(conv(xc))
    conv_silu_kernel<<<dim3(DINNER / 256, L_SEQ), 256, 0, stream>>>(xz, conv_w, conv_b, u);
    // 3) x_dbl = u @ W_x   (2048x2048 @ 2048x96)
    gemm_f32<<<dim3((NXDBL + 63) / 64, L_SEQ / 64), 256, 0, stream>>>(u, W_x, x_dbl, L_SEQ, NXDBL, DINNER);
    // 4) delta = softplus(dlt @ W_dt + b_dt)
    delta_kernel<<<dim3(DINNER / 256, L_SEQ / 16), 256, 0, stream>>>(x_dbl, W_dt, b_dt, delta);
    // 5) parallel scan
    scan_phase1<<<dim3(DINNER / 16, CCH), 256, 0, stream>>>(u, delta, x_dbl, A_log, aprod, hacc);
    scan_phase2<<<dim3(DINNER * DSTATE / 256), 256, 0, stream>>>(aprod, hacc);
    scan_phase3<<<dim3(DINNER / 16, CCH), 256, 0, stream>>>(xz, u, delta, x_dbl, A_log, D_par, hacc, g);
    // 6) out = g @ W_out   (2048x2048 @ 2048x1024)
    gemm_f32<<<dim3(DMODEL / 64, L_SEQ / 64), 256, 0, stream>>>(g, W_out, out, L_SEQ, DMODEL, DINNER);
}

// Round 3
// 523.062 us; speedup vs baseline: 2.2445x; 1.4189x over previous
//
#include <hip/hip_runtime.h>
#include <hip/hip_bf16.h>
#include <math.h>

// Problem constants
#define L_SEQ   2048
#define DMODEL  1024
#define DINNER  2048
#define DSTATE  16
#define DCONV   4
#define DTRANK  64
#define NXDBL   96   // DT_RANK + 2*D_STATE

#define CCH 32   // time chunks for parallel scan
#define TC  64   // timesteps per chunk (CCH*TC == L_SEQ)

typedef __bf16 bf16x8 __attribute__((ext_vector_type(8)));
typedef float f32x4 __attribute__((ext_vector_type(4)));
typedef unsigned short ushort4v __attribute__((ext_vector_type(4)));
typedef unsigned short ushort8v __attribute__((ext_vector_type(8)));

// fp32 -> bf16 (RNE) via bit ops; hi/lo split for bf16x3 GEMM.
__device__ __forceinline__ unsigned short f2bh(float f) {
    unsigned u = __float_as_uint(f);
    u += 0x7fffu + ((u >> 16) & 1u);
    return (unsigned short)(u >> 16);
}
__device__ __forceinline__ float bh2f(unsigned short h) {
    return __uint_as_float(((unsigned)h) << 16);
}

// ---------------------------------------------------------------------------
// Weight prep: W[K][N] fp32 -> WT_hi/WT_lo [N][K] bf16 (transpose + split).
// 32x32 tiles, 256 threads.
// ---------------------------------------------------------------------------
__global__ __launch_bounds__(256) void transpose_split(
    const float* __restrict__ W, unsigned short* __restrict__ WT_hi,
    unsigned short* __restrict__ WT_lo, int K, int N)
{
    __shared__ float tile[32][33];
    const int tid = threadIdx.x;
    const int k0 = blockIdx.y * 32, n0 = blockIdx.x * 32;
    const int r = tid >> 3, c4 = (tid & 7) * 4;

    const float4 w4 = *(const float4*)(W + (size_t)(k0 + r) * N + n0 + c4);
    tile[r][c4 + 0] = w4.x;
    tile[r][c4 + 1] = w4.y;
    tile[r][c4 + 2] = w4.z;
    tile[r][c4 + 3] = w4.w;
    __syncthreads();

    ushort4v h, l;
#pragma unroll
    for (int j = 0; j < 4; ++j) {
        const float v = tile[c4 + j][r];
        const unsigned short hh = f2bh(v);
        h[j] = hh;
        l[j] = f2bh(v - bh2f(hh));
    }
    *(ushort4v*)(WT_hi + (size_t)(n0 + r) * K + k0 + c4) = h;
    *(ushort4v*)(WT_lo + (size_t)(n0 + r) * K + k0 + c4) = l;
}

// ---------------------------------------------------------------------------
// bf16x3 MFMA GEMM: C[M,N] = A[M,K] @ B[K,N] with fp32 A (split on the fly)
// and pre-transposed/split B (BT_hi/BT_lo as [N][K] bf16).
// Block tile: BM x 128, BM = WMI*32. BK=32. 256 threads = 4 waves (2x2).
// Each wave: WMI x 4 grid of 16x16x32 MFMA tiles, 3 MFMAs per tile per k-step
// (hi*hi + lo*hi + hi*lo).  M%BM==0, N%128==0, K%32==0.
// ---------------------------------------------------------------------------
template <int WMI>
__global__ __launch_bounds__(256) void gemm_bf16x3(
    const float* __restrict__ A, const unsigned short* __restrict__ BT_hi,
    const unsigned short* __restrict__ BT_lo, float* __restrict__ C,
    int M, int N, int K)
{
    constexpr int BM = WMI * 32;
    constexpr int LDT = 40;   // padded k-stride (ushorts): 80B rows, 16B-aligned frags
    __shared__ __align__(16) unsigned short AsH[BM * LDT];
    __shared__ __align__(16) unsigned short AsL[BM * LDT];
    __shared__ __align__(16) unsigned short BsH[128 * LDT];
    __shared__ __align__(16) unsigned short BsL[128 * LDT];

    const int tid = threadIdx.x;
    const int lane = tid & 63;
    const int wave = tid >> 6;
    const int wm = wave >> 1, wn = wave & 1;
    const int bm = blockIdx.y * BM;
    const int bn = blockIdx.x * 128;
    const int l16 = lane & 15;
    const int kq = lane >> 4;   // 0..3

    f32x4 acc[WMI][4];
#pragma unroll
    for (int mi = 0; mi < WMI; ++mi)
#pragma unroll
        for (int ni = 0; ni < 4; ++ni) acc[mi][ni] = {0.f, 0.f, 0.f, 0.f};

    for (int k0 = 0; k0 < K; k0 += 32) {
        __syncthreads();
        // --- stage A: BM x 32 fp32 -> hi/lo bf16 LDS
#pragma unroll
        for (int i = 0; i < WMI; ++i) {
            const int c = tid + 256 * i;          // BM*8 chunks of float4
            const int row = c >> 3, seg = c & 7;
            const float4 a4 = *(const float4*)(A + (size_t)(bm + row) * K + k0 + seg * 4);
            float v[4] = {a4.x, a4.y, a4.z, a4.w};
            ushort4v h, l;
#pragma unroll
            for (int j = 0; j < 4; ++j) {
                const unsigned short hh = f2bh(v[j]);
                h[j] = hh;
                l[j] = f2bh(v[j] - bh2f(hh));
            }
            *(ushort4v*)&AsH[row * LDT + seg * 4] = h;
            *(ushort4v*)&AsL[row * LDT + seg * 4] = l;
        }
        // --- stage B: 128 x 32 bf16 hi/lo (already split/transposed)
#pragma unroll
        for (int i = 0; i < 2; ++i) {
            const int c = tid + 256 * i;          // 512 chunks of ushort8
            const int row = c >> 2, seg = c & 3;
            const size_t gofs = (size_t)(bn + row) * K + k0 + seg * 8;
            *(ushort8v*)&BsH[row * LDT + seg * 8] = *(const ushort8v*)(BT_hi + gofs);
            *(ushort8v*)&BsL[row * LDT + seg * 8] = *(const ushort8v*)(BT_lo + gofs);
        }
        __syncthreads();

        bf16x8 ah[WMI], al[WMI], bh[4], bl[4];
#pragma unroll
        for (int mi = 0; mi < WMI; ++mi) {
            const int r = (wm * WMI + mi) * 16 + l16;
            ah[mi] = *(const bf16x8*)&AsH[r * LDT + kq * 8];
            al[mi] = *(const bf16x8*)&AsL[r * LDT + kq * 8];
        }
#pragma unroll
        for (int ni = 0; ni < 4; ++ni) {
            const int r = wn * 64 + ni * 16 + l16;
            bh[ni] = *(const bf16x8*)&BsH[r * LDT + kq * 8];
            bl[ni] = *(const bf16x8*)&BsL[r * LDT + kq * 8];
        }
#pragma unroll
        for (int mi = 0; mi < WMI; ++mi)
#pragma unroll
            for (int ni = 0; ni < 4; ++ni) {
                acc[mi][ni] = __builtin_amdgcn_mfma_f32_16x16x32_bf16(ah[mi], bh[ni], acc[mi][ni], 0, 0, 0);
                acc[mi][ni] = __builtin_amdgcn_mfma_f32_16x16x32_bf16(al[mi], bh[ni], acc[mi][ni], 0, 0, 0);
                acc[mi][ni] = __builtin_amdgcn_mfma_f32_16x16x32_bf16(ah[mi], bl[ni], acc[mi][ni], 0, 0, 0);
            }
    }

    // --- epilogue: C/D layout col = lane&15, row = (lane>>4)*4 + reg
#pragma unroll
    for (int mi = 0; mi < WMI; ++mi)
#pragma unroll
        for (int ni = 0; ni < 4; ++ni) {
            const int col = bn + wn * 64 + ni * 16 + l16;
#pragma unroll
            for (int r = 0; r < 4; ++r) {
                const int row = bm + (wm * WMI + mi) * 16 + kq * 4 + r;
                C[(size_t)row * N + col] = acc[mi][ni][r];
            }
        }
}

// ---------------------------------------------------------------------------
// fp32 tiled GEMM (kept for the small N=96 GEMM3): 64x64 tile, BK=16.
// ---------------------------------------------------------------------------
__global__ __launch_bounds__(256) void gemm_f32(
    const float* __restrict__ A, const float* __restrict__ B, float* __restrict__ C,
    int M, int N, int K)
{
    __shared__ float As[16][68];
    __shared__ float Bs[16][68];

    const int tid = threadIdx.x;
    const int bm = blockIdx.y * 64;
    const int bn = blockIdx.x * 64;
    const int tx = tid & 15;
    const int ty = tid >> 4;

    float acc[4][4];
#pragma unroll
    for (int i = 0; i < 4; ++i)
#pragma unroll
        for (int j = 0; j < 4; ++j) acc[i][j] = 0.f;

    const int arow = tid >> 2, akq = tid & 3;
    const int brow = tid >> 4, bcq = tid & 15;

    for (int k0 = 0; k0 < K; k0 += 16) {
        {
            const float4 a4 = *(const float4*)(A + (size_t)(bm + arow) * K + k0 + 4 * akq);
            As[4 * akq + 0][arow] = a4.x;
            As[4 * akq + 1][arow] = a4.y;
            As[4 * akq + 2][arow] = a4.z;
            As[4 * akq + 3][arow] = a4.w;
        }
        {
            const int n = bn + 4 * bcq;
            float4 b4;
            if (n + 3 < N) {
                b4 = *(const float4*)(B + (size_t)(k0 + brow) * N + n);
            } else {
                float v0 = (n + 0 < N) ? B[(size_t)(k0 + brow) * N + n + 0] : 0.f;
                float v1 = (n + 1 < N) ? B[(size_t)(k0 + brow) * N + n + 1] : 0.f;
                float v2 = (n + 2 < N) ? B[(size_t)(k0 + brow) * N + n + 2] : 0.f;
                float v3 = (n + 3 < N) ? B[(size_t)(k0 + brow) * N + n + 3] : 0.f;
                b4 = make_float4(v0, v1, v2, v3);
            }
            *(float4*)&Bs[brow][4 * bcq] = b4;
        }
        __syncthreads();
#pragma unroll
        for (int k = 0; k < 16; ++k) {
            float a[4], b[4];
            *(float4*)a = *(const float4*)&As[k][4 * ty];
            *(float4*)b = *(const float4*)&Bs[k][4 * tx];
#pragma unroll
            for (int i = 0; i < 4; ++i)
#pragma unroll
                for (int j = 0; j < 4; ++j) acc[i][j] = fmaf(a[i], b[j], acc[i][j]);
        }
        __syncthreads();
    }

#pragma unroll
    for (int i = 0; i < 4; ++i) {
        const int m = bm + 4 * ty + i;
        const int n = bn + 4 * tx;
        if (n + 3 < N) {
            *(float4*)(C + (size_t)m * N + n) = make_float4(acc[i][0], acc[i][1], acc[i][2], acc[i][3]);
        } else {
#pragma unroll
            for (int j = 0; j < 4; ++j)
                if (n + j < N) C[(size_t)m * N + n + j] = acc[i][j];
        }
    }
}

// ---------------------------------------------------------------------------
// Depthwise causal conv (D_CONV=4) + SiLU.
// ---------------------------------------------------------------------------
__global__ __launch_bounds__(256) void conv_silu_kernel(
    const float* __restrict__ xz, const float* __restrict__ conv_w,
    const float* __restrict__ conv_b, float* __restrict__ u)
{
    const int d = blockIdx.x * 256 + threadIdx.x;
    const int t = blockIdx.y;
    float acc = conv_b[d];
#pragma unroll
    for (int j = 0; j < DCONV; ++j) {
        const int tt = t - (DCONV - 1) + j;
        if (tt >= 0) acc = fmaf(xz[(size_t)tt * (2 * DINNER) + d], conv_w[d * DCONV + j], acc);
    }
    const float s = acc / (1.f + __expf(-acc));
    u[(size_t)t * DINNER + d] = s;
}

// ---------------------------------------------------------------------------
// delta = softplus(dlt @ W_dt + b_dt)
// ---------------------------------------------------------------------------
__global__ __launch_bounds__(256) void delta_kernel(
    const float* __restrict__ x_dbl, const float* __restrict__ W_dt,
    const float* __restrict__ b_dt, float* __restrict__ delta)
{
    __shared__ float dl[16][64];
    const int tid = threadIdx.x;
    const int d = blockIdx.x * 256 + tid;
    const int t0 = blockIdx.y * 16;

    for (int i = tid; i < 16 * 64; i += 256) {
        const int tt = i >> 6, k = i & 63;
        dl[tt][k] = x_dbl[(size_t)(t0 + tt) * NXDBL + k];
    }
    __syncthreads();

    const float bb = b_dt[d];
    float acc[16];
#pragma unroll
    for (int tt = 0; tt < 16; ++tt) acc[tt] = bb;

    for (int k = 0; k < 64; ++k) {
        const float w = W_dt[(size_t)k * DINNER + d];
#pragma unroll
        for (int tt = 0; tt < 16; ++tt) acc[tt] = fmaf(dl[tt][k], w, acc[tt]);
    }
#pragma unroll
    for (int tt = 0; tt < 16; ++tt) {
        const float x = acc[tt];
        const float sp = (x > 20.f) ? x : log1pf(__expf(x));
        delta[(size_t)(t0 + tt) * DINNER + d] = sp;
    }
}

// ---------------------------------------------------------------------------
// Parallel scan, phase 1: per-(d,n,chunk) compute Pi(a) and h-from-zero.
// ---------------------------------------------------------------------------
__global__ __launch_bounds__(256) void scan_phase1(
    const float* __restrict__ u, const float* __restrict__ delta,
    const float* __restrict__ x_dbl, const float* __restrict__ A_log,
    float* __restrict__ aprod, float* __restrict__ hacc)
{
    __shared__ float sDelta[TC][16];
    __shared__ float sU[TC][16];
    __shared__ float sB[TC][16];

    const int tid = threadIdx.x;
    const int lane = tid & 63;
    const int wave = tid >> 6;
    const int cc = lane >> 4;
    const int n = lane & 15;
    const int dd = wave * 4 + cc;
    const int d0 = blockIdx.x * 16;
    const int d = d0 + dd;
    const int ch = blockIdx.y;
    const int t0 = ch * TC;

    const float A = -__expf(A_log[d * DSTATE + n]);

    for (int i = tid; i < TC * 16; i += 256) {
        const int tt = i >> 4, q = i & 15;
        const int t = t0 + tt;
        sDelta[tt][q] = delta[(size_t)t * DINNER + d0 + q];
        sU[tt][q]     = u[(size_t)t * DINNER + d0 + q];
        sB[tt][q]     = x_dbl[(size_t)t * NXDBL + DTRANK + q];
    }
    __syncthreads();

    float h = 0.f, ap = 1.f;
#pragma unroll 4
    for (int tt = 0; tt < TC; ++tt) {
        const float dt = sDelta[tt][dd];
        const float a = __expf(dt * A);
        h = fmaf(a, h, dt * sU[tt][dd] * sB[tt][n]);
        ap *= a;
    }
    const size_t idx = (size_t)ch * DINNER * DSTATE + (size_t)d * DSTATE + n;
    aprod[idx] = ap;
    hacc[idx]  = h;
}

// ---------------------------------------------------------------------------
// Phase 2: exclusive scan over chunk summaries (hacc -> hinit in place).
// ---------------------------------------------------------------------------
__global__ __launch_bounds__(256) void scan_phase2(
    const float* __restrict__ aprod, float* __restrict__ hacc)
{
    const int i = blockIdx.x * 256 + threadIdx.x;
    float h0 = 0.f;
#pragma unroll 4
    for (int c = 0; c < CCH; ++c) {
        const size_t idx = (size_t)c * DINNER * DSTATE + i;
        const float a  = aprod[idx];
        const float hc = hacc[idx];
        hacc[idx] = h0;
        h0 = fmaf(a, h0, hc);
    }
}

// ---------------------------------------------------------------------------
// Phase 3: replay from corrected init, reduce over n, gate, write g (fp32).
// ---------------------------------------------------------------------------
__global__ __launch_bounds__(256) void scan_phase3(
    const float* __restrict__ xz, const float* __restrict__ u,
    const float* __restrict__ delta, const float* __restrict__ x_dbl,
    const float* __restrict__ A_log, const float* __restrict__ D_param,
    const float* __restrict__ hinit, float* __restrict__ g)
{
    __shared__ float sDelta[TC][16];
    __shared__ float sU[TC][16];
    __shared__ float sZ[TC][16];
    __shared__ float sB[TC][16];
    __shared__ float sC[TC][16];

    const int tid = threadIdx.x;
    const int lane = tid & 63;
    const int wave = tid >> 6;
    const int cc = lane >> 4;
    const int n = lane & 15;
    const int dd = wave * 4 + cc;
    const int d0 = blockIdx.x * 16;
    const int d = d0 + dd;
    const int ch = blockIdx.y;
    const int t0 = ch * TC;

    const float A = -__expf(A_log[d * DSTATE + n]);
    const float Dp = D_param[d];
    float h = hinit[(size_t)ch * DINNER * DSTATE + (size_t)d * DSTATE + n];

    for (int i = tid; i < TC * 16; i += 256) {
        const int tt = i >> 4, q = i & 15;
        const int t = t0 + tt;
        sDelta[tt][q] = delta[(size_t)t * DINNER + d0 + q];
        sU[tt][q]     = u[(size_t)t * DINNER + d0 + q];
        sZ[tt][q]     = xz[(size_t)t * (2 * DINNER) + DINNER + d0 + q];
        sB[tt][q]     = x_dbl[(size_t)t * NXDBL + DTRANK + q];
        sC[tt][q]     = x_dbl[(size_t)t * NXDBL + DTRANK + DSTATE + q];
    }
    __syncthreads();

#pragma unroll 4
    for (int tt = 0; tt < TC; ++tt) {
        const float dt = sDelta[tt][dd];
        const float uu = sU[tt][dd];
        h = fmaf(__expf(dt * A), h, dt * uu * sB[tt][n]);
        float p = h * sC[tt][n];
        p += __shfl_xor(p, 1);
        p += __shfl_xor(p, 2);
        p += __shfl_xor(p, 4);
        p += __shfl_xor(p, 8);
        if (n == 0) {
            const float y = p + Dp * uu;
            const float z = sZ[tt][dd];
            const float gate = z / (1.f + __expf(-z));
            g[(size_t)(t0 + tt) * DINNER + d] = y * gate;
        }
    }
}

// ---------------------------------------------------------------------------
extern "C" void kernel_launch(void* const* d_in, const int* in_sizes, int n_in,
                              void* d_out, int out_size, void* d_ws, size_t ws_size,
                              hipStream_t stream)
{
    const float* x      = (const float*)d_in[0];
    const float* W_in   = (const float*)d_in[1];
    const float* conv_w = (const float*)d_in[2];
    const float* conv_b = (const float*)d_in[3];
    const float* W_x    = (const float*)d_in[4];
    const float* W_dt   = (const float*)d_in[5];
    const float* b_dt   = (const float*)d_in[6];
    const float* A_log  = (const float*)d_in[7];
    const float* D_par  = (const float*)d_in[8];
    const float* W_out  = (const float*)d_in[9];
    float* out = (float*)d_out;

    float* ws    = (float*)d_ws;
    float* xz    = ws;                                    // 2048*4096 f32
    float* u     = xz + (size_t)L_SEQ * 2 * DINNER;       // 2048*2048 f32
    float* x_dbl = u + (size_t)L_SEQ * DINNER;            // 2048*96 f32
    float* delta = x_dbl + (size_t)L_SEQ * NXDBL;         // 2048*2048 f32
    float* aprod = delta + (size_t)L_SEQ * DINNER;        // 32*2048*16 f32
    float* hacc  = aprod + (size_t)CCH * DINNER * DSTATE; // 32*2048*16 f32
    unsigned short* WinT_hi  = (unsigned short*)(hacc + (size_t)CCH * DINNER * DSTATE);
    unsigned short* WinT_lo  = WinT_hi + (size_t)(2 * DINNER) * DMODEL;   // [4096][1024]
    unsigned short* WoutT_hi = WinT_lo + (size_t)(2 * DINNER) * DMODEL;
    unsigned short* WoutT_lo = WoutT_hi + (size_t)DMODEL * DINNER;        // [1024][2048]
    float* g = u;  // alias: phase-3 stages u tiles into LDS before overwriting.

    // 0) weight prep: transpose + bf16 hi/lo split
    transpose_split<<<dim3(2 * DINNER / 32, DMODEL / 32), 256, 0, stream>>>(W_in, WinT_hi, WinT_lo, DMODEL, 2 * DINNER);
    transpose_split<<<dim3(DMODEL / 32, DINNER / 32), 256, 0, stream>>>(W_out, WoutT_hi, WoutT_lo, DINNER, DMODEL);

    // 1) xz = x @ W_in   (2048x1024 @ 1024x4096) -- bf16x3 MFMA
    gemm_bf16x3<4><<<dim3(2 * DINNER / 128, L_SEQ / 128), 256, 0, stream>>>(
        x, WinT_hi, WinT_lo, xz, L_SEQ, 2 * DINNER, DMODEL);
    // 2) u = silu(conv(xc))
    conv_silu_kernel<<<dim3(DINNER / 256, L_SEQ), 256, 0, stream>>>(xz, conv_w, conv_b, u);
    // 3) x_dbl = u @ W_x   (2048x2048 @ 2048x96) -- fp32
    gemm_f32<<<dim3((NXDBL + 63) / 64, L_SEQ / 64), 256, 0, stream>>>(u, W_x, x_dbl, L_SEQ, NXDBL, DINNER);
    // 4) delta = softplus(dlt @ W_dt + b_dt)
    delta_kernel<<<dim3(DINNER / 256, L_SEQ / 16), 256, 0, stream>>>(x_dbl, W_dt, b_dt, delta);
    // 5) parallel scan
    scan_phase1<<<dim3(DINNER / 16, CCH), 256, 0, stream>>>(u, delta, x_dbl, A_log, aprod, hacc);
    scan_phase2<<<dim3(DINNER * DSTATE / 256), 256, 0, stream>>>(aprod, hacc);
    scan_phase3<<<dim3(DINNER / 16, CCH), 256, 0, stream>>>(xz, u, delta, x_dbl, A_log, D_par, hacc, g);
    // 6) out = g @ W_out   (2048x2048 @ 2048x1024) -- bf16x3 MFMA, BM=64
    gemm_bf16x3<2><<<dim3(DMODEL / 128, L_SEQ / 64), 256, 0, stream>>>(
        g, WoutT_hi, WoutT_lo, out, L_SEQ, DMODEL, DINNER);
}

// Round 4
// 386.538 us; speedup vs baseline: 3.0373x; 1.3532x over previous
//
#include <hip/hip_runtime.h>
#include <hip/hip_bf16.h>
#include <math.h>

// Problem constants
#define L_SEQ   2048
#define DMODEL  1024
#define DINNER  2048
#define DSTATE  16
#define DCONV   4
#define DTRANK  64
#define NXDBL   96   // DT_RANK + 2*D_STATE

#define CCH 32   // time chunks for parallel scan
#define TC  64   // timesteps per chunk (CCH*TC == L_SEQ)
#define KS3 16   // split-K factor for GEMM3

typedef __bf16 bf16x8 __attribute__((ext_vector_type(8)));
typedef float f32x4 __attribute__((ext_vector_type(4)));
typedef unsigned short ushort4v __attribute__((ext_vector_type(4)));
typedef unsigned short ushort8v __attribute__((ext_vector_type(8)));

// fp32 -> bf16 (RNE) via bit ops; hi/lo split for bf16x3 GEMM.
__device__ __forceinline__ unsigned short f2bh(float f) {
    unsigned u = __float_as_uint(f);
    u += 0x7fffu + ((u >> 16) & 1u);
    return (unsigned short)(u >> 16);
}
__device__ __forceinline__ float bh2f(unsigned short h) {
    return __uint_as_float(((unsigned)h) << 16);
}

// ---------------------------------------------------------------------------
// Weight prep: W[K][N] fp32 -> WT_hi/WT_lo [N][K] bf16 (transpose + split).
// ---------------------------------------------------------------------------
__global__ __launch_bounds__(256) void transpose_split(
    const float* __restrict__ W, unsigned short* __restrict__ WT_hi,
    unsigned short* __restrict__ WT_lo, int K, int N)
{
    __shared__ float tile[32][33];
    const int tid = threadIdx.x;
    const int k0 = blockIdx.y * 32, n0 = blockIdx.x * 32;
    const int r = tid >> 3, c4 = (tid & 7) * 4;

    const float4 w4 = *(const float4*)(W + (size_t)(k0 + r) * N + n0 + c4);
    tile[r][c4 + 0] = w4.x;
    tile[r][c4 + 1] = w4.y;
    tile[r][c4 + 2] = w4.z;
    tile[r][c4 + 3] = w4.w;
    __syncthreads();

    ushort4v h, l;
#pragma unroll
    for (int j = 0; j < 4; ++j) {
        const float v = tile[c4 + j][r];
        const unsigned short hh = f2bh(v);
        h[j] = hh;
        l[j] = f2bh(v - bh2f(hh));
    }
    *(ushort4v*)(WT_hi + (size_t)(n0 + r) * K + k0 + c4) = h;
    *(ushort4v*)(WT_lo + (size_t)(n0 + r) * K + k0 + c4) = l;
}

// ---------------------------------------------------------------------------
// bf16x3 MFMA GEMM: C[M,N] = A[M,K] @ B[K,N], fp32 A split on the fly,
// pre-transposed/split B ([N][K] bf16 hi/lo).
// Block tile: BM x 128, BM = WMI*32. BK=32. 256 threads = 4 waves (2x2).
// ---------------------------------------------------------------------------
template <int WMI>
__global__ __launch_bounds__(256) void gemm_bf16x3(
    const float* __restrict__ A, const unsigned short* __restrict__ BT_hi,
    const unsigned short* __restrict__ BT_lo, float* __restrict__ C,
    int M, int N, int K)
{
    constexpr int BM = WMI * 32;
    constexpr int LDT = 40;
    __shared__ __align__(16) unsigned short AsH[BM * LDT];
    __shared__ __align__(16) unsigned short AsL[BM * LDT];
    __shared__ __align__(16) unsigned short BsH[128 * LDT];
    __shared__ __align__(16) unsigned short BsL[128 * LDT];

    const int tid = threadIdx.x;
    const int lane = tid & 63;
    const int wave = tid >> 6;
    const int wm = wave >> 1, wn = wave & 1;
    const int bm = blockIdx.y * BM;
    const int bn = blockIdx.x * 128;
    const int l16 = lane & 15;
    const int kq = lane >> 4;

    f32x4 acc[WMI][4];
#pragma unroll
    for (int mi = 0; mi < WMI; ++mi)
#pragma unroll
        for (int ni = 0; ni < 4; ++ni) acc[mi][ni] = {0.f, 0.f, 0.f, 0.f};

    for (int k0 = 0; k0 < K; k0 += 32) {
        __syncthreads();
#pragma unroll
        for (int i = 0; i < WMI; ++i) {
            const int c = tid + 256 * i;
            const int row = c >> 3, seg = c & 7;
            const float4 a4 = *(const float4*)(A + (size_t)(bm + row) * K + k0 + seg * 4);
            float v[4] = {a4.x, a4.y, a4.z, a4.w};
            ushort4v h, l;
#pragma unroll
            for (int j = 0; j < 4; ++j) {
                const unsigned short hh = f2bh(v[j]);
                h[j] = hh;
                l[j] = f2bh(v[j] - bh2f(hh));
            }
            *(ushort4v*)&AsH[row * LDT + seg * 4] = h;
            *(ushort4v*)&AsL[row * LDT + seg * 4] = l;
        }
#pragma unroll
        for (int i = 0; i < 2; ++i) {
            const int c = tid + 256 * i;
            const int row = c >> 2, seg = c & 3;
            const size_t gofs = (size_t)(bn + row) * K + k0 + seg * 8;
            *(ushort8v*)&BsH[row * LDT + seg * 8] = *(const ushort8v*)(BT_hi + gofs);
            *(ushort8v*)&BsL[row * LDT + seg * 8] = *(const ushort8v*)(BT_lo + gofs);
        }
        __syncthreads();

        bf16x8 ah[WMI], al[WMI], bh[4], bl[4];
#pragma unroll
        for (int mi = 0; mi < WMI; ++mi) {
            const int r = (wm * WMI + mi) * 16 + l16;
            ah[mi] = *(const bf16x8*)&AsH[r * LDT + kq * 8];
            al[mi] = *(const bf16x8*)&AsL[r * LDT + kq * 8];
        }
#pragma unroll
        for (int ni = 0; ni < 4; ++ni) {
            const int r = wn * 64 + ni * 16 + l16;
            bh[ni] = *(const bf16x8*)&BsH[r * LDT + kq * 8];
            bl[ni] = *(const bf16x8*)&BsL[r * LDT + kq * 8];
        }
#pragma unroll
        for (int mi = 0; mi < WMI; ++mi)
#pragma unroll
            for (int ni = 0; ni < 4; ++ni) {
                acc[mi][ni] = __builtin_amdgcn_mfma_f32_16x16x32_bf16(ah[mi], bh[ni], acc[mi][ni], 0, 0, 0);
                acc[mi][ni] = __builtin_amdgcn_mfma_f32_16x16x32_bf16(al[mi], bh[ni], acc[mi][ni], 0, 0, 0);
                acc[mi][ni] = __builtin_amdgcn_mfma_f32_16x16x32_bf16(ah[mi], bl[ni], acc[mi][ni], 0, 0, 0);
            }
    }

#pragma unroll
    for (int mi = 0; mi < WMI; ++mi)
#pragma unroll
        for (int ni = 0; ni < 4; ++ni) {
            const int col = bn + wn * 64 + ni * 16 + l16;
#pragma unroll
            for (int r = 0; r < 4; ++r) {
                const int row = bm + (wm * WMI + mi) * 16 + kq * 4 + r;
                C[(size_t)row * N + col] = acc[mi][ni][r];
            }
        }
}

// ---------------------------------------------------------------------------
// GEMM3 split-K bf16x3: part[ks] = u[:, ks*128:(ks+1)*128] @ W_x[ks-chunk, :].
// Block: 64 (m) x 96 (n) x 128 (k-chunk). Grid (KS3, M/64) = 512 blocks.
// 4 waves: wm = wave&1 (32-row half), wn = wave>>1 (48-col half).
// ---------------------------------------------------------------------------
__global__ __launch_bounds__(256) void gemm3_splitk(
    const float* __restrict__ A,              // u [L_SEQ][DINNER]
    const unsigned short* __restrict__ BT_hi, // W_xT [NXDBL][DINNER]
    const unsigned short* __restrict__ BT_lo,
    float* __restrict__ part)                 // [KS3][L_SEQ][NXDBL]
{
    constexpr int LDT = 40;
    __shared__ __align__(16) unsigned short AsH[64 * LDT];
    __shared__ __align__(16) unsigned short AsL[64 * LDT];
    __shared__ __align__(16) unsigned short BsH[96 * LDT];
    __shared__ __align__(16) unsigned short BsL[96 * LDT];

    const int tid = threadIdx.x;
    const int lane = tid & 63;
    const int wave = tid >> 6;
    const int wm = wave & 1, wn = wave >> 1;
    const int ks = blockIdx.x;
    const int bm = blockIdx.y * 64;
    const int kbase = ks * (DINNER / KS3);    // 128-wide k-chunk
    const int l16 = lane & 15;
    const int kq = lane >> 4;

    f32x4 acc[2][3];
#pragma unroll
    for (int mi = 0; mi < 2; ++mi)
#pragma unroll
        for (int ni = 0; ni < 3; ++ni) acc[mi][ni] = {0.f, 0.f, 0.f, 0.f};

    for (int k0 = 0; k0 < DINNER / KS3; k0 += 32) {
        __syncthreads();
#pragma unroll
        for (int i = 0; i < 2; ++i) {
            const int c = tid + 256 * i;      // 512 float4 chunks (64 rows x 8)
            const int row = c >> 3, seg = c & 7;
            const float4 a4 = *(const float4*)(A + (size_t)(bm + row) * DINNER + kbase + k0 + seg * 4);
            float v[4] = {a4.x, a4.y, a4.z, a4.w};
            ushort4v h, l;
#pragma unroll
            for (int j = 0; j < 4; ++j) {
                const unsigned short hh = f2bh(v[j]);
                h[j] = hh;
                l[j] = f2bh(v[j] - bh2f(hh));
            }
            *(ushort4v*)&AsH[row * LDT + seg * 4] = h;
            *(ushort4v*)&AsL[row * LDT + seg * 4] = l;
        }
        for (int c = tid; c < 96 * 4; c += 256) {
            const int row = c >> 2, seg = c & 3;
            const size_t gofs = (size_t)row * DINNER + kbase + k0 + seg * 8;
            *(ushort8v*)&BsH[row * LDT + seg * 8] = *(const ushort8v*)(BT_hi + gofs);
            *(ushort8v*)&BsL[row * LDT + seg * 8] = *(const ushort8v*)(BT_lo + gofs);
        }
        __syncthreads();

        bf16x8 ah[2], al[2], bh[3], bl[3];
#pragma unroll
        for (int mi = 0; mi < 2; ++mi) {
            const int r = wm * 32 + mi * 16 + l16;
            ah[mi] = *(const bf16x8*)&AsH[r * LDT + kq * 8];
            al[mi] = *(const bf16x8*)&AsL[r * LDT + kq * 8];
        }
#pragma unroll
        for (int ni = 0; ni < 3; ++ni) {
            const int r = wn * 48 + ni * 16 + l16;
            bh[ni] = *(const bf16x8*)&BsH[r * LDT + kq * 8];
            bl[ni] = *(const bf16x8*)&BsL[r * LDT + kq * 8];
        }
#pragma unroll
        for (int mi = 0; mi < 2; ++mi)
#pragma unroll
            for (int ni = 0; ni < 3; ++ni) {
                acc[mi][ni] = __builtin_amdgcn_mfma_f32_16x16x32_bf16(ah[mi], bh[ni], acc[mi][ni], 0, 0, 0);
                acc[mi][ni] = __builtin_amdgcn_mfma_f32_16x16x32_bf16(al[mi], bh[ni], acc[mi][ni], 0, 0, 0);
                acc[mi][ni] = __builtin_amdgcn_mfma_f32_16x16x32_bf16(ah[mi], bl[ni], acc[mi][ni], 0, 0, 0);
            }
    }

#pragma unroll
    for (int mi = 0; mi < 2; ++mi)
#pragma unroll
        for (int ni = 0; ni < 3; ++ni) {
            const int col = wn * 48 + ni * 16 + l16;
#pragma unroll
            for (int r = 0; r < 4; ++r) {
                const int row = bm + wm * 32 + mi * 16 + kq * 4 + r;
                part[((size_t)ks * L_SEQ + row) * NXDBL + col] = acc[mi][ni][r];
            }
        }
}

// ---------------------------------------------------------------------------
// Sum the KS3 partials into x_dbl. float4 per thread; 192 blocks.
// ---------------------------------------------------------------------------
__global__ __launch_bounds__(256) void reduce_part(
    const float* __restrict__ part, float* __restrict__ x_dbl)
{
    const size_t i = ((size_t)blockIdx.x * 256 + threadIdx.x) * 4;
    float4 s = make_float4(0.f, 0.f, 0.f, 0.f);
#pragma unroll 4
    for (int ks = 0; ks < KS3; ++ks) {
        const float4 p = *(const float4*)(part + (size_t)ks * L_SEQ * NXDBL + i);
        s.x += p.x; s.y += p.y; s.z += p.z; s.w += p.w;
    }
    *(float4*)(x_dbl + i) = s;
}

// ---------------------------------------------------------------------------
// Depthwise causal conv (D_CONV=4) + SiLU.
// ---------------------------------------------------------------------------
__global__ __launch_bounds__(256) void conv_silu_kernel(
    const float* __restrict__ xz, const float* __restrict__ conv_w,
    const float* __restrict__ conv_b, float* __restrict__ u)
{
    const int d = blockIdx.x * 256 + threadIdx.x;
    const int t = blockIdx.y;
    float acc = conv_b[d];
#pragma unroll
    for (int j = 0; j < DCONV; ++j) {
        const int tt = t - (DCONV - 1) + j;
        if (tt >= 0) acc = fmaf(xz[(size_t)tt * (2 * DINNER) + d], conv_w[d * DCONV + j], acc);
    }
    const float s = acc / (1.f + __expf(-acc));
    u[(size_t)t * DINNER + d] = s;
}

// ---------------------------------------------------------------------------
// delta = softplus(dlt @ W_dt + b_dt)
// ---------------------------------------------------------------------------
__global__ __launch_bounds__(256) void delta_kernel(
    const float* __restrict__ x_dbl, const float* __restrict__ W_dt,
    const float* __restrict__ b_dt, float* __restrict__ delta)
{
    __shared__ float dl[16][64];
    const int tid = threadIdx.x;
    const int d = blockIdx.x * 256 + tid;
    const int t0 = blockIdx.y * 16;

    for (int i = tid; i < 16 * 64; i += 256) {
        const int tt = i >> 6, k = i & 63;
        dl[tt][k] = x_dbl[(size_t)(t0 + tt) * NXDBL + k];
    }
    __syncthreads();

    const float bb = b_dt[d];
    float acc[16];
#pragma unroll
    for (int tt = 0; tt < 16; ++tt) acc[tt] = bb;

    for (int k = 0; k < 64; ++k) {
        const float w = W_dt[(size_t)k * DINNER + d];
#pragma unroll
        for (int tt = 0; tt < 16; ++tt) acc[tt] = fmaf(dl[tt][k], w, acc[tt]);
    }
#pragma unroll
    for (int tt = 0; tt < 16; ++tt) {
        const float x = acc[tt];
        const float sp = (x > 20.f) ? x : log1pf(__expf(x));
        delta[(size_t)(t0 + tt) * DINNER + d] = sp;
    }
}

// ---------------------------------------------------------------------------
// Parallel scan, phase 1.
// ---------------------------------------------------------------------------
__global__ __launch_bounds__(256) void scan_phase1(
    const float* __restrict__ u, const float* __restrict__ delta,
    const float* __restrict__ x_dbl, const float* __restrict__ A_log,
    float* __restrict__ aprod, float* __restrict__ hacc)
{
    __shared__ float sDelta[TC][16];
    __shared__ float sU[TC][16];
    __shared__ float sB[TC][16];

    const int tid = threadIdx.x;
    const int lane = tid & 63;
    const int wave = tid >> 6;
    const int cc = lane >> 4;
    const int n = lane & 15;
    const int dd = wave * 4 + cc;
    const int d0 = blockIdx.x * 16;
    const int d = d0 + dd;
    const int ch = blockIdx.y;
    const int t0 = ch * TC;

    const float A = -__expf(A_log[d * DSTATE + n]);

    for (int i = tid; i < TC * 16; i += 256) {
        const int tt = i >> 4, q = i & 15;
        const int t = t0 + tt;
        sDelta[tt][q] = delta[(size_t)t * DINNER + d0 + q];
        sU[tt][q]     = u[(size_t)t * DINNER + d0 + q];
        sB[tt][q]     = x_dbl[(size_t)t * NXDBL + DTRANK + q];
    }
    __syncthreads();

    float h = 0.f, ap = 1.f;
#pragma unroll 4
    for (int tt = 0; tt < TC; ++tt) {
        const float dt = sDelta[tt][dd];
        const float a = __expf(dt * A);
        h = fmaf(a, h, dt * sU[tt][dd] * sB[tt][n]);
        ap *= a;
    }
    const size_t idx = (size_t)ch * DINNER * DSTATE + (size_t)d * DSTATE + n;
    aprod[idx] = ap;
    hacc[idx]  = h;
}

// ---------------------------------------------------------------------------
// Phase 2: exclusive scan over chunk summaries (hacc -> hinit in place).
// ---------------------------------------------------------------------------
__global__ __launch_bounds__(256) void scan_phase2(
    const float* __restrict__ aprod, float* __restrict__ hacc)
{
    const int i = blockIdx.x * 256 + threadIdx.x;
    float h0 = 0.f;
#pragma unroll 4
    for (int c = 0; c < CCH; ++c) {
        const size_t idx = (size_t)c * DINNER * DSTATE + i;
        const float a  = aprod[idx];
        const float hc = hacc[idx];
        hacc[idx] = h0;
        h0 = fmaf(a, h0, hc);
    }
}

// ---------------------------------------------------------------------------
// Phase 3: replay from corrected init, reduce over n, gate, write g (fp32).
// ---------------------------------------------------------------------------
__global__ __launch_bounds__(256) void scan_phase3(
    const float* __restrict__ xz, const float* __restrict__ u,
    const float* __restrict__ delta, const float* __restrict__ x_dbl,
    const float* __restrict__ A_log, const float* __restrict__ D_param,
    const float* __restrict__ hinit, float* __restrict__ g)
{
    __shared__ float sDelta[TC][16];
    __shared__ float sU[TC][16];
    __shared__ float sZ[TC][16];
    __shared__ float sB[TC][16];
    __shared__ float sC[TC][16];

    const int tid = threadIdx.x;
    const int lane = tid & 63;
    const int wave = tid >> 6;
    const int cc = lane >> 4;
    const int n = lane & 15;
    const int dd = wave * 4 + cc;
    const int d0 = blockIdx.x * 16;
    const int d = d0 + dd;
    const int ch = blockIdx.y;
    const int t0 = ch * TC;

    const float A = -__expf(A_log[d * DSTATE + n]);
    const float Dp = D_param[d];
    float h = hinit[(size_t)ch * DINNER * DSTATE + (size_t)d * DSTATE + n];

    for (int i = tid; i < TC * 16; i += 256) {
        const int tt = i >> 4, q = i & 15;
        const int t = t0 + tt;
        sDelta[tt][q] = delta[(size_t)t * DINNER + d0 + q];
        sU[tt][q]     = u[(size_t)t * DINNER + d0 + q];
        sZ[tt][q]     = xz[(size_t)t * (2 * DINNER) + DINNER + d0 + q];
        sB[tt][q]     = x_dbl[(size_t)t * NXDBL + DTRANK + q];
        sC[tt][q]     = x_dbl[(size_t)t * NXDBL + DTRANK + DSTATE + q];
    }
    __syncthreads();

#pragma unroll 4
    for (int tt = 0; tt < TC; ++tt) {
        const float dt = sDelta[tt][dd];
        const float uu = sU[tt][dd];
        h = fmaf(__expf(dt * A), h, dt * uu * sB[tt][n]);
        float p = h * sC[tt][n];
        p += __shfl_xor(p, 1);
        p += __shfl_xor(p, 2);
        p += __shfl_xor(p, 4);
        p += __shfl_xor(p, 8);
        if (n == 0) {
            const float y = p + Dp * uu;
            const float z = sZ[tt][dd];
            const float gate = z / (1.f + __expf(-z));
            g[(size_t)(t0 + tt) * DINNER + d] = y * gate;
        }
    }
}

// ---------------------------------------------------------------------------
extern "C" void kernel_launch(void* const* d_in, const int* in_sizes, int n_in,
                              void* d_out, int out_size, void* d_ws, size_t ws_size,
                              hipStream_t stream)
{
    const float* x      = (const float*)d_in[0];
    const float* W_in   = (const float*)d_in[1];
    const float* conv_w = (const float*)d_in[2];
    const float* conv_b = (const float*)d_in[3];
    const float* W_x    = (const float*)d_in[4];
    const float* W_dt   = (const float*)d_in[5];
    const float* b_dt   = (const float*)d_in[6];
    const float* A_log  = (const float*)d_in[7];
    const float* D_par  = (const float*)d_in[8];
    const float* W_out  = (const float*)d_in[9];
    float* out = (float*)d_out;

    float* ws    = (float*)d_ws;
    float* xz    = ws;                                    // 2048*4096 f32
    float* u     = xz + (size_t)L_SEQ * 2 * DINNER;       // 2048*2048 f32
    float* x_dbl = u + (size_t)L_SEQ * DINNER;            // 2048*96 f32
    float* delta = x_dbl + (size_t)L_SEQ * NXDBL;         // 2048*2048 f32
    float* aprod = delta + (size_t)L_SEQ * DINNER;        // 32*2048*16 f32
    float* hacc  = aprod + (size_t)CCH * DINNER * DSTATE; // 32*2048*16 f32
    unsigned short* WinT_hi  = (unsigned short*)(hacc + (size_t)CCH * DINNER * DSTATE);
    unsigned short* WinT_lo  = WinT_hi + (size_t)(2 * DINNER) * DMODEL;   // [4096][1024]
    unsigned short* WoutT_hi = WinT_lo + (size_t)(2 * DINNER) * DMODEL;
    unsigned short* WoutT_lo = WoutT_hi + (size_t)DMODEL * DINNER;        // [1024][2048]
    unsigned short* WxT_hi   = WoutT_lo + (size_t)DMODEL * DINNER;        // [96][2048]
    unsigned short* WxT_lo   = WxT_hi + (size_t)NXDBL * DINNER;
    // part aliases WinT (12.6 MB < 16.8 MB): GEMM1 consumed WinT before GEMM3
    // writes part, and transposes re-run every call (stream-ordered, safe).
    float* part = (float*)WinT_hi;                        // [KS3][2048][96]
    float* g = u;  // alias: phase-3 stages u tiles into LDS before overwriting.

    // 0) weight prep: transpose + bf16 hi/lo split
    transpose_split<<<dim3(2 * DINNER / 32, DMODEL / 32), 256, 0, stream>>>(W_in, WinT_hi, WinT_lo, DMODEL, 2 * DINNER);
    transpose_split<<<dim3(DMODEL / 32, DINNER / 32), 256, 0, stream>>>(W_out, WoutT_hi, WoutT_lo, DINNER, DMODEL);
    transpose_split<<<dim3(NXDBL / 32, DINNER / 32), 256, 0, stream>>>(W_x, WxT_hi, WxT_lo, DINNER, NXDBL);

    // 1) xz = x @ W_in   (2048x1024 @ 1024x4096) -- bf16x3 MFMA
    gemm_bf16x3<4><<<dim3(2 * DINNER / 128, L_SEQ / 128), 256, 0, stream>>>(
        x, WinT_hi, WinT_lo, xz, L_SEQ, 2 * DINNER, DMODEL);
    // 2) u = silu(conv(xc))
    conv_silu_kernel<<<dim3(DINNER / 256, L_SEQ), 256, 0, stream>>>(xz, conv_w, conv_b, u);
    // 3) x_dbl = u @ W_x   (2048x2048 @ 2048x96) -- split-K bf16x3 MFMA
    gemm3_splitk<<<dim3(KS3, L_SEQ / 64), 256, 0, stream>>>(u, WxT_hi, WxT_lo, part);
    reduce_part<<<dim3(L_SEQ * NXDBL / 4 / 256), 256, 0, stream>>>(part, x_dbl);
    // 4) delta = softplus(dlt @ W_dt + b_dt)
    delta_kernel<<<dim3(DINNER / 256, L_SEQ / 16), 256, 0, stream>>>(x_dbl, W_dt, b_dt, delta);
    // 5) parallel scan
    scan_phase1<<<dim3(DINNER / 16, CCH), 256, 0, stream>>>(u, delta, x_dbl, A_log, aprod, hacc);
    scan_phase2<<<dim3(DINNER * DSTATE / 256), 256, 0, stream>>>(aprod, hacc);
    scan_phase3<<<dim3(DINNER / 16, CCH), 256, 0, stream>>>(xz, u, delta, x_dbl, A_log, D_par, hacc, g);
    // 6) out = g @ W_out   (2048x2048 @ 2048x1024) -- bf16x3 MFMA, BM=64
    gemm_bf16x3<2><<<dim3(DMODEL / 128, L_SEQ / 64), 256, 0, stream>>>(
        g, WoutT_hi, WoutT_lo, out, L_SEQ, DMODEL, DINNER);
}

// Round 5
// 360.284 us; speedup vs baseline: 3.2586x; 1.0729x over previous
//
#include <hip/hip_runtime.h>
#include <hip/hip_bf16.h>
#include <math.h>

// Problem constants
#define L_SEQ   2048
#define DMODEL  1024
#define DINNER  2048
#define DSTATE  16
#define DCONV   4
#define DTRANK  64
#define NXDBL   96   // DT_RANK + 2*D_STATE

#define CCH 64   // time chunks for parallel scan
#define TC  32   // timesteps per chunk (CCH*TC == L_SEQ)
#define KS3 16   // split-K factor for GEMM3

#define LOG2E 1.44269504088896340736f

typedef __bf16 bf16x8 __attribute__((ext_vector_type(8)));
typedef float f32x4 __attribute__((ext_vector_type(4)));
typedef unsigned short ushort4v __attribute__((ext_vector_type(4)));
typedef unsigned short ushort8v __attribute__((ext_vector_type(8)));

// fp32 -> bf16 (RNE) via bit ops; hi/lo split for bf16x3 GEMM.
__device__ __forceinline__ unsigned short f2bh(float f) {
    unsigned u = __float_as_uint(f);
    u += 0x7fffu + ((u >> 16) & 1u);
    return (unsigned short)(u >> 16);
}
__device__ __forceinline__ float bh2f(unsigned short h) {
    return __uint_as_float(((unsigned)h) << 16);
}

// ---------------------------------------------------------------------------
// Weight prep: W[K][N] fp32 -> WT_hi/WT_lo [N][K] bf16 (transpose + split).
// ---------------------------------------------------------------------------
__global__ __launch_bounds__(256) void transpose_split(
    const float* __restrict__ W, unsigned short* __restrict__ WT_hi,
    unsigned short* __restrict__ WT_lo, int K, int N)
{
    __shared__ float tile[32][33];
    const int tid = threadIdx.x;
    const int k0 = blockIdx.y * 32, n0 = blockIdx.x * 32;
    const int r = tid >> 3, c4 = (tid & 7) * 4;

    const float4 w4 = *(const float4*)(W + (size_t)(k0 + r) * N + n0 + c4);
    tile[r][c4 + 0] = w4.x;
    tile[r][c4 + 1] = w4.y;
    tile[r][c4 + 2] = w4.z;
    tile[r][c4 + 3] = w4.w;
    __syncthreads();

    ushort4v h, l;
#pragma unroll
    for (int j = 0; j < 4; ++j) {
        const float v = tile[c4 + j][r];
        const unsigned short hh = f2bh(v);
        h[j] = hh;
        l[j] = f2bh(v - bh2f(hh));
    }
    *(ushort4v*)(WT_hi + (size_t)(n0 + r) * K + k0 + c4) = h;
    *(ushort4v*)(WT_lo + (size_t)(n0 + r) * K + k0 + c4) = l;
}

// ---------------------------------------------------------------------------
// bf16x3 MFMA GEMM: C[M,N] = A[M,K] @ B[K,N], fp32 A split on the fly,
// pre-transposed/split B ([N][K] bf16 hi/lo).
// Block tile: BM x 128, BM = WMI*32. BK=32. 256 threads = 4 waves (2x2).
// ---------------------------------------------------------------------------
template <int WMI>
__global__ __launch_bounds__(256) void gemm_bf16x3(
    const float* __restrict__ A, const unsigned short* __restrict__ BT_hi,
    const unsigned short* __restrict__ BT_lo, float* __restrict__ C,
    int M, int N, int K)
{
    constexpr int BM = WMI * 32;
    constexpr int LDT = 40;
    __shared__ __align__(16) unsigned short AsH[BM * LDT];
    __shared__ __align__(16) unsigned short AsL[BM * LDT];
    __shared__ __align__(16) unsigned short BsH[128 * LDT];
    __shared__ __align__(16) unsigned short BsL[128 * LDT];

    const int tid = threadIdx.x;
    const int lane = tid & 63;
    const int wave = tid >> 6;
    const int wm = wave >> 1, wn = wave & 1;
    const int bm = blockIdx.y * BM;
    const int bn = blockIdx.x * 128;
    const int l16 = lane & 15;
    const int kq = lane >> 4;

    f32x4 acc[WMI][4];
#pragma unroll
    for (int mi = 0; mi < WMI; ++mi)
#pragma unroll
        for (int ni = 0; ni < 4; ++ni) acc[mi][ni] = {0.f, 0.f, 0.f, 0.f};

    for (int k0 = 0; k0 < K; k0 += 32) {
        __syncthreads();
#pragma unroll
        for (int i = 0; i < WMI; ++i) {
            const int c = tid + 256 * i;
            const int row = c >> 3, seg = c & 7;
            const float4 a4 = *(const float4*)(A + (size_t)(bm + row) * K + k0 + seg * 4);
            float v[4] = {a4.x, a4.y, a4.z, a4.w};
            ushort4v h, l;
#pragma unroll
            for (int j = 0; j < 4; ++j) {
                const unsigned short hh = f2bh(v[j]);
                h[j] = hh;
                l[j] = f2bh(v[j] - bh2f(hh));
            }
            *(ushort4v*)&AsH[row * LDT + seg * 4] = h;
            *(ushort4v*)&AsL[row * LDT + seg * 4] = l;
        }
#pragma unroll
        for (int i = 0; i < 2; ++i) {
            const int c = tid + 256 * i;
            const int row = c >> 2, seg = c & 3;
            const size_t gofs = (size_t)(bn + row) * K + k0 + seg * 8;
            *(ushort8v*)&BsH[row * LDT + seg * 8] = *(const ushort8v*)(BT_hi + gofs);
            *(ushort8v*)&BsL[row * LDT + seg * 8] = *(const ushort8v*)(BT_lo + gofs);
        }
        __syncthreads();

        bf16x8 ah[WMI], al[WMI], bh[4], bl[4];
#pragma unroll
        for (int mi = 0; mi < WMI; ++mi) {
            const int r = (wm * WMI + mi) * 16 + l16;
            ah[mi] = *(const bf16x8*)&AsH[r * LDT + kq * 8];
            al[mi] = *(const bf16x8*)&AsL[r * LDT + kq * 8];
        }
#pragma unroll
        for (int ni = 0; ni < 4; ++ni) {
            const int r = wn * 64 + ni * 16 + l16;
            bh[ni] = *(const bf16x8*)&BsH[r * LDT + kq * 8];
            bl[ni] = *(const bf16x8*)&BsL[r * LDT + kq * 8];
        }
#pragma unroll
        for (int mi = 0; mi < WMI; ++mi)
#pragma unroll
            for (int ni = 0; ni < 4; ++ni) {
                acc[mi][ni] = __builtin_amdgcn_mfma_f32_16x16x32_bf16(ah[mi], bh[ni], acc[mi][ni], 0, 0, 0);
                acc[mi][ni] = __builtin_amdgcn_mfma_f32_16x16x32_bf16(al[mi], bh[ni], acc[mi][ni], 0, 0, 0);
                acc[mi][ni] = __builtin_amdgcn_mfma_f32_16x16x32_bf16(ah[mi], bl[ni], acc[mi][ni], 0, 0, 0);
            }
    }

#pragma unroll
    for (int mi = 0; mi < WMI; ++mi)
#pragma unroll
        for (int ni = 0; ni < 4; ++ni) {
            const int col = bn + wn * 64 + ni * 16 + l16;
#pragma unroll
            for (int r = 0; r < 4; ++r) {
                const int row = bm + (wm * WMI + mi) * 16 + kq * 4 + r;
                C[(size_t)row * N + col] = acc[mi][ni][r];
            }
        }
}

// ---------------------------------------------------------------------------
// GEMM3 split-K bf16x3: part[ks] = u[:, ks*128:(ks+1)*128] @ W_x[ks-chunk, :].
// ---------------------------------------------------------------------------
__global__ __launch_bounds__(256) void gemm3_splitk(
    const float* __restrict__ A,
    const unsigned short* __restrict__ BT_hi,
    const unsigned short* __restrict__ BT_lo,
    float* __restrict__ part)
{
    constexpr int LDT = 40;
    __shared__ __align__(16) unsigned short AsH[64 * LDT];
    __shared__ __align__(16) unsigned short AsL[64 * LDT];
    __shared__ __align__(16) unsigned short BsH[96 * LDT];
    __shared__ __align__(16) unsigned short BsL[96 * LDT];

    const int tid = threadIdx.x;
    const int lane = tid & 63;
    const int wave = tid >> 6;
    const int wm = wave & 1, wn = wave >> 1;
    const int ks = blockIdx.x;
    const int bm = blockIdx.y * 64;
    const int kbase = ks * (DINNER / KS3);
    const int l16 = lane & 15;
    const int kq = lane >> 4;

    f32x4 acc[2][3];
#pragma unroll
    for (int mi = 0; mi < 2; ++mi)
#pragma unroll
        for (int ni = 0; ni < 3; ++ni) acc[mi][ni] = {0.f, 0.f, 0.f, 0.f};

    for (int k0 = 0; k0 < DINNER / KS3; k0 += 32) {
        __syncthreads();
#pragma unroll
        for (int i = 0; i < 2; ++i) {
            const int c = tid + 256 * i;
            const int row = c >> 3, seg = c & 7;
            const float4 a4 = *(const float4*)(A + (size_t)(bm + row) * DINNER + kbase + k0 + seg * 4);
            float v[4] = {a4.x, a4.y, a4.z, a4.w};
            ushort4v h, l;
#pragma unroll
            for (int j = 0; j < 4; ++j) {
                const unsigned short hh = f2bh(v[j]);
                h[j] = hh;
                l[j] = f2bh(v[j] - bh2f(hh));
            }
            *(ushort4v*)&AsH[row * LDT + seg * 4] = h;
            *(ushort4v*)&AsL[row * LDT + seg * 4] = l;
        }
        for (int c = tid; c < 96 * 4; c += 256) {
            const int row = c >> 2, seg = c & 3;
            const size_t gofs = (size_t)row * DINNER + kbase + k0 + seg * 8;
            *(ushort8v*)&BsH[row * LDT + seg * 8] = *(const ushort8v*)(BT_hi + gofs);
            *(ushort8v*)&BsL[row * LDT + seg * 8] = *(const ushort8v*)(BT_lo + gofs);
        }
        __syncthreads();

        bf16x8 ah[2], al[2], bh[3], bl[3];
#pragma unroll
        for (int mi = 0; mi < 2; ++mi) {
            const int r = wm * 32 + mi * 16 + l16;
            ah[mi] = *(const bf16x8*)&AsH[r * LDT + kq * 8];
            al[mi] = *(const bf16x8*)&AsL[r * LDT + kq * 8];
        }
#pragma unroll
        for (int ni = 0; ni < 3; ++ni) {
            const int r = wn * 48 + ni * 16 + l16;
            bh[ni] = *(const bf16x8*)&BsH[r * LDT + kq * 8];
            bl[ni] = *(const bf16x8*)&BsL[r * LDT + kq * 8];
        }
#pragma unroll
        for (int mi = 0; mi < 2; ++mi)
#pragma unroll
            for (int ni = 0; ni < 3; ++ni) {
                acc[mi][ni] = __builtin_amdgcn_mfma_f32_16x16x32_bf16(ah[mi], bh[ni], acc[mi][ni], 0, 0, 0);
                acc[mi][ni] = __builtin_amdgcn_mfma_f32_16x16x32_bf16(al[mi], bh[ni], acc[mi][ni], 0, 0, 0);
                acc[mi][ni] = __builtin_amdgcn_mfma_f32_16x16x32_bf16(ah[mi], bl[ni], acc[mi][ni], 0, 0, 0);
            }
    }

#pragma unroll
    for (int mi = 0; mi < 2; ++mi)
#pragma unroll
        for (int ni = 0; ni < 3; ++ni) {
            const int col = wn * 48 + ni * 16 + l16;
#pragma unroll
            for (int r = 0; r < 4; ++r) {
                const int row = bm + wm * 32 + mi * 16 + kq * 4 + r;
                part[((size_t)ks * L_SEQ + row) * NXDBL + col] = acc[mi][ni][r];
            }
        }
}

// ---------------------------------------------------------------------------
// Sum the KS3 partials into x_dbl.
// ---------------------------------------------------------------------------
__global__ __launch_bounds__(256) void reduce_part(
    const float* __restrict__ part, float* __restrict__ x_dbl)
{
    const size_t i = ((size_t)blockIdx.x * 256 + threadIdx.x) * 4;
    float4 s = make_float4(0.f, 0.f, 0.f, 0.f);
#pragma unroll 4
    for (int ks = 0; ks < KS3; ++ks) {
        const float4 p = *(const float4*)(part + (size_t)ks * L_SEQ * NXDBL + i);
        s.x += p.x; s.y += p.y; s.z += p.z; s.w += p.w;
    }
    *(float4*)(x_dbl + i) = s;
}

// ---------------------------------------------------------------------------
// Depthwise causal conv (D_CONV=4) + SiLU.
// ---------------------------------------------------------------------------
__global__ __launch_bounds__(256) void conv_silu_kernel(
    const float* __restrict__ xz, const float* __restrict__ conv_w,
    const float* __restrict__ conv_b, float* __restrict__ u)
{
    const int d = blockIdx.x * 256 + threadIdx.x;
    const int t = blockIdx.y;
    float acc = conv_b[d];
#pragma unroll
    for (int j = 0; j < DCONV; ++j) {
        const int tt = t - (DCONV - 1) + j;
        if (tt >= 0) acc = fmaf(xz[(size_t)tt * (2 * DINNER) + d], conv_w[d * DCONV + j], acc);
    }
    const float s = acc / (1.f + __expf(-acc));
    u[(size_t)t * DINNER + d] = s;
}

// ---------------------------------------------------------------------------
// delta = softplus(dlt @ W_dt + b_dt)
// ---------------------------------------------------------------------------
__global__ __launch_bounds__(256) void delta_kernel(
    const float* __restrict__ x_dbl, const float* __restrict__ W_dt,
    const float* __restrict__ b_dt, float* __restrict__ delta)
{
    __shared__ float dl[16][64];
    const int tid = threadIdx.x;
    const int d = blockIdx.x * 256 + tid;
    const int t0 = blockIdx.y * 16;

    for (int i = tid; i < 16 * 64; i += 256) {
        const int tt = i >> 6, k = i & 63;
        dl[tt][k] = x_dbl[(size_t)(t0 + tt) * NXDBL + k];
    }
    __syncthreads();

    const float bb = b_dt[d];
    float acc[16];
#pragma unroll
    for (int tt = 0; tt < 16; ++tt) acc[tt] = bb;

    for (int k = 0; k < 64; ++k) {
        const float w = W_dt[(size_t)k * DINNER + d];
#pragma unroll
        for (int tt = 0; tt < 16; ++tt) acc[tt] = fmaf(dl[tt][k], w, acc[tt]);
    }
#pragma unroll
    for (int tt = 0; tt < 16; ++tt) {
        const float x = acc[tt];
        const float sp = (x > 20.f) ? x : log1pf(__expf(x));
        delta[(size_t)(t0 + tt) * DINNER + d] = sp;
    }
}

// ---------------------------------------------------------------------------
// Scan phase 1: lane = channel d, h[16]+A2[16] in registers, no shuffles.
// dt/u direct coalesced global; B via LDS broadcast. Per chunk: h-from-zero
// and a-product (via exp2(A2 * sum(dt))).
// ---------------------------------------------------------------------------
__global__ __launch_bounds__(256) void scan_phase1(
    const float* __restrict__ u, const float* __restrict__ delta,
    const float* __restrict__ x_dbl, const float* __restrict__ A_log,
    float* __restrict__ aprod, float* __restrict__ hacc)
{
    __shared__ float sB[TC][16];

    const int tid = threadIdx.x;
    const int d = blockIdx.x * 256 + tid;
    const int ch = blockIdx.y;
    const int t0 = ch * TC;

    // A2[n] = -exp(A_log[d][n]) * log2(e)
    float A2[16];
#pragma unroll
    for (int j = 0; j < 4; ++j) {
        const float4 a4 = *(const float4*)(A_log + (size_t)d * DSTATE + j * 4);
        A2[4 * j + 0] = -__expf(a4.x) * LOG2E;
        A2[4 * j + 1] = -__expf(a4.y) * LOG2E;
        A2[4 * j + 2] = -__expf(a4.z) * LOG2E;
        A2[4 * j + 3] = -__expf(a4.w) * LOG2E;
    }

    for (int i = tid; i < TC * 16; i += 256) {
        const int tt = i >> 4, q = i & 15;
        sB[tt][q] = x_dbl[(size_t)(t0 + tt) * NXDBL + DTRANK + q];
    }
    __syncthreads();

    float h[16];
#pragma unroll
    for (int n = 0; n < 16; ++n) h[n] = 0.f;
    float S = 0.f;

    for (int tt = 0; tt < TC; ++tt) {
        const float dt = delta[(size_t)(t0 + tt) * DINNER + d];
        const float uu = u[(size_t)(t0 + tt) * DINNER + d];
        const float du = dt * uu;
        S += dt;
        float4 b[4];
#pragma unroll
        for (int j = 0; j < 4; ++j) b[j] = *(const float4*)&sB[tt][j * 4];
        const float* bp = (const float*)b;
#pragma unroll
        for (int n = 0; n < 16; ++n) {
            const float a = exp2f(dt * A2[n]);
            h[n] = fmaf(a, h[n], du * bp[n]);
        }
    }

    const size_t base = ((size_t)ch * DINNER + d) * DSTATE;
#pragma unroll
    for (int j = 0; j < 4; ++j) {
        float4 av, hv;
        av.x = exp2f(S * A2[4 * j + 0]);
        av.y = exp2f(S * A2[4 * j + 1]);
        av.z = exp2f(S * A2[4 * j + 2]);
        av.w = exp2f(S * A2[4 * j + 3]);
        hv.x = h[4 * j + 0]; hv.y = h[4 * j + 1];
        hv.z = h[4 * j + 2]; hv.w = h[4 * j + 3];
        *(float4*)(aprod + base + j * 4) = av;
        *(float4*)(hacc + base + j * 4) = hv;
    }
}

// ---------------------------------------------------------------------------
// Phase 2: exclusive scan over chunk summaries (hacc -> hinit in place).
// ---------------------------------------------------------------------------
__global__ __launch_bounds__(256) void scan_phase2(
    const float* __restrict__ aprod, float* __restrict__ hacc)
{
    const int i = blockIdx.x * 256 + threadIdx.x;
    float h0 = 0.f;
#pragma unroll 4
    for (int c = 0; c < CCH; ++c) {
        const size_t idx = (size_t)c * DINNER * DSTATE + i;
        const float a  = aprod[idx];
        const float hc = hacc[idx];
        hacc[idx] = h0;
        h0 = fmaf(a, h0, hc);
    }
}

// ---------------------------------------------------------------------------
// Phase 3: lane = channel d, replay from corrected init, y in-register,
// gate, write g. No shuffles, no LDS for dt/u/z.
// ---------------------------------------------------------------------------
__global__ __launch_bounds__(256) void scan_phase3(
    const float* __restrict__ xz, const float* __restrict__ u,
    const float* __restrict__ delta, const float* __restrict__ x_dbl,
    const float* __restrict__ A_log, const float* __restrict__ D_param,
    const float* __restrict__ hinit, float* __restrict__ g)
{
    __shared__ float sBC[TC][32];   // [t][0..15]=B, [16..31]=C

    const int tid = threadIdx.x;
    const int d = blockIdx.x * 256 + tid;
    const int ch = blockIdx.y;
    const int t0 = ch * TC;

    float A2[16];
#pragma unroll
    for (int j = 0; j < 4; ++j) {
        const float4 a4 = *(const float4*)(A_log + (size_t)d * DSTATE + j * 4);
        A2[4 * j + 0] = -__expf(a4.x) * LOG2E;
        A2[4 * j + 1] = -__expf(a4.y) * LOG2E;
        A2[4 * j + 2] = -__expf(a4.z) * LOG2E;
        A2[4 * j + 3] = -__expf(a4.w) * LOG2E;
    }
    const float Dp = D_param[d];

    float h[16];
    {
        const size_t base = ((size_t)ch * DINNER + d) * DSTATE;
#pragma unroll
        for (int j = 0; j < 4; ++j) {
            const float4 hv = *(const float4*)(hinit + base + j * 4);
            h[4 * j + 0] = hv.x; h[4 * j + 1] = hv.y;
            h[4 * j + 2] = hv.z; h[4 * j + 3] = hv.w;
        }
    }

    for (int i = tid; i < TC * 32; i += 256) {
        const int tt = i >> 5, q = i & 31;
        sBC[tt][q] = x_dbl[(size_t)(t0 + tt) * NXDBL + DTRANK + q];
    }
    __syncthreads();

    for (int tt = 0; tt < TC; ++tt) {
        const float dt = delta[(size_t)(t0 + tt) * DINNER + d];
        const float uu = u[(size_t)(t0 + tt) * DINNER + d];
        const float z  = xz[(size_t)(t0 + tt) * (2 * DINNER) + DINNER + d];
        const float du = dt * uu;
        float4 b[4], c[4];
#pragma unroll
        for (int j = 0; j < 4; ++j) {
            b[j] = *(const float4*)&sBC[tt][j * 4];
            c[j] = *(const float4*)&sBC[tt][16 + j * 4];
        }
        const float* bp = (const float*)b;
        const float* cp = (const float*)c;
        float y = Dp * uu;
#pragma unroll
        for (int n = 0; n < 16; ++n) {
            const float a = exp2f(dt * A2[n]);
            h[n] = fmaf(a, h[n], du * bp[n]);
            y = fmaf(h[n], cp[n], y);
        }
        const float gate = z / (1.f + __expf(-z));
        g[(size_t)(t0 + tt) * DINNER + d] = y * gate;
    }
}

// ---------------------------------------------------------------------------
extern "C" void kernel_launch(void* const* d_in, const int* in_sizes, int n_in,
                              void* d_out, int out_size, void* d_ws, size_t ws_size,
                              hipStream_t stream)
{
    const float* x      = (const float*)d_in[0];
    const float* W_in   = (const float*)d_in[1];
    const float* conv_w = (const float*)d_in[2];
    const float* conv_b = (const float*)d_in[3];
    const float* W_x    = (const float*)d_in[4];
    const float* W_dt   = (const float*)d_in[5];
    const float* b_dt   = (const float*)d_in[6];
    const float* A_log  = (const float*)d_in[7];
    const float* D_par  = (const float*)d_in[8];
    const float* W_out  = (const float*)d_in[9];
    float* out = (float*)d_out;

    float* ws    = (float*)d_ws;
    float* xz    = ws;                                    // 2048*4096 f32
    float* u     = xz + (size_t)L_SEQ * 2 * DINNER;       // 2048*2048 f32
    float* x_dbl = u + (size_t)L_SEQ * DINNER;            // 2048*96 f32
    float* delta = x_dbl + (size_t)L_SEQ * NXDBL;         // 2048*2048 f32
    float* aprod = delta + (size_t)L_SEQ * DINNER;        // 64*2048*16 f32
    float* hacc  = aprod + (size_t)CCH * DINNER * DSTATE; // 64*2048*16 f32
    unsigned short* WinT_hi  = (unsigned short*)(hacc + (size_t)CCH * DINNER * DSTATE);
    unsigned short* WinT_lo  = WinT_hi + (size_t)(2 * DINNER) * DMODEL;   // [4096][1024]
    unsigned short* WoutT_hi = WinT_lo + (size_t)(2 * DINNER) * DMODEL;
    unsigned short* WoutT_lo = WoutT_hi + (size_t)DMODEL * DINNER;        // [1024][2048]
    unsigned short* WxT_hi   = WoutT_lo + (size_t)DMODEL * DINNER;        // [96][2048]
    unsigned short* WxT_lo   = WxT_hi + (size_t)NXDBL * DINNER;
    // part aliases WinT (12.6 MB < 16.8 MB): GEMM1 consumed WinT before GEMM3
    // writes part, and transposes re-run every call (stream-ordered, safe).
    float* part = (float*)WinT_hi;                        // [KS3][2048][96]
    float* g = u;  // alias: phase-3 lane reads u[t][d] then writes g[t][d]
                   // same thread, same iteration -> safe.

    // 0) weight prep: transpose + bf16 hi/lo split
    transpose_split<<<dim3(2 * DINNER / 32, DMODEL / 32), 256, 0, stream>>>(W_in, WinT_hi, WinT_lo, DMODEL, 2 * DINNER);
    transpose_split<<<dim3(DMODEL / 32, DINNER / 32), 256, 0, stream>>>(W_out, WoutT_hi, WoutT_lo, DINNER, DMODEL);
    transpose_split<<<dim3(NXDBL / 32, DINNER / 32), 256, 0, stream>>>(W_x, WxT_hi, WxT_lo, DINNER, NXDBL);

    // 1) xz = x @ W_in   (2048x1024 @ 1024x4096) -- bf16x3 MFMA
    gemm_bf16x3<4><<<dim3(2 * DINNER / 128, L_SEQ / 128), 256, 0, stream>>>(
        x, WinT_hi, WinT_lo, xz, L_SEQ, 2 * DINNER, DMODEL);
    // 2) u = silu(conv(xc))
    conv_silu_kernel<<<dim3(DINNER / 256, L_SEQ), 256, 0, stream>>>(xz, conv_w, conv_b, u);
    // 3) x_dbl = u @ W_x   (2048x2048 @ 2048x96) -- split-K bf16x3 MFMA
    gemm3_splitk<<<dim3(KS3, L_SEQ / 64), 256, 0, stream>>>(u, WxT_hi, WxT_lo, part);
    reduce_part<<<dim3(L_SEQ * NXDBL / 4 / 256), 256, 0, stream>>>(part, x_dbl);
    // 4) delta = softplus(dlt @ W_dt + b_dt)
    delta_kernel<<<dim3(DINNER / 256, L_SEQ / 16), 256, 0, stream>>>(x_dbl, W_dt, b_dt, delta);
    // 5) parallel scan (lane-per-d, register state)
    scan_phase1<<<dim3(DINNER / 256, CCH), 256, 0, stream>>>(u, delta, x_dbl, A_log, aprod, hacc);
    scan_phase2<<<dim3(DINNER * DSTATE / 256), 256, 0, stream>>>(aprod, hacc);
    scan_phase3<<<dim3(DINNER / 256, CCH), 256, 0, stream>>>(xz, u, delta, x_dbl, A_log, D_par, hacc, g);
    // 6) out = g @ W_out   (2048x2048 @ 2048x1024) -- bf16x3 MFMA, BM=64
    gemm_bf16x3<2><<<dim3(DMODEL / 128, L_SEQ / 64), 256, 0, stream>>>(
        g, WoutT_hi, WoutT_lo, out, L_SEQ, DMODEL, DINNER);
}

// Round 6
// 346.577 us; speedup vs baseline: 3.3875x; 1.0395x over previous
//
#include <hip/hip_runtime.h>
#include <hip/hip_bf16.h>
#include <math.h>

// Problem constants
#define L_SEQ   2048
#define DMODEL  1024
#define DINNER  2048
#define DSTATE  16
#define DCONV   4
#define DTRANK  64
#define NXDBL   96   // DT_RANK + 2*D_STATE

#define CCH 64   // time chunks for parallel scan
#define TC  32   // timesteps per chunk (CCH*TC == L_SEQ)
#define KS3 16   // split-K factor for GEMM3

#define LOG2E 1.44269504088896340736f

typedef __bf16 bf16x8 __attribute__((ext_vector_type(8)));
typedef float f32x4 __attribute__((ext_vector_type(4)));
typedef unsigned short ushort4v __attribute__((ext_vector_type(4)));
typedef unsigned short ushort8v __attribute__((ext_vector_type(8)));

// fp32 -> bf16 (RNE) via bit ops; hi/lo split for bf16x3 GEMM.
__device__ __forceinline__ unsigned short f2bh(float f) {
    unsigned u = __float_as_uint(f);
    u += 0x7fffu + ((u >> 16) & 1u);
    return (unsigned short)(u >> 16);
}
__device__ __forceinline__ float bh2f(unsigned short h) {
    return __uint_as_float(((unsigned)h) << 16);
}
// 16B-granule XOR swizzle for unpadded [row][32-ushort] LDS tiles:
// logical granule g of row r lives at physical granule g ^ ((r>>1)&3).
// Fragment reads (16 lanes = 16 rows, fixed granule) then hit all 32 banks
// 2-way (free); staging writes are bank-uniform.
__device__ __forceinline__ int swz8(int row, int g) {
    return (g ^ ((row >> 1) & 3)) * 8;
}

// ---------------------------------------------------------------------------
// Weight prep: W[K][N] fp32 -> WT_hi/WT_lo [N][K] bf16 (transpose + split).
// ---------------------------------------------------------------------------
__global__ __launch_bounds__(256) void transpose_split(
    const float* __restrict__ W, unsigned short* __restrict__ WT_hi,
    unsigned short* __restrict__ WT_lo, int K, int N)
{
    __shared__ float tile[32][33];
    const int tid = threadIdx.x;
    const int k0 = blockIdx.y * 32, n0 = blockIdx.x * 32;
    const int r = tid >> 3, c4 = (tid & 7) * 4;

    const float4 w4 = *(const float4*)(W + (size_t)(k0 + r) * N + n0 + c4);
    tile[r][c4 + 0] = w4.x;
    tile[r][c4 + 1] = w4.y;
    tile[r][c4 + 2] = w4.z;
    tile[r][c4 + 3] = w4.w;
    __syncthreads();

    ushort4v h, l;
#pragma unroll
    for (int j = 0; j < 4; ++j) {
        const float v = tile[c4 + j][r];
        const unsigned short hh = f2bh(v);
        h[j] = hh;
        l[j] = f2bh(v - bh2f(hh));
    }
    *(ushort4v*)(WT_hi + (size_t)(n0 + r) * K + k0 + c4) = h;
    *(ushort4v*)(WT_lo + (size_t)(n0 + r) * K + k0 + c4) = l;
}

// ---------------------------------------------------------------------------
// Elementwise fp32 -> bf16 hi/lo split (for x).
// ---------------------------------------------------------------------------
__global__ __launch_bounds__(256) void split_hi_lo(
    const float* __restrict__ in, unsigned short* __restrict__ hi,
    unsigned short* __restrict__ lo)
{
    const size_t i = ((size_t)blockIdx.x * 256 + threadIdx.x) * 4;
    const float4 v4 = *(const float4*)(in + i);
    const float v[4] = {v4.x, v4.y, v4.z, v4.w};
    ushort4v h, l;
#pragma unroll
    for (int j = 0; j < 4; ++j) {
        const unsigned short hh = f2bh(v[j]);
        h[j] = hh;
        l[j] = f2bh(v[j] - bh2f(hh));
    }
    *(ushort4v*)(hi + i) = h;
    *(ushort4v*)(lo + i) = l;
}

// ---------------------------------------------------------------------------
// bf16x3 MFMA GEMM, fully pre-split operands:
// C[M,N] = A[M,K] @ B[K,N], A as AH/AL [M][K] bf16, B as BH/BL [N][K] bf16.
// Block tile: BM x 128, BM = WMI*32, BK=32. 256 threads = 4 waves (2x2).
// LDS staging is pure 16B copies into swizzled unpadded tiles.
// ---------------------------------------------------------------------------
template <int WMI>
__global__ __launch_bounds__(256) void gemm_pre(
    const unsigned short* __restrict__ AH, const unsigned short* __restrict__ AL,
    const unsigned short* __restrict__ BH, const unsigned short* __restrict__ BL,
    float* __restrict__ C, int M, int N, int K)
{
    constexpr int BM = WMI * 32;
    __shared__ __align__(16) unsigned short AsH[BM * 32];
    __shared__ __align__(16) unsigned short AsL[BM * 32];
    __shared__ __align__(16) unsigned short BsH[128 * 32];
    __shared__ __align__(16) unsigned short BsL[128 * 32];

    const int tid = threadIdx.x;
    const int lane = tid & 63;
    const int wave = tid >> 6;
    const int wm = wave >> 1, wn = wave & 1;
    const int bm = blockIdx.y * BM;
    const int bn = blockIdx.x * 128;
    const int l16 = lane & 15;
    const int kq = lane >> 4;

    f32x4 acc[WMI][4];
#pragma unroll
    for (int mi = 0; mi < WMI; ++mi)
#pragma unroll
        for (int ni = 0; ni < 4; ++ni) acc[mi][ni] = {0.f, 0.f, 0.f, 0.f};

    for (int k0 = 0; k0 < K; k0 += 32) {
        __syncthreads();
        // --- stage A (BM*4 granules, hi+lo)
#pragma unroll
        for (int i = 0; i < (BM * 4) / 256; ++i) {
            const int c = tid + 256 * i;
            const int row = c >> 2, g = c & 3;
            const int dst = row * 32 + swz8(row, g);
            const size_t src = (size_t)(bm + row) * K + k0 + g * 8;
            *(ushort8v*)&AsH[dst] = *(const ushort8v*)(AH + src);
            *(ushort8v*)&AsL[dst] = *(const ushort8v*)(AL + src);
        }
        // --- stage B (512 granules, hi+lo)
#pragma unroll
        for (int i = 0; i < 2; ++i) {
            const int c = tid + 256 * i;
            const int row = c >> 2, g = c & 3;
            const int dst = row * 32 + swz8(row, g);
            const size_t src = (size_t)(bn + row) * K + k0 + g * 8;
            *(ushort8v*)&BsH[dst] = *(const ushort8v*)(BH + src);
            *(ushort8v*)&BsL[dst] = *(const ushort8v*)(BL + src);
        }
        __syncthreads();

        bf16x8 ah[WMI], al[WMI], bh[4], bl[4];
#pragma unroll
        for (int mi = 0; mi < WMI; ++mi) {
            const int r = (wm * WMI + mi) * 16 + l16;
            const int off = r * 32 + swz8(r, kq);
            ah[mi] = *(const bf16x8*)&AsH[off];
            al[mi] = *(const bf16x8*)&AsL[off];
        }
#pragma unroll
        for (int ni = 0; ni < 4; ++ni) {
            const int r = wn * 64 + ni * 16 + l16;
            const int off = r * 32 + swz8(r, kq);
            bh[ni] = *(const bf16x8*)&BsH[off];
            bl[ni] = *(const bf16x8*)&BsL[off];
        }
#pragma unroll
        for (int mi = 0; mi < WMI; ++mi)
#pragma unroll
            for (int ni = 0; ni < 4; ++ni) {
                acc[mi][ni] = __builtin_amdgcn_mfma_f32_16x16x32_bf16(ah[mi], bh[ni], acc[mi][ni], 0, 0, 0);
                acc[mi][ni] = __builtin_amdgcn_mfma_f32_16x16x32_bf16(al[mi], bh[ni], acc[mi][ni], 0, 0, 0);
                acc[mi][ni] = __builtin_amdgcn_mfma_f32_16x16x32_bf16(ah[mi], bl[ni], acc[mi][ni], 0, 0, 0);
            }
    }

    // epilogue: C/D layout col = lane&15, row = (lane>>4)*4 + reg
#pragma unroll
    for (int mi = 0; mi < WMI; ++mi)
#pragma unroll
        for (int ni = 0; ni < 4; ++ni) {
            const int col = bn + wn * 64 + ni * 16 + l16;
#pragma unroll
            for (int r = 0; r < 4; ++r) {
                const int row = bm + (wm * WMI + mi) * 16 + kq * 4 + r;
                C[(size_t)row * N + col] = acc[mi][ni][r];
            }
        }
}

// ---------------------------------------------------------------------------
// GEMM3 split-K, pre-split A (uH/uL) and B (WxT hi/lo).
// Block: 64 (m) x 96 (n) x 128 (k-chunk). Grid (KS3, M/64) = 512 blocks.
// ---------------------------------------------------------------------------
__global__ __launch_bounds__(256) void gemm3_splitk(
    const unsigned short* __restrict__ AH, const unsigned short* __restrict__ AL,
    const unsigned short* __restrict__ BH, const unsigned short* __restrict__ BL,
    float* __restrict__ part)
{
    __shared__ __align__(16) unsigned short AsH[64 * 32];
    __shared__ __align__(16) unsigned short AsL[64 * 32];
    __shared__ __align__(16) unsigned short BsH[96 * 32];
    __shared__ __align__(16) unsigned short BsL[96 * 32];

    const int tid = threadIdx.x;
    const int lane = tid & 63;
    const int wave = tid >> 6;
    const int wm = wave & 1, wn = wave >> 1;
    const int ks = blockIdx.x;
    const int bm = blockIdx.y * 64;
    const int kbase = ks * (DINNER / KS3);
    const int l16 = lane & 15;
    const int kq = lane >> 4;

    f32x4 acc[2][3];
#pragma unroll
    for (int mi = 0; mi < 2; ++mi)
#pragma unroll
        for (int ni = 0; ni < 3; ++ni) acc[mi][ni] = {0.f, 0.f, 0.f, 0.f};

    for (int k0 = 0; k0 < DINNER / KS3; k0 += 32) {
        __syncthreads();
        {
            const int c = tid;                 // 64*4 = 256 granules
            const int row = c >> 2, g = c & 3;
            const int dst = row * 32 + swz8(row, g);
            const size_t src = (size_t)(bm + row) * DINNER + kbase + k0 + g * 8;
            *(ushort8v*)&AsH[dst] = *(const ushort8v*)(AH + src);
            *(ushort8v*)&AsL[dst] = *(const ushort8v*)(AL + src);
        }
        for (int c = tid; c < 96 * 4; c += 256) {
            const int row = c >> 2, g = c & 3;
            const int dst = row * 32 + swz8(row, g);
            const size_t src = (size_t)row * DINNER + kbase + k0 + g * 8;
            *(ushort8v*)&BsH[dst] = *(const ushort8v*)(BH + src);
            *(ushort8v*)&BsL[dst] = *(const ushort8v*)(BL + src);
        }
        __syncthreads();

        bf16x8 ah[2], al[2], bh[3], bl[3];
#pragma unroll
        for (int mi = 0; mi < 2; ++mi) {
            const int r = wm * 32 + mi * 16 + l16;
            const int off = r * 32 + swz8(r, kq);
            ah[mi] = *(const bf16x8*)&AsH[off];
            al[mi] = *(const bf16x8*)&AsL[off];
        }
#pragma unroll
        for (int ni = 0; ni < 3; ++ni) {
            const int r = wn * 48 + ni * 16 + l16;
            const int off = r * 32 + swz8(r, kq);
            bh[ni] = *(const bf16x8*)&BsH[off];
            bl[ni] = *(const bf16x8*)&BsL[off];
        }
#pragma unroll
        for (int mi = 0; mi < 2; ++mi)
#pragma unroll
            for (int ni = 0; ni < 3; ++ni) {
                acc[mi][ni] = __builtin_amdgcn_mfma_f32_16x16x32_bf16(ah[mi], bh[ni], acc[mi][ni], 0, 0, 0);
                acc[mi][ni] = __builtin_amdgcn_mfma_f32_16x16x32_bf16(al[mi], bh[ni], acc[mi][ni], 0, 0, 0);
                acc[mi][ni] = __builtin_amdgcn_mfma_f32_16x16x32_bf16(ah[mi], bl[ni], acc[mi][ni], 0, 0, 0);
            }
    }

#pragma unroll
    for (int mi = 0; mi < 2; ++mi)
#pragma unroll
        for (int ni = 0; ni < 3; ++ni) {
            const int col = wn * 48 + ni * 16 + l16;
#pragma unroll
            for (int r = 0; r < 4; ++r) {
                const int row = bm + wm * 32 + mi * 16 + kq * 4 + r;
                part[((size_t)ks * L_SEQ + row) * NXDBL + col] = acc[mi][ni][r];
            }
        }
}

// ---------------------------------------------------------------------------
// Sum the KS3 partials into x_dbl.
// ---------------------------------------------------------------------------
__global__ __launch_bounds__(256) void reduce_part(
    const float* __restrict__ part, float* __restrict__ x_dbl)
{
    const size_t i = ((size_t)blockIdx.x * 256 + threadIdx.x) * 4;
    float4 s = make_float4(0.f, 0.f, 0.f, 0.f);
#pragma unroll 4
    for (int ks = 0; ks < KS3; ++ks) {
        const float4 p = *(const float4*)(part + (size_t)ks * L_SEQ * NXDBL + i);
        s.x += p.x; s.y += p.y; s.z += p.z; s.w += p.w;
    }
    *(float4*)(x_dbl + i) = s;
}

// ---------------------------------------------------------------------------
// Depthwise causal conv (D_CONV=4) + SiLU; emits u fp32 + uH/uL bf16 split.
// ---------------------------------------------------------------------------
__global__ __launch_bounds__(256) void conv_silu_kernel(
    const float* __restrict__ xz, const float* __restrict__ conv_w,
    const float* __restrict__ conv_b, float* __restrict__ u,
    unsigned short* __restrict__ uH, unsigned short* __restrict__ uL)
{
    const int d = blockIdx.x * 256 + threadIdx.x;
    const int t = blockIdx.y;
    float acc = conv_b[d];
#pragma unroll
    for (int j = 0; j < DCONV; ++j) {
        const int tt = t - (DCONV - 1) + j;
        if (tt >= 0) acc = fmaf(xz[(size_t)tt * (2 * DINNER) + d], conv_w[d * DCONV + j], acc);
    }
    const float s = acc / (1.f + __expf(-acc));
    const size_t idx = (size_t)t * DINNER + d;
    u[idx] = s;
    const unsigned short hh = f2bh(s);
    uH[idx] = hh;
    uL[idx] = f2bh(s - bh2f(hh));
}

// ---------------------------------------------------------------------------
// delta = softplus(dlt @ W_dt + b_dt)
// ---------------------------------------------------------------------------
__global__ __launch_bounds__(256) void delta_kernel(
    const float* __restrict__ x_dbl, const float* __restrict__ W_dt,
    const float* __restrict__ b_dt, float* __restrict__ delta)
{
    __shared__ float dl[16][64];
    const int tid = threadIdx.x;
    const int d = blockIdx.x * 256 + tid;
    const int t0 = blockIdx.y * 16;

    for (int i = tid; i < 16 * 64; i += 256) {
        const int tt = i >> 6, k = i & 63;
        dl[tt][k] = x_dbl[(size_t)(t0 + tt) * NXDBL + k];
    }
    __syncthreads();

    const float bb = b_dt[d];
    float acc[16];
#pragma unroll
    for (int tt = 0; tt < 16; ++tt) acc[tt] = bb;

    for (int k = 0; k < 64; ++k) {
        const float w = W_dt[(size_t)k * DINNER + d];
#pragma unroll
        for (int tt = 0; tt < 16; ++tt) acc[tt] = fmaf(dl[tt][k], w, acc[tt]);
    }
#pragma unroll
    for (int tt = 0; tt < 16; ++tt) {
        const float x = acc[tt];
        const float sp = (x > 20.f) ? x : log1pf(__expf(x));
        delta[(size_t)(t0 + tt) * DINNER + d] = sp;
    }
}

// ---------------------------------------------------------------------------
// Scan phase 1: lane = channel d, h[16]+A2[16] in registers.
// ---------------------------------------------------------------------------
__global__ __launch_bounds__(256) void scan_phase1(
    const float* __restrict__ u, const float* __restrict__ delta,
    const float* __restrict__ x_dbl, const float* __restrict__ A_log,
    float* __restrict__ aprod, float* __restrict__ hacc)
{
    __shared__ float sB[TC][16];

    const int tid = threadIdx.x;
    const int d = blockIdx.x * 256 + tid;
    const int ch = blockIdx.y;
    const int t0 = ch * TC;

    float A2[16];
#pragma unroll
    for (int j = 0; j < 4; ++j) {
        const float4 a4 = *(const float4*)(A_log + (size_t)d * DSTATE + j * 4);
        A2[4 * j + 0] = -__expf(a4.x) * LOG2E;
        A2[4 * j + 1] = -__expf(a4.y) * LOG2E;
        A2[4 * j + 2] = -__expf(a4.z) * LOG2E;
        A2[4 * j + 3] = -__expf(a4.w) * LOG2E;
    }

    for (int i = tid; i < TC * 16; i += 256) {
        const int tt = i >> 4, q = i & 15;
        sB[tt][q] = x_dbl[(size_t)(t0 + tt) * NXDBL + DTRANK + q];
    }
    __syncthreads();

    float h[16];
#pragma unroll
    for (int n = 0; n < 16; ++n) h[n] = 0.f;
    float S = 0.f;

    for (int tt = 0; tt < TC; ++tt) {
        const float dt = delta[(size_t)(t0 + tt) * DINNER + d];
        const float uu = u[(size_t)(t0 + tt) * DINNER + d];
        const float du = dt * uu;
        S += dt;
        float4 b[4];
#pragma unroll
        for (int j = 0; j < 4; ++j) b[j] = *(const float4*)&sB[tt][j * 4];
        const float* bp = (const float*)b;
#pragma unroll
        for (int n = 0; n < 16; ++n) {
            const float a = exp2f(dt * A2[n]);
            h[n] = fmaf(a, h[n], du * bp[n]);
        }
    }

    const size_t base = ((size_t)ch * DINNER + d) * DSTATE;
#pragma unroll
    for (int j = 0; j < 4; ++j) {
        float4 av, hv;
        av.x = exp2f(S * A2[4 * j + 0]);
        av.y = exp2f(S * A2[4 * j + 1]);
        av.z = exp2f(S * A2[4 * j + 2]);
        av.w = exp2f(S * A2[4 * j + 3]);
        hv.x = h[4 * j + 0]; hv.y = h[4 * j + 1];
        hv.z = h[4 * j + 2]; hv.w = h[4 * j + 3];
        *(float4*)(aprod + base + j * 4) = av;
        *(float4*)(hacc + base + j * 4) = hv;
    }
}

// ---------------------------------------------------------------------------
// Phase 2: exclusive scan over chunk summaries (hacc -> hinit in place).
// ---------------------------------------------------------------------------
__global__ __launch_bounds__(256) void scan_phase2(
    const float* __restrict__ aprod, float* __restrict__ hacc)
{
    const int i = blockIdx.x * 256 + threadIdx.x;
    float h0 = 0.f;
#pragma unroll 4
    for (int c = 0; c < CCH; ++c) {
        const size_t idx = (size_t)c * DINNER * DSTATE + i;
        const float a  = aprod[idx];
        const float hc = hacc[idx];
        hacc[idx] = h0;
        h0 = fmaf(a, h0, hc);
    }
}

// ---------------------------------------------------------------------------
// Phase 3: lane = channel d, replay from corrected init, gate,
// write g directly as bf16 hi/lo (feeds GEMM6 with no further split).
// ---------------------------------------------------------------------------
__global__ __launch_bounds__(256) void scan_phase3(
    const float* __restrict__ xz, const float* __restrict__ u,
    const float* __restrict__ delta, const float* __restrict__ x_dbl,
    const float* __restrict__ A_log, const float* __restrict__ D_param,
    const float* __restrict__ hinit,
    unsigned short* __restrict__ gH, unsigned short* __restrict__ gL)
{
    __shared__ float sBC[TC][32];   // [t][0..15]=B, [16..31]=C

    const int tid = threadIdx.x;
    const int d = blockIdx.x * 256 + tid;
    const int ch = blockIdx.y;
    const int t0 = ch * TC;

    float A2[16];
#pragma unroll
    for (int j = 0; j < 4; ++j) {
        const float4 a4 = *(const float4*)(A_log + (size_t)d * DSTATE + j * 4);
        A2[4 * j + 0] = -__expf(a4.x) * LOG2E;
        A2[4 * j + 1] = -__expf(a4.y) * LOG2E;
        A2[4 * j + 2] = -__expf(a4.z) * LOG2E;
        A2[4 * j + 3] = -__expf(a4.w) * LOG2E;
    }
    const float Dp = D_param[d];

    float h[16];
    {
        const size_t base = ((size_t)ch * DINNER + d) * DSTATE;
#pragma unroll
        for (int j = 0; j < 4; ++j) {
            const float4 hv = *(const float4*)(hinit + base + j * 4);
            h[4 * j + 0] = hv.x; h[4 * j + 1] = hv.y;
            h[4 * j + 2] = hv.z; h[4 * j + 3] = hv.w;
        }
    }

    for (int i = tid; i < TC * 32; i += 256) {
        const int tt = i >> 5, q = i & 31;
        sBC[tt][q] = x_dbl[(size_t)(t0 + tt) * NXDBL + DTRANK + q];
    }
    __syncthreads();

    for (int tt = 0; tt < TC; ++tt) {
        const float dt = delta[(size_t)(t0 + tt) * DINNER + d];
        const float uu = u[(size_t)(t0 + tt) * DINNER + d];
        const float z  = xz[(size_t)(t0 + tt) * (2 * DINNER) + DINNER + d];
        const float du = dt * uu;
        float4 b[4], c[4];
#pragma unroll
        for (int j = 0; j < 4; ++j) {
            b[j] = *(const float4*)&sBC[tt][j * 4];
            c[j] = *(const float4*)&sBC[tt][16 + j * 4];
        }
        const float* bp = (const float*)b;
        const float* cp = (const float*)c;
        float y = Dp * uu;
#pragma unroll
        for (int n = 0; n < 16; ++n) {
            const float a = exp2f(dt * A2[n]);
            h[n] = fmaf(a, h[n], du * bp[n]);
            y = fmaf(h[n], cp[n], y);
        }
        const float gate = z / (1.f + __expf(-z));
        const float gv = y * gate;
        const size_t idx = (size_t)(t0 + tt) * DINNER + d;
        const unsigned short hh = f2bh(gv);
        gH[idx] = hh;
        gL[idx] = f2bh(gv - bh2f(hh));
    }
}

// ---------------------------------------------------------------------------
extern "C" void kernel_launch(void* const* d_in, const int* in_sizes, int n_in,
                              void* d_out, int out_size, void* d_ws, size_t ws_size,
                              hipStream_t stream)
{
    const float* x      = (const float*)d_in[0];
    const float* W_in   = (const float*)d_in[1];
    const float* conv_w = (const float*)d_in[2];
    const float* conv_b = (const float*)d_in[3];
    const float* W_x    = (const float*)d_in[4];
    const float* W_dt   = (const float*)d_in[5];
    const float* b_dt   = (const float*)d_in[6];
    const float* A_log  = (const float*)d_in[7];
    const float* D_par  = (const float*)d_in[8];
    const float* W_out  = (const float*)d_in[9];
    float* out = (float*)d_out;

    float* ws    = (float*)d_ws;
    float* xz    = ws;                                    // 2048*4096 f32
    float* u     = xz + (size_t)L_SEQ * 2 * DINNER;       // 2048*2048 f32
    float* x_dbl = u + (size_t)L_SEQ * DINNER;            // 2048*96 f32
    float* delta = x_dbl + (size_t)L_SEQ * NXDBL;         // 2048*2048 f32
    float* aprod = delta + (size_t)L_SEQ * DINNER;        // 64*2048*16 f32
    float* hacc  = aprod + (size_t)CCH * DINNER * DSTATE; // 64*2048*16 f32
    unsigned short* WinT_hi  = (unsigned short*)(hacc + (size_t)CCH * DINNER * DSTATE);
    unsigned short* WinT_lo  = WinT_hi + (size_t)(2 * DINNER) * DMODEL;   // [4096][1024]
    unsigned short* WoutT_hi = WinT_lo + (size_t)(2 * DINNER) * DMODEL;
    unsigned short* WoutT_lo = WoutT_hi + (size_t)DMODEL * DINNER;        // [1024][2048]
    unsigned short* WxT_hi   = WoutT_lo + (size_t)DMODEL * DINNER;        // [96][2048]
    unsigned short* WxT_lo   = WxT_hi + (size_t)NXDBL * DINNER;

    // Aliases (all verified against launch order):
    // xH/xL <- delta buffer: consumed by GEMM1 (step 1), delta written step 4.
    unsigned short* xH = (unsigned short*)delta;          // [2048][1024]
    unsigned short* xL = xH + (size_t)L_SEQ * DMODEL;
    // uH/uL <- aprod+hacc: written by conv (2), read by gemm3 (3); aprod/hacc
    // written in phase1 (5).
    unsigned short* uH = (unsigned short*)aprod;          // [2048][2048]
    unsigned short* uL = uH + (size_t)L_SEQ * DINNER;
    // part <- WinT region (12.6 MB <= 16 MB): GEMM1 consumed WinT first.
    float* part = (float*)WinT_hi;                        // [KS3][2048][96]
    // gH/gL <- WinT region too (16 MB exactly): part consumed by reduce (3b),
    // gH/gL written in phase3 (5c), read by GEMM6 (6).
    unsigned short* gH = WinT_hi;                         // [2048][2048]
    unsigned short* gL = gH + (size_t)L_SEQ * DINNER;

    // 0) weight prep + x split
    transpose_split<<<dim3(2 * DINNER / 32, DMODEL / 32), 256, 0, stream>>>(W_in, WinT_hi, WinT_lo, DMODEL, 2 * DINNER);
    transpose_split<<<dim3(DMODEL / 32, DINNER / 32), 256, 0, stream>>>(W_out, WoutT_hi, WoutT_lo, DINNER, DMODEL);
    transpose_split<<<dim3(NXDBL / 32, DINNER / 32), 256, 0, stream>>>(W_x, WxT_hi, WxT_lo, DINNER, NXDBL);
    split_hi_lo<<<dim3(L_SEQ * DMODEL / 4 / 256), 256, 0, stream>>>(x, xH, xL);

    // 1) xz = x @ W_in   (2048x1024 @ 1024x4096)
    gemm_pre<4><<<dim3(2 * DINNER / 128, L_SEQ / 128), 256, 0, stream>>>(
        xH, xL, WinT_hi, WinT_lo, xz, L_SEQ, 2 * DINNER, DMODEL);
    // 2) u = silu(conv(xc)) (+ hi/lo split)
    conv_silu_kernel<<<dim3(DINNER / 256, L_SEQ), 256, 0, stream>>>(xz, conv_w, conv_b, u, uH, uL);
    // 3) x_dbl = u @ W_x   (split-K)
    gemm3_splitk<<<dim3(KS3, L_SEQ / 64), 256, 0, stream>>>(uH, uL, WxT_hi, WxT_lo, part);
    reduce_part<<<dim3(L_SEQ * NXDBL / 4 / 256), 256, 0, stream>>>(part, x_dbl);
    // 4) delta = softplus(dlt @ W_dt + b_dt)   (overwrites xH/xL - safe)
    delta_kernel<<<dim3(DINNER / 256, L_SEQ / 16), 256, 0, stream>>>(x_dbl, W_dt, b_dt, delta);
    // 5) parallel scan (phase1 overwrites uH/uL - safe)
    scan_phase1<<<dim3(DINNER / 256, CCH), 256, 0, stream>>>(u, delta, x_dbl, A_log, aprod, hacc);
    scan_phase2<<<dim3(DINNER * DSTATE / 256), 256, 0, stream>>>(aprod, hacc);
    scan_phase3<<<dim3(DINNER / 256, CCH), 256, 0, stream>>>(xz, u, delta, x_dbl, A_log, D_par, hacc, gH, gL);
    // 6) out = g @ W_out   (2048x2048 @ 2048x1024)
    gemm_pre<2><<<dim3(DMODEL / 128, L_SEQ / 64), 256, 0, stream>>>(
        gH, gL, WoutT_hi, WoutT_lo, out, L_SEQ, DMODEL, DINNER);
}

// Round 8
// 324.267 us; speedup vs baseline: 3.6205x; 1.0688x over previous
//
#include <hip/hip_runtime.h>
#include <hip/hip_bf16.h>
#include <math.h>

// Problem constants
#define L_SEQ   2048
#define DMODEL  1024
#define DINNER  2048
#define DSTATE  16
#define DCONV   4
#define DTRANK  64
#define NXDBL   96   // DT_RANK + 2*D_STATE

#define CCH 64   // time chunks for parallel scan
#define TC  32   // timesteps per chunk (CCH*TC == L_SEQ)
#define KS3 16   // split-K factor for GEMM3

#define LOG2E 1.44269504088896340736f

typedef _Float16 half8v __attribute__((ext_vector_type(8)));
typedef _Float16 half4v __attribute__((ext_vector_type(4)));
typedef float f32x4 __attribute__((ext_vector_type(4)));

// fp16x2 split: a = (fp16)a + (fp16)(a - (float)(fp16)a), ~22 mantissa bits.
// GEMM computes (ah+al)@bh with 2 MFMAs; error = a@(b-bh) ~ 2^-11 rel of B.
struct H2 { _Float16 h, l; };
__device__ __forceinline__ H2 splitf16(float v) {
    H2 r;
    r.h = (_Float16)v;
    r.l = (_Float16)(v - (float)r.h);
    return r;
}

// 16B-granule XOR swizzle for unpadded [row][32-half] LDS tiles:
// logical granule g of row r lives at physical granule g ^ ((r>>1)&3).
// Fragment reads (16 lanes = 16 rows, fixed granule) hit all 32 banks 2-way
// (free per m136); staging writes are bank-uniform.
__device__ __forceinline__ int swz8(int row, int g) {
    return (g ^ ((row >> 1) & 3)) * 8;
}

// ---------------------------------------------------------------------------
// Weight prep: W[K][N] fp32 -> WT [N][K] fp16 (transpose + single rounding).
// ---------------------------------------------------------------------------
__global__ __launch_bounds__(256) void transpose_f16(
    const float* __restrict__ W, _Float16* __restrict__ WT, int K, int N)
{
    __shared__ float tile[32][33];
    const int tid = threadIdx.x;
    const int k0 = blockIdx.y * 32, n0 = blockIdx.x * 32;
    const int r = tid >> 3, c4 = (tid & 7) * 4;

    const float4 w4 = *(const float4*)(W + (size_t)(k0 + r) * N + n0 + c4);
    tile[r][c4 + 0] = w4.x;
    tile[r][c4 + 1] = w4.y;
    tile[r][c4 + 2] = w4.z;
    tile[r][c4 + 3] = w4.w;
    __syncthreads();

    half4v h;
#pragma unroll
    for (int j = 0; j < 4; ++j) h[j] = (_Float16)tile[c4 + j][r];
    *(half4v*)(WT + (size_t)(n0 + r) * K + k0 + c4) = h;
}

// ---------------------------------------------------------------------------
// Elementwise fp32 -> fp16 hi/lo split (for x).
// ---------------------------------------------------------------------------
__global__ __launch_bounds__(256) void split_hi_lo(
    const float* __restrict__ in, _Float16* __restrict__ hi,
    _Float16* __restrict__ lo)
{
    const size_t i = ((size_t)blockIdx.x * 256 + threadIdx.x) * 4;
    const float4 v4 = *(const float4*)(in + i);
    const float v[4] = {v4.x, v4.y, v4.z, v4.w};
    half4v h, l;
#pragma unroll
    for (int j = 0; j < 4; ++j) {
        const H2 s = splitf16(v[j]);
        h[j] = s.h;
        l[j] = s.l;
    }
    *(half4v*)(hi + i) = h;
    *(half4v*)(lo + i) = l;
}

// ---------------------------------------------------------------------------
// fp16x2 MFMA GEMM: C[M,N] = A[M,K] @ B[K,N], A as AH/AL [M][K] fp16,
// B as BH [N][K] fp16 (single). 2 MFMAs per tile: (ah+al)@bh.
// Block tile: BM x 128, BM = WMI*32, BK=32. 256 threads = 4 waves (2x2).
// ---------------------------------------------------------------------------
template <int WMI>
__global__ __launch_bounds__(256) void gemm_pre(
    const _Float16* __restrict__ AH, const _Float16* __restrict__ AL,
    const _Float16* __restrict__ BH, float* __restrict__ C,
    int M, int N, int K)
{
    constexpr int BM = WMI * 32;
    __shared__ __align__(16) _Float16 AsH[BM * 32];
    __shared__ __align__(16) _Float16 AsL[BM * 32];
    __shared__ __align__(16) _Float16 Bs[128 * 32];

    const int tid = threadIdx.x;
    const int lane = tid & 63;
    const int wave = tid >> 6;
    const int wm = wave >> 1, wn = wave & 1;
    const int bm = blockIdx.y * BM;
    const int bn = blockIdx.x * 128;
    const int l16 = lane & 15;
    const int kq = lane >> 4;

    f32x4 acc[WMI][4];
#pragma unroll
    for (int mi = 0; mi < WMI; ++mi)
#pragma unroll
        for (int ni = 0; ni < 4; ++ni) acc[mi][ni] = {0.f, 0.f, 0.f, 0.f};

    for (int k0 = 0; k0 < K; k0 += 32) {
        __syncthreads();
        // --- stage A (BM*4 granules of 16B, hi+lo)
#pragma unroll
        for (int i = 0; i < (BM * 4) / 256; ++i) {
            const int c = tid + 256 * i;
            const int row = c >> 2, g = c & 3;
            const int dst = row * 32 + swz8(row, g);
            const size_t src = (size_t)(bm + row) * K + k0 + g * 8;
            *(half8v*)&AsH[dst] = *(const half8v*)(AH + src);
            *(half8v*)&AsL[dst] = *(const half8v*)(AL + src);
        }
        // --- stage B (512 granules, hi only)
#pragma unroll
        for (int i = 0; i < 2; ++i) {
            const int c = tid + 256 * i;
            const int row = c >> 2, g = c & 3;
            const int dst = row * 32 + swz8(row, g);
            const size_t src = (size_t)(bn + row) * K + k0 + g * 8;
            *(half8v*)&Bs[dst] = *(const half8v*)(BH + src);
        }
        __syncthreads();

        half8v ah[WMI], al[WMI], bh[4];
#pragma unroll
        for (int mi = 0; mi < WMI; ++mi) {
            const int r = (wm * WMI + mi) * 16 + l16;
            const int off = r * 32 + swz8(r, kq);
            ah[mi] = *(const half8v*)&AsH[off];
            al[mi] = *(const half8v*)&AsL[off];
        }
#pragma unroll
        for (int ni = 0; ni < 4; ++ni) {
            const int r = wn * 64 + ni * 16 + l16;
            const int off = r * 32 + swz8(r, kq);
            bh[ni] = *(const half8v*)&Bs[off];
        }
#pragma unroll
        for (int mi = 0; mi < WMI; ++mi)
#pragma unroll
            for (int ni = 0; ni < 4; ++ni) {
                acc[mi][ni] = __builtin_amdgcn_mfma_f32_16x16x32_f16(ah[mi], bh[ni], acc[mi][ni], 0, 0, 0);
                acc[mi][ni] = __builtin_amdgcn_mfma_f32_16x16x32_f16(al[mi], bh[ni], acc[mi][ni], 0, 0, 0);
            }
    }

    // epilogue: C/D layout col = lane&15, row = (lane>>4)*4 + reg
#pragma unroll
    for (int mi = 0; mi < WMI; ++mi)
#pragma unroll
        for (int ni = 0; ni < 4; ++ni) {
            const int col = bn + wn * 64 + ni * 16 + l16;
#pragma unroll
            for (int r = 0; r < 4; ++r) {
                const int row = bm + (wm * WMI + mi) * 16 + kq * 4 + r;
                C[(size_t)row * N + col] = acc[mi][ni][r];
            }
        }
}

// ---------------------------------------------------------------------------
// GEMM3 split-K fp16x2: part[ks] = u[:, ks-chunk] @ W_x[ks-chunk, :].
// Block: 64 (m) x 96 (n) x 128 (k-chunk). Grid (KS3, M/64) = 512 blocks.
// ---------------------------------------------------------------------------
__global__ __launch_bounds__(256) void gemm3_splitk(
    const _Float16* __restrict__ AH, const _Float16* __restrict__ AL,
    const _Float16* __restrict__ BH, float* __restrict__ part)
{
    __shared__ __align__(16) _Float16 AsH[64 * 32];
    __shared__ __align__(16) _Float16 AsL[64 * 32];
    __shared__ __align__(16) _Float16 Bs[96 * 32];

    const int tid = threadIdx.x;
    const int lane = tid & 63;
    const int wave = tid >> 6;
    const int wm = wave & 1, wn = wave >> 1;
    const int ks = blockIdx.x;
    const int bm = blockIdx.y * 64;
    const int kbase = ks * (DINNER / KS3);
    const int l16 = lane & 15;
    const int kq = lane >> 4;

    f32x4 acc[2][3];
#pragma unroll
    for (int mi = 0; mi < 2; ++mi)
#pragma unroll
        for (int ni = 0; ni < 3; ++ni) acc[mi][ni] = {0.f, 0.f, 0.f, 0.f};

    for (int k0 = 0; k0 < DINNER / KS3; k0 += 32) {
        __syncthreads();
        {
            const int c = tid;                 // 64*4 = 256 granules
            const int row = c >> 2, g = c & 3;
            const int dst = row * 32 + swz8(row, g);
            const size_t src = (size_t)(bm + row) * DINNER + kbase + k0 + g * 8;
            *(half8v*)&AsH[dst] = *(const half8v*)(AH + src);
            *(half8v*)&AsL[dst] = *(const half8v*)(AL + src);
        }
        for (int c = tid; c < 96 * 4; c += 256) {
            const int row = c >> 2, g = c & 3;
            const int dst = row * 32 + swz8(row, g);
            const size_t src = (size_t)row * DINNER + kbase + k0 + g * 8;
            *(half8v*)&Bs[dst] = *(const half8v*)(BH + src);
        }
        __syncthreads();

        half8v ah[2], al[2], bh[3];
#pragma unroll
        for (int mi = 0; mi < 2; ++mi) {
            const int r = wm * 32 + mi * 16 + l16;
            const int off = r * 32 + swz8(r, kq);
            ah[mi] = *(const half8v*)&AsH[off];
            al[mi] = *(const half8v*)&AsL[off];
        }
#pragma unroll
        for (int ni = 0; ni < 3; ++ni) {
            const int r = wn * 48 + ni * 16 + l16;
            const int off = r * 32 + swz8(r, kq);
            bh[ni] = *(const half8v*)&Bs[off];
        }
#pragma unroll
        for (int mi = 0; mi < 2; ++mi)
#pragma unroll
            for (int ni = 0; ni < 3; ++ni) {
                acc[mi][ni] = __builtin_amdgcn_mfma_f32_16x16x32_f16(ah[mi], bh[ni], acc[mi][ni], 0, 0, 0);
                acc[mi][ni] = __builtin_amdgcn_mfma_f32_16x16x32_f16(al[mi], bh[ni], acc[mi][ni], 0, 0, 0);
            }
    }

#pragma unroll
    for (int mi = 0; mi < 2; ++mi)
#pragma unroll
        for (int ni = 0; ni < 3; ++ni) {
            const int col = wn * 48 + ni * 16 + l16;
#pragma unroll
            for (int r = 0; r < 4; ++r) {
                const int row = bm + wm * 32 + mi * 16 + kq * 4 + r;
                part[((size_t)ks * L_SEQ + row) * NXDBL + col] = acc[mi][ni][r];
            }
        }
}

// ---------------------------------------------------------------------------
// Sum the KS3 partials into x_dbl.
// ---------------------------------------------------------------------------
__global__ __launch_bounds__(256) void reduce_part(
    const float* __restrict__ part, float* __restrict__ x_dbl)
{
    const size_t i = ((size_t)blockIdx.x * 256 + threadIdx.x) * 4;
    float4 s = make_float4(0.f, 0.f, 0.f, 0.f);
#pragma unroll 4
    for (int ks = 0; ks < KS3; ++ks) {
        const float4 p = *(const float4*)(part + (size_t)ks * L_SEQ * NXDBL + i);
        s.x += p.x; s.y += p.y; s.z += p.z; s.w += p.w;
    }
    *(float4*)(x_dbl + i) = s;
}

// ---------------------------------------------------------------------------
// Depthwise causal conv (D_CONV=4) + SiLU; emits u fp32 + uH/uL fp16 split.
// ---------------------------------------------------------------------------
__global__ __launch_bounds__(256) void conv_silu_kernel(
    const float* __restrict__ xz, const float* __restrict__ conv_w,
    const float* __restrict__ conv_b, float* __restrict__ u,
    _Float16* __restrict__ uH, _Float16* __restrict__ uL)
{
    const int d = blockIdx.x * 256 + threadIdx.x;
    const int t = blockIdx.y;
    float acc = conv_b[d];
#pragma unroll
    for (int j = 0; j < DCONV; ++j) {
        const int tt = t - (DCONV - 1) + j;
        if (tt >= 0) acc = fmaf(xz[(size_t)tt * (2 * DINNER) + d], conv_w[d * DCONV + j], acc);
    }
    const float s = acc / (1.f + __expf(-acc));
    const size_t idx = (size_t)t * DINNER + d;
    u[idx] = s;
    const H2 sp = splitf16(s);
    uH[idx] = sp.h;
    uL[idx] = sp.l;
}

// ---------------------------------------------------------------------------
// delta = softplus(dlt @ W_dt + b_dt)
// ---------------------------------------------------------------------------
__global__ __launch_bounds__(256) void delta_kernel(
    const float* __restrict__ x_dbl, const float* __restrict__ W_dt,
    const float* __restrict__ b_dt, float* __restrict__ delta)
{
    __shared__ float dl[16][64];
    const int tid = threadIdx.x;
    const int d = blockIdx.x * 256 + tid;
    const int t0 = blockIdx.y * 16;

    for (int i = tid; i < 16 * 64; i += 256) {
        const int tt = i >> 6, k = i & 63;
        dl[tt][k] = x_dbl[(size_t)(t0 + tt) * NXDBL + k];
    }
    __syncthreads();

    const float bb = b_dt[d];
    float acc[16];
#pragma unroll
    for (int tt = 0; tt < 16; ++tt) acc[tt] = bb;

    for (int k = 0; k < 64; ++k) {
        const float w = W_dt[(size_t)k * DINNER + d];
#pragma unroll
        for (int tt = 0; tt < 16; ++tt) acc[tt] = fmaf(dl[tt][k], w, acc[tt]);
    }
#pragma unroll
    for (int tt = 0; tt < 16; ++tt) {
        const float x = acc[tt];
        const float sp = (x > 20.f) ? x : log1pf(__expf(x));
        delta[(size_t)(t0 + tt) * DINNER + d] = sp;
    }
}

// ---------------------------------------------------------------------------
// Scan phase 1: lane = channel d, h[16]+A2[16] in registers.
// ---------------------------------------------------------------------------
__global__ __launch_bounds__(256) void scan_phase1(
    const float* __restrict__ u, const float* __restrict__ delta,
    const float* __restrict__ x_dbl, const float* __restrict__ A_log,
    float* __restrict__ aprod, float* __restrict__ hacc)
{
    __shared__ float sB[TC][16];

    const int tid = threadIdx.x;
    const int d = blockIdx.x * 256 + tid;
    const int ch = blockIdx.y;
    const int t0 = ch * TC;

    float A2[16];
#pragma unroll
    for (int j = 0; j < 4; ++j) {
        const float4 a4 = *(const float4*)(A_log + (size_t)d * DSTATE + j * 4);
        A2[4 * j + 0] = -__expf(a4.x) * LOG2E;
        A2[4 * j + 1] = -__expf(a4.y) * LOG2E;
        A2[4 * j + 2] = -__expf(a4.z) * LOG2E;
        A2[4 * j + 3] = -__expf(a4.w) * LOG2E;
    }

    for (int i = tid; i < TC * 16; i += 256) {
        const int tt = i >> 4, q = i & 15;
        sB[tt][q] = x_dbl[(size_t)(t0 + tt) * NXDBL + DTRANK + q];
    }
    __syncthreads();

    float h[16];
#pragma unroll
    for (int n = 0; n < 16; ++n) h[n] = 0.f;
    float S = 0.f;

    for (int tt = 0; tt < TC; ++tt) {
        const float dt = delta[(size_t)(t0 + tt) * DINNER + d];
        const float uu = u[(size_t)(t0 + tt) * DINNER + d];
        const float du = dt * uu;
        S += dt;
        float4 b[4];
#pragma unroll
        for (int j = 0; j < 4; ++j) b[j] = *(const float4*)&sB[tt][j * 4];
        const float* bp = (const float*)b;
#pragma unroll
        for (int n = 0; n < 16; ++n) {
            const float a = exp2f(dt * A2[n]);
            h[n] = fmaf(a, h[n], du * bp[n]);
        }
    }

    const size_t base = ((size_t)ch * DINNER + d) * DSTATE;
#pragma unroll
    for (int j = 0; j < 4; ++j) {
        float4 av, hv;
        av.x = exp2f(S * A2[4 * j + 0]);
        av.y = exp2f(S * A2[4 * j + 1]);
        av.z = exp2f(S * A2[4 * j + 2]);
        av.w = exp2f(S * A2[4 * j + 3]);
        hv.x = h[4 * j + 0]; hv.y = h[4 * j + 1];
        hv.z = h[4 * j + 2]; hv.w = h[4 * j + 3];
        *(float4*)(aprod + base + j * 4) = av;
        *(float4*)(hacc + base + j * 4) = hv;
    }
}

// ---------------------------------------------------------------------------
// Phase 2: exclusive scan over chunk summaries (hacc -> hinit in place).
// ---------------------------------------------------------------------------
__global__ __launch_bounds__(256) void scan_phase2(
    const float* __restrict__ aprod, float* __restrict__ hacc)
{
    const int i = blockIdx.x * 256 + threadIdx.x;
    float h0 = 0.f;
#pragma unroll 4
    for (int c = 0; c < CCH; ++c) {
        const size_t idx = (size_t)c * DINNER * DSTATE + i;
        const float a  = aprod[idx];
        const float hc = hacc[idx];
        hacc[idx] = h0;
        h0 = fmaf(a, h0, hc);
    }
}

// ---------------------------------------------------------------------------
// Phase 3: lane = channel d, replay from corrected init, gate,
// write g directly as fp16 hi/lo (feeds GEMM6 with no further split).
// ---------------------------------------------------------------------------
__global__ __launch_bounds__(256) void scan_phase3(
    const float* __restrict__ xz, const float* __restrict__ u,
    const float* __restrict__ delta, const float* __restrict__ x_dbl,
    const float* __restrict__ A_log, const float* __restrict__ D_param,
    const float* __restrict__ hinit,
    _Float16* __restrict__ gH, _Float16* __restrict__ gL)
{
    __shared__ float sBC[TC][32];   // [t][0..15]=B, [16..31]=C

    const int tid = threadIdx.x;
    const int d = blockIdx.x * 256 + tid;
    const int ch = blockIdx.y;
    const int t0 = ch * TC;

    float A2[16];
#pragma unroll
    for (int j = 0; j < 4; ++j) {
        const float4 a4 = *(const float4*)(A_log + (size_t)d * DSTATE + j * 4);
        A2[4 * j + 0] = -__expf(a4.x) * LOG2E;
        A2[4 * j + 1] = -__expf(a4.y) * LOG2E;
        A2[4 * j + 2] = -__expf(a4.z) * LOG2E;
        A2[4 * j + 3] = -__expf(a4.w) * LOG2E;
    }
    const float Dp = D_param[d];

    float h[16];
    {
        const size_t base = ((size_t)ch * DINNER + d) * DSTATE;
#pragma unroll
        for (int j = 0; j < 4; ++j) {
            const float4 hv = *(const float4*)(hinit + base + j * 4);
            h[4 * j + 0] = hv.x; h[4 * j + 1] = hv.y;
            h[4 * j + 2] = hv.z; h[4 * j + 3] = hv.w;
        }
    }

    for (int i = tid; i < TC * 32; i += 256) {
        const int tt = i >> 5, q = i & 31;
        sBC[tt][q] = x_dbl[(size_t)(t0 + tt) * NXDBL + DTRANK + q];
    }
    __syncthreads();

    for (int tt = 0; tt < TC; ++tt) {
        const float dt = delta[(size_t)(t0 + tt) * DINNER + d];
        const float uu = u[(size_t)(t0 + tt) * DINNER + d];
        const float z  = xz[(size_t)(t0 + tt) * (2 * DINNER) + DINNER + d];
        const float du = dt * uu;
        float4 b[4], c[4];
#pragma unroll
        for (int j = 0; j < 4; ++j) {
            b[j] = *(const float4*)&sBC[tt][j * 4];
            c[j] = *(const float4*)&sBC[tt][16 + j * 4];
        }
        const float* bp = (const float*)b;
        const float* cp = (const float*)c;
        float y = Dp * uu;
#pragma unroll
        for (int n = 0; n < 16; ++n) {
            const float a = exp2f(dt * A2[n]);
            h[n] = fmaf(a, h[n], du * bp[n]);
            y = fmaf(h[n], cp[n], y);
        }
        const float gate = z / (1.f + __expf(-z));
        const float gv = y * gate;
        const size_t idx = (size_t)(t0 + tt) * DINNER + d;
        const H2 gs = splitf16(gv);
        gH[idx] = gs.h;
        gL[idx] = gs.l;
    }
}

// ---------------------------------------------------------------------------
extern "C" void kernel_launch(void* const* d_in, const int* in_sizes, int n_in,
                              void* d_out, int out_size, void* d_ws, size_t ws_size,
                              hipStream_t stream)
{
    const float* x      = (const float*)d_in[0];
    const float* W_in   = (const float*)d_in[1];
    const float* conv_w = (const float*)d_in[2];
    const float* conv_b = (const float*)d_in[3];
    const float* W_x    = (const float*)d_in[4];
    const float* W_dt   = (const float*)d_in[5];
    const float* b_dt   = (const float*)d_in[6];
    const float* A_log  = (const float*)d_in[7];
    const float* D_par  = (const float*)d_in[8];
    const float* W_out  = (const float*)d_in[9];
    float* out = (float*)d_out;

    float* ws    = (float*)d_ws;
    float* xz    = ws;                                    // 8M f32 (32 MB)
    float* u     = xz + (size_t)L_SEQ * 2 * DINNER;       // 4M f32 (16 MB)
    float* x_dbl = u + (size_t)L_SEQ * DINNER;            // 196K f32
    float* delta = x_dbl + (size_t)L_SEQ * NXDBL;         // 4M f32 (16 MB)
    float* aprod = delta + (size_t)L_SEQ * DINNER;        // 2M f32 (8 MB)
    float* hacc  = aprod + (size_t)CCH * DINNER * DSTATE; // 2M f32 (8 MB)
    _Float16* WinT  = (_Float16*)(hacc + (size_t)CCH * DINNER * DSTATE); // [4096][1024] (8 MB)
    _Float16* WoutT = WinT + (size_t)(2 * DINNER) * DMODEL;              // [1024][2048] (4 MB)
    _Float16* WxT   = WoutT + (size_t)DMODEL * DINNER;                   // [96][2048]

    // Aliases (lifetimes verified against launch order):
    // xH/xL <- delta buffer (8 MB of 16): used step 0d->1; delta written step 4.
    _Float16* xH = (_Float16*)delta;
    _Float16* xL = xH + (size_t)L_SEQ * DMODEL;
    // part <- delta buffer (12.6 MB of 16): written step 3 (xH/xL dead after 1),
    // consumed step 3b; delta written step 4.
    float* part = (float*)delta;
    // uH <- aprod, uL <- hacc: written step 2, read step 3 (gemm3);
    // aprod/hacc written step 5a -> safe.
    _Float16* uH = (_Float16*)aprod;
    _Float16* uL = (_Float16*)hacc;
    // gH <- WinT (dead after step 1), gL <- aprod (dead after step 5b);
    // both written step 5c, read step 6.
    _Float16* gH = WinT;
    _Float16* gL = (_Float16*)aprod;

    // 0) weight prep (single-fp16 transpose) + x hi/lo split
    transpose_f16<<<dim3(2 * DINNER / 32, DMODEL / 32), 256, 0, stream>>>(W_in, WinT, DMODEL, 2 * DINNER);
    transpose_f16<<<dim3(DMODEL / 32, DINNER / 32), 256, 0, stream>>>(W_out, WoutT, DINNER, DMODEL);
    transpose_f16<<<dim3(NXDBL / 32, DINNER / 32), 256, 0, stream>>>(W_x, WxT, DINNER, NXDBL);
    split_hi_lo<<<dim3(L_SEQ * DMODEL / 4 / 256), 256, 0, stream>>>(x, xH, xL);

    // 1) xz = x @ W_in   (2048x1024 @ 1024x4096)
    gemm_pre<4><<<dim3(2 * DINNER / 128, L_SEQ / 128), 256, 0, stream>>>(
        xH, xL, WinT, xz, L_SEQ, 2 * DINNER, DMODEL);
    // 2) u = silu(conv(xc)) (+ fp16 hi/lo split)
    conv_silu_kernel<<<dim3(DINNER / 256, L_SEQ), 256, 0, stream>>>(xz, conv_w, conv_b, u, uH, uL);
    // 3) x_dbl = u @ W_x   (split-K)
    gemm3_splitk<<<dim3(KS3, L_SEQ / 64), 256, 0, stream>>>(uH, uL, WxT, part);
    reduce_part<<<dim3(L_SEQ * NXDBL / 4 / 256), 256, 0, stream>>>(part, x_dbl);
    // 4) delta = softplus(dlt @ W_dt + b_dt)   (overwrites part region - safe)
    delta_kernel<<<dim3(DINNER / 256, L_SEQ / 16), 256, 0, stream>>>(x_dbl, W_dt, b_dt, delta);
    // 5) parallel scan (phase1 overwrites uH/uL; phase3 overwrites WinT/aprod)
    scan_phase1<<<dim3(DINNER / 256, CCH), 256, 0, stream>>>(u, delta, x_dbl, A_log, aprod, hacc);
    scan_phase2<<<dim3(DINNER * DSTATE / 256), 256, 0, stream>>>(aprod, hacc);
    scan_phase3<<<dim3(DINNER / 256, CCH), 256, 0, stream>>>(xz, u, delta, x_dbl, A_log, D_par, hacc, gH, gL);
    // 6) out = g @ W_out   (2048x2048 @ 2048x1024)
    gemm_pre<2><<<dim3(DMODEL / 128, L_SEQ / 64), 256, 0, stream>>>(
        gH, gL, WoutT, out, L_SEQ, DMODEL, DINNER);
}

// Round 9
// 312.416 us; speedup vs baseline: 3.7579x; 1.0379x over previous
//
#include <hip/hip_runtime.h>
#include <hip/hip_bf16.h>
#include <math.h>

// Problem constants
#define L_SEQ   2048
#define DMODEL  1024
#define DINNER  2048
#define DSTATE  16
#define DCONV   4
#define DTRANK  64
#define NXDBL   96   // DT_RANK + 2*D_STATE

#define CCH 64   // time chunks for parallel scan
#define TC  32   // timesteps per chunk (CCH*TC == L_SEQ)
#define KS3 16   // split-K factor for GEMM3

#define LOG2E 1.44269504088896340736f

typedef _Float16 half8v __attribute__((ext_vector_type(8)));
typedef _Float16 half4v __attribute__((ext_vector_type(4)));
typedef float f32x4 __attribute__((ext_vector_type(4)));

// fp16x2 split: a = (fp16)a + (fp16)(a - (float)(fp16)a), ~22 mantissa bits.
// GEMM computes (ah+al)@bh with 2 MFMAs; error = a@(b-bh) ~ 2^-11 rel of B.
struct H2 { _Float16 h, l; };
__device__ __forceinline__ H2 splitf16(float v) {
    H2 r;
    r.h = (_Float16)v;
    r.l = (_Float16)(v - (float)r.h);
    return r;
}

// 16B-granule XOR swizzle for unpadded [row][32-half] LDS tiles (gemm3).
__device__ __forceinline__ int swz8(int row, int g) {
    return (g ^ ((row >> 1) & 3)) * 8;
}

// ---------------------------------------------------------------------------
// Weight prep: W[K][N] fp32 -> WT [N][K] fp16 (transpose + single rounding).
// ---------------------------------------------------------------------------
__global__ __launch_bounds__(256) void transpose_f16(
    const float* __restrict__ W, _Float16* __restrict__ WT, int K, int N)
{
    __shared__ float tile[32][33];
    const int tid = threadIdx.x;
    const int k0 = blockIdx.y * 32, n0 = blockIdx.x * 32;
    const int r = tid >> 3, c4 = (tid & 7) * 4;

    const float4 w4 = *(const float4*)(W + (size_t)(k0 + r) * N + n0 + c4);
    tile[r][c4 + 0] = w4.x;
    tile[r][c4 + 1] = w4.y;
    tile[r][c4 + 2] = w4.z;
    tile[r][c4 + 3] = w4.w;
    __syncthreads();

    half4v h;
#pragma unroll
    for (int j = 0; j < 4; ++j) h[j] = (_Float16)tile[c4 + j][r];
    *(half4v*)(WT + (size_t)(n0 + r) * K + k0 + c4) = h;
}

// ---------------------------------------------------------------------------
// Elementwise fp32 -> fp16 hi/lo split (for x).
// ---------------------------------------------------------------------------
__global__ __launch_bounds__(256) void split_hi_lo(
    const float* __restrict__ in, _Float16* __restrict__ hi,
    _Float16* __restrict__ lo)
{
    const size_t i = ((size_t)blockIdx.x * 256 + threadIdx.x) * 4;
    const float4 v4 = *(const float4*)(in + i);
    const float v[4] = {v4.x, v4.y, v4.z, v4.w};
    half4v h, l;
#pragma unroll
    for (int j = 0; j < 4; ++j) {
        const H2 s = splitf16(v[j]);
        h[j] = s.h;
        l[j] = s.l;
    }
    *(half4v*)(hi + i) = h;
    *(half4v*)(lo + i) = l;
}

// ---------------------------------------------------------------------------
// fp16x2 MFMA GEMM, BK=64: C[M,N] = A[M,koff:koff+Klen] @ B[..], A as AH/AL
// [M][K] fp16, B as BH [N][K] fp16. blockIdx.z selects a K-slice (split-K);
// C is offset by z*M*N (Klen==K, gridDim.z==1 -> plain GEMM).
// Block tile: BM x 128, BM = WMI*32. 256 threads = 4 waves (2x2).
// LDS rows are 64 halves (128B); granule swizzle g^(row&7) keeps staging
// writes and b128 fragment reads 2-way (free).
// ---------------------------------------------------------------------------
template <int WMI>
__global__ __launch_bounds__(256) void gemm_pre(
    const _Float16* __restrict__ AH, const _Float16* __restrict__ AL,
    const _Float16* __restrict__ BH, float* __restrict__ C,
    int M, int N, int K, int Klen)
{
    constexpr int BM = WMI * 32;
    __shared__ __align__(16) _Float16 AsH[BM * 64];
    __shared__ __align__(16) _Float16 AsL[BM * 64];
    __shared__ __align__(16) _Float16 Bs[128 * 64];

    const int tid = threadIdx.x;
    const int lane = tid & 63;
    const int wave = tid >> 6;
    const int wm = wave >> 1, wn = wave & 1;
    const int bm = blockIdx.y * BM;
    const int bn = blockIdx.x * 128;
    const int koff = blockIdx.z * Klen;
    C += (size_t)blockIdx.z * M * N;
    const int l16 = lane & 15;
    const int kq = lane >> 4;

    f32x4 acc[WMI][4];
#pragma unroll
    for (int mi = 0; mi < WMI; ++mi)
#pragma unroll
        for (int ni = 0; ni < 4; ++ni) acc[mi][ni] = {0.f, 0.f, 0.f, 0.f};

    for (int k0 = koff; k0 < koff + Klen; k0 += 64) {
        __syncthreads();
        // --- stage A (BM rows x 8 granules, hi+lo)
#pragma unroll
        for (int i = 0; i < (BM * 8) / 256; ++i) {
            const int c = tid + 256 * i;
            const int row = c >> 3, g = c & 7;
            const int dst = row * 64 + ((g ^ (row & 7)) * 8);
            const size_t src = (size_t)(bm + row) * K + k0 + g * 8;
            *(half8v*)&AsH[dst] = *(const half8v*)(AH + src);
            *(half8v*)&AsL[dst] = *(const half8v*)(AL + src);
        }
        // --- stage B (128 rows x 8 granules)
#pragma unroll
        for (int i = 0; i < 4; ++i) {
            const int c = tid + 256 * i;
            const int row = c >> 3, g = c & 7;
            const int dst = row * 64 + ((g ^ (row & 7)) * 8);
            const size_t src = (size_t)(bn + row) * K + k0 + g * 8;
            *(half8v*)&Bs[dst] = *(const half8v*)(BH + src);
        }
        __syncthreads();

#pragma unroll
        for (int kk = 0; kk < 2; ++kk) {
            half8v ah[WMI], al[WMI], bh[4];
#pragma unroll
            for (int mi = 0; mi < WMI; ++mi) {
                const int r = (wm * WMI + mi) * 16 + l16;
                const int off = r * 64 + (((kk * 4 + kq) ^ (r & 7)) * 8);
                ah[mi] = *(const half8v*)&AsH[off];
                al[mi] = *(const half8v*)&AsL[off];
            }
#pragma unroll
            for (int ni = 0; ni < 4; ++ni) {
                const int r = wn * 64 + ni * 16 + l16;
                const int off = r * 64 + (((kk * 4 + kq) ^ (r & 7)) * 8);
                bh[ni] = *(const half8v*)&Bs[off];
            }
#pragma unroll
            for (int mi = 0; mi < WMI; ++mi)
#pragma unroll
                for (int ni = 0; ni < 4; ++ni) {
                    acc[mi][ni] = __builtin_amdgcn_mfma_f32_16x16x32_f16(ah[mi], bh[ni], acc[mi][ni], 0, 0, 0);
                    acc[mi][ni] = __builtin_amdgcn_mfma_f32_16x16x32_f16(al[mi], bh[ni], acc[mi][ni], 0, 0, 0);
                }
        }
    }

    // epilogue: C/D layout col = lane&15, row = (lane>>4)*4 + reg
#pragma unroll
    for (int mi = 0; mi < WMI; ++mi)
#pragma unroll
        for (int ni = 0; ni < 4; ++ni) {
            const int col = bn + wn * 64 + ni * 16 + l16;
#pragma unroll
            for (int r = 0; r < 4; ++r) {
                const int row = bm + (wm * WMI + mi) * 16 + kq * 4 + r;
                C[(size_t)row * N + col] = acc[mi][ni][r];
            }
        }
}

// ---------------------------------------------------------------------------
// Sum 2 split-K partials into out (GEMM6).
// ---------------------------------------------------------------------------
__global__ __launch_bounds__(256) void reduce6(
    const float* __restrict__ part, float* __restrict__ out)
{
    const size_t i = ((size_t)blockIdx.x * 256 + threadIdx.x) * 4;
    const float4 a = *(const float4*)(part + i);
    const float4 b = *(const float4*)(part + (size_t)L_SEQ * DMODEL + i);
    *(float4*)(out + i) = make_float4(a.x + b.x, a.y + b.y, a.z + b.z, a.w + b.w);
}

// ---------------------------------------------------------------------------
// GEMM3 split-K fp16x2: part[ks] = u[:, ks-chunk] @ W_x[ks-chunk, :].
// Block: 64 (m) x 96 (n) x 128 (k-chunk). Grid (KS3, M/64) = 512 blocks.
// ---------------------------------------------------------------------------
__global__ __launch_bounds__(256) void gemm3_splitk(
    const _Float16* __restrict__ AH, const _Float16* __restrict__ AL,
    const _Float16* __restrict__ BH, float* __restrict__ part)
{
    __shared__ __align__(16) _Float16 AsH[64 * 32];
    __shared__ __align__(16) _Float16 AsL[64 * 32];
    __shared__ __align__(16) _Float16 Bs[96 * 32];

    const int tid = threadIdx.x;
    const int lane = tid & 63;
    const int wave = tid >> 6;
    const int wm = wave & 1, wn = wave >> 1;
    const int ks = blockIdx.x;
    const int bm = blockIdx.y * 64;
    const int kbase = ks * (DINNER / KS3);
    const int l16 = lane & 15;
    const int kq = lane >> 4;

    f32x4 acc[2][3];
#pragma unroll
    for (int mi = 0; mi < 2; ++mi)
#pragma unroll
        for (int ni = 0; ni < 3; ++ni) acc[mi][ni] = {0.f, 0.f, 0.f, 0.f};

    for (int k0 = 0; k0 < DINNER / KS3; k0 += 32) {
        __syncthreads();
        {
            const int c = tid;                 // 64*4 = 256 granules
            const int row = c >> 2, g = c & 3;
            const int dst = row * 32 + swz8(row, g);
            const size_t src = (size_t)(bm + row) * DINNER + kbase + k0 + g * 8;
            *(half8v*)&AsH[dst] = *(const half8v*)(AH + src);
            *(half8v*)&AsL[dst] = *(const half8v*)(AL + src);
        }
        for (int c = tid; c < 96 * 4; c += 256) {
            const int row = c >> 2, g = c & 3;
            const int dst = row * 32 + swz8(row, g);
            const size_t src = (size_t)row * DINNER + kbase + k0 + g * 8;
            *(half8v*)&Bs[dst] = *(const half8v*)(BH + src);
        }
        __syncthreads();

        half8v ah[2], al[2], bh[3];
#pragma unroll
        for (int mi = 0; mi < 2; ++mi) {
            const int r = wm * 32 + mi * 16 + l16;
            const int off = r * 32 + swz8(r, kq);
            ah[mi] = *(const half8v*)&AsH[off];
            al[mi] = *(const half8v*)&AsL[off];
        }
#pragma unroll
        for (int ni = 0; ni < 3; ++ni) {
            const int r = wn * 48 + ni * 16 + l16;
            const int off = r * 32 + swz8(r, kq);
            bh[ni] = *(const half8v*)&Bs[off];
        }
#pragma unroll
        for (int mi = 0; mi < 2; ++mi)
#pragma unroll
            for (int ni = 0; ni < 3; ++ni) {
                acc[mi][ni] = __builtin_amdgcn_mfma_f32_16x16x32_f16(ah[mi], bh[ni], acc[mi][ni], 0, 0, 0);
                acc[mi][ni] = __builtin_amdgcn_mfma_f32_16x16x32_f16(al[mi], bh[ni], acc[mi][ni], 0, 0, 0);
            }
    }

#pragma unroll
    for (int mi = 0; mi < 2; ++mi)
#pragma unroll
        for (int ni = 0; ni < 3; ++ni) {
            const int col = wn * 48 + ni * 16 + l16;
#pragma unroll
            for (int r = 0; r < 4; ++r) {
                const int row = bm + wm * 32 + mi * 16 + kq * 4 + r;
                part[((size_t)ks * L_SEQ + row) * NXDBL + col] = acc[mi][ni][r];
            }
        }
}

// ---------------------------------------------------------------------------
// Sum the KS3 partials into x_dbl.
// ---------------------------------------------------------------------------
__global__ __launch_bounds__(256) void reduce_part(
    const float* __restrict__ part, float* __restrict__ x_dbl)
{
    const size_t i = ((size_t)blockIdx.x * 256 + threadIdx.x) * 4;
    float4 s = make_float4(0.f, 0.f, 0.f, 0.f);
#pragma unroll 4
    for (int ks = 0; ks < KS3; ++ks) {
        const float4 p = *(const float4*)(part + (size_t)ks * L_SEQ * NXDBL + i);
        s.x += p.x; s.y += p.y; s.z += p.z; s.w += p.w;
    }
    *(float4*)(x_dbl + i) = s;
}

// ---------------------------------------------------------------------------
// Depthwise causal conv (D_CONV=4) + SiLU; emits u fp32 + uH/uL fp16 split.
// ---------------------------------------------------------------------------
__global__ __launch_bounds__(256) void conv_silu_kernel(
    const float* __restrict__ xz, const float* __restrict__ conv_w,
    const float* __restrict__ conv_b, float* __restrict__ u,
    _Float16* __restrict__ uH, _Float16* __restrict__ uL)
{
    const int d = blockIdx.x * 256 + threadIdx.x;
    const int t = blockIdx.y;
    float acc = conv_b[d];
#pragma unroll
    for (int j = 0; j < DCONV; ++j) {
        const int tt = t - (DCONV - 1) + j;
        if (tt >= 0) acc = fmaf(xz[(size_t)tt * (2 * DINNER) + d], conv_w[d * DCONV + j], acc);
    }
    const float s = acc / (1.f + __expf(-acc));
    const size_t idx = (size_t)t * DINNER + d;
    u[idx] = s;
    const H2 sp = splitf16(s);
    uH[idx] = sp.h;
    uL[idx] = sp.l;
}

// ---------------------------------------------------------------------------
// delta = softplus(dlt @ W_dt + b_dt)
// ---------------------------------------------------------------------------
__global__ __launch_bounds__(256) void delta_kernel(
    const float* __restrict__ x_dbl, const float* __restrict__ W_dt,
    const float* __restrict__ b_dt, float* __restrict__ delta)
{
    __shared__ float dl[16][64];
    const int tid = threadIdx.x;
    const int d = blockIdx.x * 256 + tid;
    const int t0 = blockIdx.y * 16;

    for (int i = tid; i < 16 * 64; i += 256) {
        const int tt = i >> 6, k = i & 63;
        dl[tt][k] = x_dbl[(size_t)(t0 + tt) * NXDBL + k];
    }
    __syncthreads();

    const float bb = b_dt[d];
    float acc[16];
#pragma unroll
    for (int tt = 0; tt < 16; ++tt) acc[tt] = bb;

    for (int k = 0; k < 64; ++k) {
        const float w = W_dt[(size_t)k * DINNER + d];
#pragma unroll
        for (int tt = 0; tt < 16; ++tt) acc[tt] = fmaf(dl[tt][k], w, acc[tt]);
    }
#pragma unroll
    for (int tt = 0; tt < 16; ++tt) {
        const float x = acc[tt];
        const float sp = (x > 20.f) ? x : log1pf(__expf(x));
        delta[(size_t)(t0 + tt) * DINNER + d] = sp;
    }
}

// ---------------------------------------------------------------------------
// Scan phase 1: lane = channel d, h[16]+A2[16] in registers.
// ---------------------------------------------------------------------------
__global__ __launch_bounds__(256) void scan_phase1(
    const float* __restrict__ u, const float* __restrict__ delta,
    const float* __restrict__ x_dbl, const float* __restrict__ A_log,
    float* __restrict__ aprod, float* __restrict__ hacc)
{
    __shared__ float sB[TC][16];

    const int tid = threadIdx.x;
    const int d = blockIdx.x * 256 + tid;
    const int ch = blockIdx.y;
    const int t0 = ch * TC;

    float A2[16];
#pragma unroll
    for (int j = 0; j < 4; ++j) {
        const float4 a4 = *(const float4*)(A_log + (size_t)d * DSTATE + j * 4);
        A2[4 * j + 0] = -__expf(a4.x) * LOG2E;
        A2[4 * j + 1] = -__expf(a4.y) * LOG2E;
        A2[4 * j + 2] = -__expf(a4.z) * LOG2E;
        A2[4 * j + 3] = -__expf(a4.w) * LOG2E;
    }

    for (int i = tid; i < TC * 16; i += 256) {
        const int tt = i >> 4, q = i & 15;
        sB[tt][q] = x_dbl[(size_t)(t0 + tt) * NXDBL + DTRANK + q];
    }
    __syncthreads();

    float h[16];
#pragma unroll
    for (int n = 0; n < 16; ++n) h[n] = 0.f;
    float S = 0.f;

    for (int tt = 0; tt < TC; ++tt) {
        const float dt = delta[(size_t)(t0 + tt) * DINNER + d];
        const float uu = u[(size_t)(t0 + tt) * DINNER + d];
        const float du = dt * uu;
        S += dt;
        float4 b[4];
#pragma unroll
        for (int j = 0; j < 4; ++j) b[j] = *(const float4*)&sB[tt][j * 4];
        const float* bp = (const float*)b;
#pragma unroll
        for (int n = 0; n < 16; ++n) {
            const float a = exp2f(dt * A2[n]);
            h[n] = fmaf(a, h[n], du * bp[n]);
        }
    }

    const size_t base = ((size_t)ch * DINNER + d) * DSTATE;
#pragma unroll
    for (int j = 0; j < 4; ++j) {
        float4 av, hv;
        av.x = exp2f(S * A2[4 * j + 0]);
        av.y = exp2f(S * A2[4 * j + 1]);
        av.z = exp2f(S * A2[4 * j + 2]);
        av.w = exp2f(S * A2[4 * j + 3]);
        hv.x = h[4 * j + 0]; hv.y = h[4 * j + 1];
        hv.z = h[4 * j + 2]; hv.w = h[4 * j + 3];
        *(float4*)(aprod + base + j * 4) = av;
        *(float4*)(hacc + base + j * 4) = hv;
    }
}

// ---------------------------------------------------------------------------
// Phase 2: exclusive scan over chunk summaries (hacc -> hinit in place).
// ---------------------------------------------------------------------------
__global__ __launch_bounds__(256) void scan_phase2(
    const float* __restrict__ aprod, float* __restrict__ hacc)
{
    const int i = blockIdx.x * 256 + threadIdx.x;
    float h0 = 0.f;
#pragma unroll 4
    for (int c = 0; c < CCH; ++c) {
        const size_t idx = (size_t)c * DINNER * DSTATE + i;
        const float a  = aprod[idx];
        const float hc = hacc[idx];
        hacc[idx] = h0;
        h0 = fmaf(a, h0, hc);
    }
}

// ---------------------------------------------------------------------------
// Phase 3: lane = channel d, replay from corrected init, gate,
// write g directly as fp16 hi/lo (feeds GEMM6 with no further split).
// ---------------------------------------------------------------------------
__global__ __launch_bounds__(256) void scan_phase3(
    const float* __restrict__ xz, const float* __restrict__ u,
    const float* __restrict__ delta, const float* __restrict__ x_dbl,
    const float* __restrict__ A_log, const float* __restrict__ D_param,
    const float* __restrict__ hinit,
    _Float16* __restrict__ gH, _Float16* __restrict__ gL)
{
    __shared__ float sBC[TC][32];   // [t][0..15]=B, [16..31]=C

    const int tid = threadIdx.x;
    const int d = blockIdx.x * 256 + tid;
    const int ch = blockIdx.y;
    const int t0 = ch * TC;

    float A2[16];
#pragma unroll
    for (int j = 0; j < 4; ++j) {
        const float4 a4 = *(const float4*)(A_log + (size_t)d * DSTATE + j * 4);
        A2[4 * j + 0] = -__expf(a4.x) * LOG2E;
        A2[4 * j + 1] = -__expf(a4.y) * LOG2E;
        A2[4 * j + 2] = -__expf(a4.z) * LOG2E;
        A2[4 * j + 3] = -__expf(a4.w) * LOG2E;
    }
    const float Dp = D_param[d];

    float h[16];
    {
        const size_t base = ((size_t)ch * DINNER + d) * DSTATE;
#pragma unroll
        for (int j = 0; j < 4; ++j) {
            const float4 hv = *(const float4*)(hinit + base + j * 4);
            h[4 * j + 0] = hv.x; h[4 * j + 1] = hv.y;
            h[4 * j + 2] = hv.z; h[4 * j + 3] = hv.w;
        }
    }

    for (int i = tid; i < TC * 32; i += 256) {
        const int tt = i >> 5, q = i & 31;
        sBC[tt][q] = x_dbl[(size_t)(t0 + tt) * NXDBL + DTRANK + q];
    }
    __syncthreads();

    for (int tt = 0; tt < TC; ++tt) {
        const float dt = delta[(size_t)(t0 + tt) * DINNER + d];
        const float uu = u[(size_t)(t0 + tt) * DINNER + d];
        const float z  = xz[(size_t)(t0 + tt) * (2 * DINNER) + DINNER + d];
        const float du = dt * uu;
        float4 b[4], c[4];
#pragma unroll
        for (int j = 0; j < 4; ++j) {
            b[j] = *(const float4*)&sBC[tt][j * 4];
            c[j] = *(const float4*)&sBC[tt][16 + j * 4];
        }
        const float* bp = (const float*)b;
        const float* cp = (const float*)c;
        float y = Dp * uu;
#pragma unroll
        for (int n = 0; n < 16; ++n) {
            const float a = exp2f(dt * A2[n]);
            h[n] = fmaf(a, h[n], du * bp[n]);
            y = fmaf(h[n], cp[n], y);
        }
        const float gate = z / (1.f + __expf(-z));
        const float gv = y * gate;
        const size_t idx = (size_t)(t0 + tt) * DINNER + d;
        const H2 gs = splitf16(gv);
        gH[idx] = gs.h;
        gL[idx] = gs.l;
    }
}

// ---------------------------------------------------------------------------
extern "C" void kernel_launch(void* const* d_in, const int* in_sizes, int n_in,
                              void* d_out, int out_size, void* d_ws, size_t ws_size,
                              hipStream_t stream)
{
    const float* x      = (const float*)d_in[0];
    const float* W_in   = (const float*)d_in[1];
    const float* conv_w = (const float*)d_in[2];
    const float* conv_b = (const float*)d_in[3];
    const float* W_x    = (const float*)d_in[4];
    const float* W_dt   = (const float*)d_in[5];
    const float* b_dt   = (const float*)d_in[6];
    const float* A_log  = (const float*)d_in[7];
    const float* D_par  = (const float*)d_in[8];
    const float* W_out  = (const float*)d_in[9];
    float* out = (float*)d_out;

    float* ws    = (float*)d_ws;
    float* xz    = ws;                                    // 8M f32 (32 MB)
    float* u     = xz + (size_t)L_SEQ * 2 * DINNER;       // 4M f32 (16 MB)
    float* x_dbl = u + (size_t)L_SEQ * DINNER;            // 196K f32
    float* delta = x_dbl + (size_t)L_SEQ * NXDBL;         // 4M f32 (16 MB)
    float* aprod = delta + (size_t)L_SEQ * DINNER;        // 2M f32 (8 MB)
    float* hacc  = aprod + (size_t)CCH * DINNER * DSTATE; // 2M f32 (8 MB)
    _Float16* WinT  = (_Float16*)(hacc + (size_t)CCH * DINNER * DSTATE); // [4096][1024] (8 MB)
    _Float16* WoutT = WinT + (size_t)(2 * DINNER) * DMODEL;              // [1024][2048] (4 MB)
    _Float16* WxT   = WoutT + (size_t)DMODEL * DINNER;                   // [96][2048]

    // Aliases (lifetimes verified against launch order):
    // xH/xL <- delta buffer (8 MB of 16): used step 0d->1; delta written step 4.
    _Float16* xH = (_Float16*)delta;
    _Float16* xL = xH + (size_t)L_SEQ * DMODEL;
    // part <- delta buffer (12.6 MB of 16): written step 3 (xH/xL dead after 1),
    // consumed step 3b; delta written step 4.
    float* part = (float*)delta;
    // uH <- aprod, uL <- hacc: written step 2, read step 3 (gemm3);
    // aprod/hacc written step 5a -> safe.
    _Float16* uH = (_Float16*)aprod;
    _Float16* uL = (_Float16*)hacc;
    // gH <- WinT (dead after step 1), gL <- aprod (dead after step 5b);
    // both written step 5c, read step 6.
    _Float16* gH = WinT;
    _Float16* gL = (_Float16*)aprod;
    // part6 <- xz (32 MB >= 16 MB): xz dead after phase3 reads z (step 5c).
    float* part6 = xz;

    // 0) weight prep (single-fp16 transpose) + x hi/lo split
    transpose_f16<<<dim3(2 * DINNER / 32, DMODEL / 32), 256, 0, stream>>>(W_in, WinT, DMODEL, 2 * DINNER);
    transpose_f16<<<dim3(DMODEL / 32, DINNER / 32), 256, 0, stream>>>(W_out, WoutT, DINNER, DMODEL);
    transpose_f16<<<dim3(NXDBL / 32, DINNER / 32), 256, 0, stream>>>(W_x, WxT, DINNER, NXDBL);
    split_hi_lo<<<dim3(L_SEQ * DMODEL / 4 / 256), 256, 0, stream>>>(x, xH, xL);

    // 1) xz = x @ W_in   (2048x1024 @ 1024x4096)
    gemm_pre<4><<<dim3(2 * DINNER / 128, L_SEQ / 128, 1), 256, 0, stream>>>(
        xH, xL, WinT, xz, L_SEQ, 2 * DINNER, DMODEL, DMODEL);
    // 2) u = silu(conv(xc)) (+ fp16 hi/lo split)
    conv_silu_kernel<<<dim3(DINNER / 256, L_SEQ), 256, 0, stream>>>(xz, conv_w, conv_b, u, uH, uL);
    // 3) x_dbl = u @ W_x   (split-K)
    gemm3_splitk<<<dim3(KS3, L_SEQ / 64), 256, 0, stream>>>(uH, uL, WxT, part);
    reduce_part<<<dim3(L_SEQ * NXDBL / 4 / 256), 256, 0, stream>>>(part, x_dbl);
    // 4) delta = softplus(dlt @ W_dt + b_dt)   (overwrites part region - safe)
    delta_kernel<<<dim3(DINNER / 256, L_SEQ / 16), 256, 0, stream>>>(x_dbl, W_dt, b_dt, delta);
    // 5) parallel scan (phase1 overwrites uH/uL; phase3 overwrites WinT/aprod)
    scan_phase1<<<dim3(DINNER / 256, CCH), 256, 0, stream>>>(u, delta, x_dbl, A_log, aprod, hacc);
    scan_phase2<<<dim3(DINNER * DSTATE / 256), 256, 0, stream>>>(aprod, hacc);
    scan_phase3<<<dim3(DINNER / 256, CCH), 256, 0, stream>>>(xz, u, delta, x_dbl, A_log, D_par, hacc, gH, gL);
    // 6) out = g @ W_out   (2048x2048 @ 2048x1024), split-K x2 + reduce
    gemm_pre<2><<<dim3(DMODEL / 128, L_SEQ / 64, 2), 256, 0, stream>>>(
        gH, gL, WoutT, part6, L_SEQ, DMODEL, DINNER, DINNER / 2);
    reduce6<<<dim3(L_SEQ * DMODEL / 4 / 256), 256, 0, stream>>>(part6, out);
}

// Round 10
// 291.547 us; speedup vs baseline: 4.0269x; 1.0716x over previous
//
#include <hip/hip_runtime.h>
#include <hip/hip_bf16.h>
#include <math.h>

// Problem constants
#define L_SEQ   2048
#define DMODEL  1024
#define DINNER  2048
#define DSTATE  16
#define DCONV   4
#define DTRANK  64
#define NXDBL   96   // DT_RANK + 2*D_STATE

#define CCH 64   // time chunks for parallel scan
#define TC  32   // timesteps per chunk (CCH*TC == L_SEQ)
#define KS3 16   // split-K factor for GEMM3

#define LOG2E 1.44269504088896340736f

typedef _Float16 half8v __attribute__((ext_vector_type(8)));
typedef _Float16 half4v __attribute__((ext_vector_type(4)));
typedef float f32x4 __attribute__((ext_vector_type(4)));

// fp16x2 split: a = (fp16)a + (fp16)(a - (float)(fp16)a), ~22 mantissa bits.
struct H2 { _Float16 h, l; };
__device__ __forceinline__ H2 splitf16(float v) {
    H2 r;
    r.h = (_Float16)v;
    r.l = (_Float16)(v - (float)r.h);
    return r;
}

// ---------------------------------------------------------------------------
// Fused prep: 3 weight transposes (fp32 [K][N] -> fp16 [N][K]) + x hi/lo split
// in ONE launch; blockIdx.x ranges select the task.
// ---------------------------------------------------------------------------
__device__ __forceinline__ void trans_tile(
    float (*tile)[33], const float* __restrict__ W, _Float16* __restrict__ WT,
    int K, int N, int k0, int n0, int tid)
{
    const int r = tid >> 3, c4 = (tid & 7) * 4;
    const float4 w4 = *(const float4*)(W + (size_t)(k0 + r) * N + n0 + c4);
    tile[r][c4 + 0] = w4.x;
    tile[r][c4 + 1] = w4.y;
    tile[r][c4 + 2] = w4.z;
    tile[r][c4 + 3] = w4.w;
    __syncthreads();
    half4v h;
#pragma unroll
    for (int j = 0; j < 4; ++j) h[j] = (_Float16)tile[c4 + j][r];
    *(half4v*)(WT + (size_t)(n0 + r) * K + k0 + c4) = h;
}

__global__ __launch_bounds__(256) void prep_all(
    const float* __restrict__ W_in, const float* __restrict__ W_out,
    const float* __restrict__ W_x, const float* __restrict__ x,
    _Float16* __restrict__ WinT, _Float16* __restrict__ WoutT,
    _Float16* __restrict__ WxT, _Float16* __restrict__ xH, _Float16* __restrict__ xL)
{
    __shared__ float tile[32][33];
    const int tid = threadIdx.x;
    int b = blockIdx.x;
    if (b < 4096) {                 // W_in: K=1024, N=4096 (128 n-blocks, 32 k-blocks)
        trans_tile(tile, W_in, WinT, DMODEL, 2 * DINNER, (b >> 7) * 32, (b & 127) * 32, tid);
    } else if (b < 6144) {          // W_out: K=2048, N=1024 (32 n, 64 k)
        b -= 4096;
        trans_tile(tile, W_out, WoutT, DINNER, DMODEL, (b >> 5) * 32, (b & 31) * 32, tid);
    } else if (b < 6336) {          // W_x: K=2048, N=96 (3 n, 64 k)
        b -= 6144;
        trans_tile(tile, W_x, WxT, DINNER, NXDBL, (b / 3) * 32, (b % 3) * 32, tid);
    } else {                        // x split: 2048 blocks x 256 thr x 4 elems
        b -= 6336;
        const size_t i = ((size_t)b * 256 + tid) * 4;
        const float4 v4 = *(const float4*)(x + i);
        const float v[4] = {v4.x, v4.y, v4.z, v4.w};
        half4v h, l;
#pragma unroll
        for (int j = 0; j < 4; ++j) {
            const H2 s = splitf16(v[j]);
            h[j] = s.h;
            l[j] = s.l;
        }
        *(half4v*)(xH + i) = h;
        *(half4v*)(xL + i) = l;
    }
}

// ---------------------------------------------------------------------------
// fp16x2 MFMA GEMM, BK=64 (unchanged from R9): C = A@B, split-K via blockIdx.z.
// ---------------------------------------------------------------------------
template <int WMI>
__global__ __launch_bounds__(256) void gemm_pre(
    const _Float16* __restrict__ AH, const _Float16* __restrict__ AL,
    const _Float16* __restrict__ BH, float* __restrict__ C,
    int M, int N, int K, int Klen)
{
    constexpr int BM = WMI * 32;
    __shared__ __align__(16) _Float16 AsH[BM * 64];
    __shared__ __align__(16) _Float16 AsL[BM * 64];
    __shared__ __align__(16) _Float16 Bs[128 * 64];

    const int tid = threadIdx.x;
    const int lane = tid & 63;
    const int wave = tid >> 6;
    const int wm = wave >> 1, wn = wave & 1;
    const int bm = blockIdx.y * BM;
    const int bn = blockIdx.x * 128;
    const int koff = blockIdx.z * Klen;
    C += (size_t)blockIdx.z * M * N;
    const int l16 = lane & 15;
    const int kq = lane >> 4;

    f32x4 acc[WMI][4];
#pragma unroll
    for (int mi = 0; mi < WMI; ++mi)
#pragma unroll
        for (int ni = 0; ni < 4; ++ni) acc[mi][ni] = {0.f, 0.f, 0.f, 0.f};

    for (int k0 = koff; k0 < koff + Klen; k0 += 64) {
        __syncthreads();
#pragma unroll
        for (int i = 0; i < (BM * 8) / 256; ++i) {
            const int c = tid + 256 * i;
            const int row = c >> 3, g = c & 7;
            const int dst = row * 64 + ((g ^ (row & 7)) * 8);
            const size_t src = (size_t)(bm + row) * K + k0 + g * 8;
            *(half8v*)&AsH[dst] = *(const half8v*)(AH + src);
            *(half8v*)&AsL[dst] = *(const half8v*)(AL + src);
        }
#pragma unroll
        for (int i = 0; i < 4; ++i) {
            const int c = tid + 256 * i;
            const int row = c >> 3, g = c & 7;
            const int dst = row * 64 + ((g ^ (row & 7)) * 8);
            const size_t src = (size_t)(bn + row) * K + k0 + g * 8;
            *(half8v*)&Bs[dst] = *(const half8v*)(BH + src);
        }
        __syncthreads();

#pragma unroll
        for (int kk = 0; kk < 2; ++kk) {
            half8v ah[WMI], al[WMI], bh[4];
#pragma unroll
            for (int mi = 0; mi < WMI; ++mi) {
                const int r = (wm * WMI + mi) * 16 + l16;
                const int off = r * 64 + (((kk * 4 + kq) ^ (r & 7)) * 8);
                ah[mi] = *(const half8v*)&AsH[off];
                al[mi] = *(const half8v*)&AsL[off];
            }
#pragma unroll
            for (int ni = 0; ni < 4; ++ni) {
                const int r = wn * 64 + ni * 16 + l16;
                const int off = r * 64 + (((kk * 4 + kq) ^ (r & 7)) * 8);
                bh[ni] = *(const half8v*)&Bs[off];
            }
#pragma unroll
            for (int mi = 0; mi < WMI; ++mi)
#pragma unroll
                for (int ni = 0; ni < 4; ++ni) {
                    acc[mi][ni] = __builtin_amdgcn_mfma_f32_16x16x32_f16(ah[mi], bh[ni], acc[mi][ni], 0, 0, 0);
                    acc[mi][ni] = __builtin_amdgcn_mfma_f32_16x16x32_f16(al[mi], bh[ni], acc[mi][ni], 0, 0, 0);
                }
        }
    }

#pragma unroll
    for (int mi = 0; mi < WMI; ++mi)
#pragma unroll
        for (int ni = 0; ni < 4; ++ni) {
            const int col = bn + wn * 64 + ni * 16 + l16;
#pragma unroll
            for (int r = 0; r < 4; ++r) {
                const int row = bm + (wm * WMI + mi) * 16 + kq * 4 + r;
                C[(size_t)row * N + col] = acc[mi][ni][r];
            }
        }
}

// ---------------------------------------------------------------------------
// Sum 2 split-K partials into out (GEMM6).
// ---------------------------------------------------------------------------
__global__ __launch_bounds__(256) void reduce6(
    const float* __restrict__ part, float* __restrict__ out)
{
    const size_t i = ((size_t)blockIdx.x * 256 + threadIdx.x) * 4;
    const float4 a = *(const float4*)(part + i);
    const float4 b = *(const float4*)(part + (size_t)L_SEQ * DMODEL + i);
    *(float4*)(out + i) = make_float4(a.x + b.x, a.y + b.y, a.z + b.z, a.w + b.w);
}

// ---------------------------------------------------------------------------
// GEMM3 split-K with FUSED conv+SiLU A-staging (u never materialized).
// Block: 64 t-rows x 96 n x 128-d k-chunk, grid (KS3, 32) = 512 blocks.
// Single-stage: A (conv from xz -> fp16 hi/lo) and B staged ONCE, one barrier,
// then 4 barrier-free k-steps. 16-granule XOR swizzle g^(row&15).
// ---------------------------------------------------------------------------
__global__ __launch_bounds__(256) void gemm3_conv(
    const float* __restrict__ xz, const float* __restrict__ conv_w,
    const float* __restrict__ conv_b, const _Float16* __restrict__ BH,
    float* __restrict__ part)
{
    __shared__ __align__(16) _Float16 AsH[64 * 128];
    __shared__ __align__(16) _Float16 AsL[64 * 128];
    __shared__ __align__(16) _Float16 Bs[96 * 128];
    __shared__ float4 scw[128];
    __shared__ float scb[128];

    const int tid = threadIdx.x;
    const int lane = tid & 63;
    const int wave = tid >> 6;
    const int wm = wave & 1, wn = wave >> 1;
    const int ks = blockIdx.x;
    const int bm = blockIdx.y * 64;
    const int kbase = ks * (DINNER / KS3);   // 128-wide d-chunk
    const int l16 = lane & 15;
    const int kq = lane >> 4;

    // stage conv weights for this d-chunk
    if (tid < 128) {
        scw[tid] = *(const float4*)(conv_w + (size_t)(kbase + tid) * DCONV);
        scb[tid] = conv_b[kbase + tid];
    }
    __syncthreads();

    // --- stage A: compute u = silu(conv(xz)) for 64 t x 128 d, split hi/lo
    {
        const int row = tid >> 2;            // t-row 0..63
        const int dseg = (tid & 3) * 32;     // d-offset 0,32,64,96
        float ua[32];
#pragma unroll
        for (int jj = 0; jj < 32; ++jj) ua[jj] = scb[dseg + jj];
#pragma unroll
        for (int j = 0; j < DCONV; ++j) {
            const int t = bm + row - (DCONV - 1) + j;
            if (t >= 0) {
#pragma unroll
                for (int q = 0; q < 8; ++q) {
                    const float4 xv = *(const float4*)(xz + (size_t)t * (2 * DINNER) + kbase + dseg + q * 4);
                    const float xe[4] = {xv.x, xv.y, xv.z, xv.w};
#pragma unroll
                    for (int e = 0; e < 4; ++e) {
                        const float w = ((const float*)&scw[dseg + q * 4 + e])[j];
                        ua[q * 4 + e] = fmaf(xe[e], w, ua[q * 4 + e]);
                    }
                }
            }
        }
#pragma unroll
        for (int q = 0; q < 4; ++q) {        // 4 granules of 8 halves
            half8v h, l;
#pragma unroll
            for (int e = 0; e < 8; ++e) {
                const float a = ua[q * 8 + e];
                const float s = a / (1.f + __expf(-a));
                const H2 sp = splitf16(s);
                h[e] = sp.h;
                l[e] = sp.l;
            }
            const int g = (dseg >> 3) + q;   // granule 0..15
            const int dst = row * 128 + ((g ^ (row & 15)) * 8);
            *(half8v*)&AsH[dst] = h;
            *(half8v*)&AsL[dst] = l;
        }
    }
    // --- stage B: 96 rows x 16 granules = 1536, 6 per thread
#pragma unroll
    for (int i = 0; i < 6; ++i) {
        const int lin = tid + 256 * i;
        const int row = lin >> 4, g = lin & 15;
        const int dst = row * 128 + ((g ^ (row & 15)) * 8);
        *(half8v*)&Bs[dst] = *(const half8v*)(BH + (size_t)row * DINNER + kbase + g * 8);
    }
    __syncthreads();

    f32x4 acc[2][3];
#pragma unroll
    for (int mi = 0; mi < 2; ++mi)
#pragma unroll
        for (int ni = 0; ni < 3; ++ni) acc[mi][ni] = {0.f, 0.f, 0.f, 0.f};

#pragma unroll
    for (int kk = 0; kk < 4; ++kk) {
        half8v ah[2], al[2], bh[3];
#pragma unroll
        for (int mi = 0; mi < 2; ++mi) {
            const int r = wm * 32 + mi * 16 + l16;
            const int off = r * 128 + (((kk * 4 + kq) ^ (r & 15)) * 8);
            ah[mi] = *(const half8v*)&AsH[off];
            al[mi] = *(const half8v*)&AsL[off];
        }
#pragma unroll
        for (int ni = 0; ni < 3; ++ni) {
            const int r = wn * 48 + ni * 16 + l16;
            const int off = r * 128 + (((kk * 4 + kq) ^ (r & 15)) * 8);
            bh[ni] = *(const half8v*)&Bs[off];
        }
#pragma unroll
        for (int mi = 0; mi < 2; ++mi)
#pragma unroll
            for (int ni = 0; ni < 3; ++ni) {
                acc[mi][ni] = __builtin_amdgcn_mfma_f32_16x16x32_f16(ah[mi], bh[ni], acc[mi][ni], 0, 0, 0);
                acc[mi][ni] = __builtin_amdgcn_mfma_f32_16x16x32_f16(al[mi], bh[ni], acc[mi][ni], 0, 0, 0);
            }
    }

#pragma unroll
    for (int mi = 0; mi < 2; ++mi)
#pragma unroll
        for (int ni = 0; ni < 3; ++ni) {
            const int col = wn * 48 + ni * 16 + l16;
#pragma unroll
            for (int r = 0; r < 4; ++r) {
                const int row = bm + wm * 32 + mi * 16 + kq * 4 + r;
                part[((size_t)ks * L_SEQ + row) * NXDBL + col] = acc[mi][ni][r];
            }
        }
}

// ---------------------------------------------------------------------------
// Fused reduce + delta: sums the KS3 dlt partials in LDS, computes
// delta = softplus(dlt @ W_dt + b_dt), and (y==0) writes B/C cols of x_dbl.
// Grid (L_SEQ/16 = 128, 4); block handles 16 t x 512 d.
// ---------------------------------------------------------------------------
__global__ __launch_bounds__(256) void delta_bc(
    const float* __restrict__ part, const float* __restrict__ W_dt,
    const float* __restrict__ b_dt, float* __restrict__ delta,
    float* __restrict__ x_dbl)
{
    __shared__ float dl[16][64];
    const int tid = threadIdx.x;
    const int t0 = blockIdx.x * 16;
    const int d0 = blockIdx.y * 512;

    // stage dlt sum: 16t x 64k, each thread one float4
    {
        const int t = tid >> 4, k4 = (tid & 15) * 4;
        float4 s = make_float4(0.f, 0.f, 0.f, 0.f);
#pragma unroll 4
        for (int ks = 0; ks < KS3; ++ks) {
            const float4 p = *(const float4*)(part + ((size_t)ks * L_SEQ + t0 + t) * NXDBL + k4);
            s.x += p.x; s.y += p.y; s.z += p.z; s.w += p.w;
        }
        *(float4*)&dl[t][k4] = s;
    }
    // B/C cols 64..95 -> x_dbl (one y-block only)
    if (blockIdx.y == 0 && tid < 128) {
        const int t = tid >> 3, c4 = (tid & 7) * 4;
        float4 s = make_float4(0.f, 0.f, 0.f, 0.f);
#pragma unroll 4
        for (int ks = 0; ks < KS3; ++ks) {
            const float4 p = *(const float4*)(part + ((size_t)ks * L_SEQ + t0 + t) * NXDBL + DTRANK + c4);
            s.x += p.x; s.y += p.y; s.z += p.z; s.w += p.w;
        }
        *(float4*)(x_dbl + (size_t)(t0 + t) * NXDBL + DTRANK + c4) = s;
    }
    __syncthreads();

    // delta for 2 d's per thread (d, d+256)
    const int d = d0 + tid;
    float acc0[16], acc1[16];
    const float bb0 = b_dt[d], bb1 = b_dt[d + 256];
#pragma unroll
    for (int t = 0; t < 16; ++t) { acc0[t] = bb0; acc1[t] = bb1; }

    for (int k = 0; k < DTRANK; ++k) {
        const float w0 = W_dt[(size_t)k * DINNER + d];
        const float w1 = W_dt[(size_t)k * DINNER + d + 256];
#pragma unroll
        for (int t = 0; t < 16; ++t) {
            const float dv = dl[t][k];
            acc0[t] = fmaf(dv, w0, acc0[t]);
            acc1[t] = fmaf(dv, w1, acc1[t]);
        }
    }
#pragma unroll
    for (int t = 0; t < 16; ++t) {
        const float x0 = acc0[t], x1 = acc1[t];
        delta[(size_t)(t0 + t) * DINNER + d]       = (x0 > 20.f) ? x0 : log1pf(__expf(x0));
        delta[(size_t)(t0 + t) * DINNER + d + 256] = (x1 > 20.f) ? x1 : log1pf(__expf(x1));
    }
}

// ---------------------------------------------------------------------------
// Scan phase 1: lane = channel d; u computed inline from xz (rolling conv).
// ---------------------------------------------------------------------------
__global__ __launch_bounds__(256) void scan_phase1(
    const float* __restrict__ xz, const float* __restrict__ delta,
    const float* __restrict__ x_dbl, const float* __restrict__ A_log,
    const float* __restrict__ conv_w, const float* __restrict__ conv_b,
    float* __restrict__ aprod, float* __restrict__ hacc)
{
    __shared__ float sB[TC][16];

    const int tid = threadIdx.x;
    const int d = blockIdx.x * 256 + tid;
    const int ch = blockIdx.y;
    const int t0 = ch * TC;

    float A2[16];
#pragma unroll
    for (int j = 0; j < 4; ++j) {
        const float4 a4 = *(const float4*)(A_log + (size_t)d * DSTATE + j * 4);
        A2[4 * j + 0] = -__expf(a4.x) * LOG2E;
        A2[4 * j + 1] = -__expf(a4.y) * LOG2E;
        A2[4 * j + 2] = -__expf(a4.z) * LOG2E;
        A2[4 * j + 3] = -__expf(a4.w) * LOG2E;
    }
    const float4 cw = *(const float4*)(conv_w + (size_t)d * DCONV);
    const float cb = conv_b[d];

    for (int i = tid; i < TC * 16; i += 256) {
        const int tt = i >> 4, q = i & 15;
        sB[tt][q] = x_dbl[(size_t)(t0 + tt) * NXDBL + DTRANK + q];
    }
    __syncthreads();

    // rolling conv window
    float xw0 = (t0 >= 3) ? xz[(size_t)(t0 - 3) * (2 * DINNER) + d] : 0.f;
    float xw1 = (t0 >= 2) ? xz[(size_t)(t0 - 2) * (2 * DINNER) + d] : 0.f;
    float xw2 = (t0 >= 1) ? xz[(size_t)(t0 - 1) * (2 * DINNER) + d] : 0.f;

    float h[16];
#pragma unroll
    for (int n = 0; n < 16; ++n) h[n] = 0.f;
    float S = 0.f;

    for (int tt = 0; tt < TC; ++tt) {
        const int t = t0 + tt;
        const float xc = xz[(size_t)t * (2 * DINNER) + d];
        float a = cb;
        a = fmaf(xw0, cw.x, a);
        a = fmaf(xw1, cw.y, a);
        a = fmaf(xw2, cw.z, a);
        a = fmaf(xc, cw.w, a);
        const float uu = a / (1.f + __expf(-a));
        xw0 = xw1; xw1 = xw2; xw2 = xc;

        const float dt = delta[(size_t)t * DINNER + d];
        const float du = dt * uu;
        S += dt;
        float4 b[4];
#pragma unroll
        for (int j = 0; j < 4; ++j) b[j] = *(const float4*)&sB[tt][j * 4];
        const float* bp = (const float*)b;
#pragma unroll
        for (int n = 0; n < 16; ++n) {
            const float av = exp2f(dt * A2[n]);
            h[n] = fmaf(av, h[n], du * bp[n]);
        }
    }

    const size_t base = ((size_t)ch * DINNER + d) * DSTATE;
#pragma unroll
    for (int j = 0; j < 4; ++j) {
        float4 av, hv;
        av.x = exp2f(S * A2[4 * j + 0]);
        av.y = exp2f(S * A2[4 * j + 1]);
        av.z = exp2f(S * A2[4 * j + 2]);
        av.w = exp2f(S * A2[4 * j + 3]);
        hv.x = h[4 * j + 0]; hv.y = h[4 * j + 1];
        hv.z = h[4 * j + 2]; hv.w = h[4 * j + 3];
        *(float4*)(aprod + base + j * 4) = av;
        *(float4*)(hacc + base + j * 4) = hv;
    }
}

// ---------------------------------------------------------------------------
// Phase 2: exclusive scan over chunk summaries (hacc -> hinit in place).
// ---------------------------------------------------------------------------
__global__ __launch_bounds__(256) void scan_phase2(
    const float* __restrict__ aprod, float* __restrict__ hacc)
{
    const int i = blockIdx.x * 256 + threadIdx.x;
    float h0 = 0.f;
#pragma unroll 4
    for (int c = 0; c < CCH; ++c) {
        const size_t idx = (size_t)c * DINNER * DSTATE + i;
        const float a  = aprod[idx];
        const float hc = hacc[idx];
        hacc[idx] = h0;
        h0 = fmaf(a, h0, hc);
    }
}

// ---------------------------------------------------------------------------
// Phase 3: replay from corrected init with inline conv; gate; write g fp16.
// ---------------------------------------------------------------------------
__global__ __launch_bounds__(256) void scan_phase3(
    const float* __restrict__ xz, const float* __restrict__ delta,
    const float* __restrict__ x_dbl, const float* __restrict__ A_log,
    const float* __restrict__ conv_w, const float* __restrict__ conv_b,
    const float* __restrict__ D_param, const float* __restrict__ hinit,
    _Float16* __restrict__ gH, _Float16* __restrict__ gL)
{
    __shared__ float sBC[TC][32];   // [t][0..15]=B, [16..31]=C

    const int tid = threadIdx.x;
    const int d = blockIdx.x * 256 + tid;
    const int ch = blockIdx.y;
    const int t0 = ch * TC;

    float A2[16];
#pragma unroll
    for (int j = 0; j < 4; ++j) {
        const float4 a4 = *(const float4*)(A_log + (size_t)d * DSTATE + j * 4);
        A2[4 * j + 0] = -__expf(a4.x) * LOG2E;
        A2[4 * j + 1] = -__expf(a4.y) * LOG2E;
        A2[4 * j + 2] = -__expf(a4.z) * LOG2E;
        A2[4 * j + 3] = -__expf(a4.w) * LOG2E;
    }
    const float4 cw = *(const float4*)(conv_w + (size_t)d * DCONV);
    const float cb = conv_b[d];
    const float Dp = D_param[d];

    float h[16];
    {
        const size_t base = ((size_t)ch * DINNER + d) * DSTATE;
#pragma unroll
        for (int j = 0; j < 4; ++j) {
            const float4 hv = *(const float4*)(hinit + base + j * 4);
            h[4 * j + 0] = hv.x; h[4 * j + 1] = hv.y;
            h[4 * j + 2] = hv.z; h[4 * j + 3] = hv.w;
        }
    }

    for (int i = tid; i < TC * 32; i += 256) {
        const int tt = i >> 5, q = i & 31;
        sBC[tt][q] = x_dbl[(size_t)(t0 + tt) * NXDBL + DTRANK + q];
    }
    __syncthreads();

    float xw0 = (t0 >= 3) ? xz[(size_t)(t0 - 3) * (2 * DINNER) + d] : 0.f;
    float xw1 = (t0 >= 2) ? xz[(size_t)(t0 - 2) * (2 * DINNER) + d] : 0.f;
    float xw2 = (t0 >= 1) ? xz[(size_t)(t0 - 1) * (2 * DINNER) + d] : 0.f;

    for (int tt = 0; tt < TC; ++tt) {
        const int t = t0 + tt;
        const float xc = xz[(size_t)t * (2 * DINNER) + d];
        const float z  = xz[(size_t)t * (2 * DINNER) + DINNER + d];
        float a = cb;
        a = fmaf(xw0, cw.x, a);
        a = fmaf(xw1, cw.y, a);
        a = fmaf(xw2, cw.z, a);
        a = fmaf(xc, cw.w, a);
        const float uu = a / (1.f + __expf(-a));
        xw0 = xw1; xw1 = xw2; xw2 = xc;

        const float dt = delta[(size_t)t * DINNER + d];
        const float du = dt * uu;
        float4 b[4], c[4];
#pragma unroll
        for (int j = 0; j < 4; ++j) {
            b[j] = *(const float4*)&sBC[tt][j * 4];
            c[j] = *(const float4*)&sBC[tt][16 + j * 4];
        }
        const float* bp = (const float*)b;
        const float* cp = (const float*)c;
        float y = Dp * uu;
#pragma unroll
        for (int n = 0; n < 16; ++n) {
            const float av = exp2f(dt * A2[n]);
            h[n] = fmaf(av, h[n], du * bp[n]);
            y = fmaf(h[n], cp[n], y);
        }
        const float gate = z / (1.f + __expf(-z));
        const float gv = y * gate;
        const size_t idx = (size_t)t * DINNER + d;
        const H2 gs = splitf16(gv);
        gH[idx] = gs.h;
        gL[idx] = gs.l;
    }
}

// ---------------------------------------------------------------------------
extern "C" void kernel_launch(void* const* d_in, const int* in_sizes, int n_in,
                              void* d_out, int out_size, void* d_ws, size_t ws_size,
                              hipStream_t stream)
{
    const float* x      = (const float*)d_in[0];
    const float* W_in   = (const float*)d_in[1];
    const float* conv_w = (const float*)d_in[2];
    const float* conv_b = (const float*)d_in[3];
    const float* W_x    = (const float*)d_in[4];
    const float* W_dt   = (const float*)d_in[5];
    const float* b_dt   = (const float*)d_in[6];
    const float* A_log  = (const float*)d_in[7];
    const float* D_par  = (const float*)d_in[8];
    const float* W_out  = (const float*)d_in[9];
    float* out = (float*)d_out;

    float* ws    = (float*)d_ws;
    float* xz    = ws;                                    // 8M f32 (32 MB)
    float* part  = xz + (size_t)L_SEQ * 2 * DINNER;       // 16*2048*96 f32 (12.6 MB, old u slot 16 MB)
    float* x_dbl = part + (size_t)L_SEQ * DINNER;         // 2048*96 f32
    float* delta = x_dbl + (size_t)L_SEQ * NXDBL;         // 4M f32 (16 MB)
    float* aprod = delta + (size_t)L_SEQ * DINNER;        // 2M f32 (8 MB)
    float* hacc  = aprod + (size_t)CCH * DINNER * DSTATE; // 2M f32 (8 MB)
    _Float16* WinT  = (_Float16*)(hacc + (size_t)CCH * DINNER * DSTATE); // [4096][1024] (8 MB)
    _Float16* WoutT = WinT + (size_t)(2 * DINNER) * DMODEL;              // [1024][2048] (4 MB)
    _Float16* WxT   = WoutT + (size_t)DMODEL * DINNER;                   // [96][2048]

    // Aliases (lifetimes verified):
    // xH/xL <- delta buffer: used prep->G1; delta written by delta_bc (step 4).
    _Float16* xH = (_Float16*)delta;
    _Float16* xL = xH + (size_t)L_SEQ * DMODEL;
    // gH <- WinT (dead after G1); gL <- aprod (read by p2, then dead).
    _Float16* gH = WinT;
    _Float16* gL = (_Float16*)aprod;
    // part6 <- xz (dead after phase3 reads xc/z).
    float* part6 = xz;

    // 1) fused prep: W transposes + x split (8384 blocks)
    prep_all<<<dim3(8384), 256, 0, stream>>>(W_in, W_out, W_x, x, WinT, WoutT, WxT, xH, xL);
    // 2) xz = x @ W_in
    gemm_pre<4><<<dim3(2 * DINNER / 128, L_SEQ / 128, 1), 256, 0, stream>>>(
        xH, xL, WinT, xz, L_SEQ, 2 * DINNER, DMODEL, DMODEL);
    // 3) part = conv+silu(xz) @ W_x (fused, split-K)
    gemm3_conv<<<dim3(KS3, L_SEQ / 64), 256, 0, stream>>>(xz, conv_w, conv_b, WxT, part);
    // 4) delta + B/C reduction (fused)
    delta_bc<<<dim3(L_SEQ / 16, 4), 256, 0, stream>>>(part, W_dt, b_dt, delta, x_dbl);
    // 5) parallel scan (conv inline; u never materialized)
    scan_phase1<<<dim3(DINNER / 256, CCH), 256, 0, stream>>>(xz, delta, x_dbl, A_log, conv_w, conv_b, aprod, hacc);
    scan_phase2<<<dim3(DINNER * DSTATE / 256), 256, 0, stream>>>(aprod, hacc);
    scan_phase3<<<dim3(DINNER / 256, CCH), 256, 0, stream>>>(xz, delta, x_dbl, A_log, conv_w, conv_b, D_par, hacc, gH, gL);
    // 6) out = g @ W_out, split-K x2 + reduce
    gemm_pre<2><<<dim3(DMODEL / 128, L_SEQ / 64, 2), 256, 0, stream>>>(
        gH, gL, WoutT, part6, L_SEQ, DMODEL, DINNER, DINNER / 2);
    reduce6<<<dim3(L_SEQ * DMODEL / 4 / 256), 256, 0, stream>>>(part6, out);
}

// Round 11
// 291.540 us; speedup vs baseline: 4.0269x; 1.0000x over previous
//
#include <hip/hip_runtime.h>
#include <hip/hip_bf16.h>
#include <math.h>

// Problem constants
#define L_SEQ   2048
#define DMODEL  1024
#define DINNER  2048
#define DSTATE  16
#define DCONV   4
#define DTRANK  64
#define NXDBL   96   // DT_RANK + 2*D_STATE

#define CCH 64   // time chunks for parallel scan
#define TC  32   // timesteps per chunk (CCH*TC == L_SEQ)
#define KS3 16   // split-K factor for GEMM3
#define KS6 4    // split-K factor for GEMM6

#define LOG2E 1.44269504088896340736f

typedef _Float16 half8v __attribute__((ext_vector_type(8)));
typedef _Float16 half4v __attribute__((ext_vector_type(4)));
typedef float f32x4 __attribute__((ext_vector_type(4)));

// fp16x2 split: a = (fp16)a + (fp16)(a - (float)(fp16)a), ~22 mantissa bits.
struct H2 { _Float16 h, l; };
__device__ __forceinline__ H2 splitf16(float v) {
    H2 r;
    r.h = (_Float16)v;
    r.l = (_Float16)(v - (float)r.h);
    return r;
}

// ---------------------------------------------------------------------------
// Fused prep: 3 weight transposes (fp32 [K][N] -> fp16 [N][K]) + x hi/lo split.
// ---------------------------------------------------------------------------
__device__ __forceinline__ void trans_tile(
    float (*tile)[33], const float* __restrict__ W, _Float16* __restrict__ WT,
    int K, int N, int k0, int n0, int tid)
{
    const int r = tid >> 3, c4 = (tid & 7) * 4;
    const float4 w4 = *(const float4*)(W + (size_t)(k0 + r) * N + n0 + c4);
    tile[r][c4 + 0] = w4.x;
    tile[r][c4 + 1] = w4.y;
    tile[r][c4 + 2] = w4.z;
    tile[r][c4 + 3] = w4.w;
    __syncthreads();
    half4v h;
#pragma unroll
    for (int j = 0; j < 4; ++j) h[j] = (_Float16)tile[c4 + j][r];
    *(half4v*)(WT + (size_t)(n0 + r) * K + k0 + c4) = h;
}

__global__ __launch_bounds__(256) void prep_all(
    const float* __restrict__ W_in, const float* __restrict__ W_out,
    const float* __restrict__ W_x, const float* __restrict__ x,
    _Float16* __restrict__ WinT, _Float16* __restrict__ WoutT,
    _Float16* __restrict__ WxT, _Float16* __restrict__ xH, _Float16* __restrict__ xL)
{
    __shared__ float tile[32][33];
    const int tid = threadIdx.x;
    int b = blockIdx.x;
    if (b < 4096) {                 // W_in: K=1024, N=4096
        trans_tile(tile, W_in, WinT, DMODEL, 2 * DINNER, (b >> 7) * 32, (b & 127) * 32, tid);
    } else if (b < 6144) {          // W_out: K=2048, N=1024
        b -= 4096;
        trans_tile(tile, W_out, WoutT, DINNER, DMODEL, (b >> 5) * 32, (b & 31) * 32, tid);
    } else if (b < 6336) {          // W_x: K=2048, N=96
        b -= 6144;
        trans_tile(tile, W_x, WxT, DINNER, NXDBL, (b / 3) * 32, (b % 3) * 32, tid);
    } else {                        // x split
        b -= 6336;
        const size_t i = ((size_t)b * 256 + tid) * 4;
        const float4 v4 = *(const float4*)(x + i);
        const float v[4] = {v4.x, v4.y, v4.z, v4.w};
        half4v h, l;
#pragma unroll
        for (int j = 0; j < 4; ++j) {
            const H2 s = splitf16(v[j]);
            h[j] = s.h;
            l[j] = s.l;
        }
        *(half4v*)(xH + i) = h;
        *(half4v*)(xL + i) = l;
    }
}

// ---------------------------------------------------------------------------
// fp16x2 MFMA GEMM, BK=64, BM=64 tile (high-occupancy): C = A@B, split-K via
// blockIdx.z (Klen==K, z==1 -> plain). 4 blocks/CU via __launch_bounds__(256,4).
// ---------------------------------------------------------------------------
template <int WMI>
__global__ __launch_bounds__(256, 4) void gemm_pre(
    const _Float16* __restrict__ AH, const _Float16* __restrict__ AL,
    const _Float16* __restrict__ BH, float* __restrict__ C,
    int M, int N, int K, int Klen)
{
    constexpr int BM = WMI * 32;
    __shared__ __align__(16) _Float16 AsH[BM * 64];
    __shared__ __align__(16) _Float16 AsL[BM * 64];
    __shared__ __align__(16) _Float16 Bs[128 * 64];

    const int tid = threadIdx.x;
    const int lane = tid & 63;
    const int wave = tid >> 6;
    const int wm = wave >> 1, wn = wave & 1;
    const int bm = blockIdx.y * BM;
    const int bn = blockIdx.x * 128;
    const int koff = blockIdx.z * Klen;
    C += (size_t)blockIdx.z * M * N;
    const int l16 = lane & 15;
    const int kq = lane >> 4;

    f32x4 acc[WMI][4];
#pragma unroll
    for (int mi = 0; mi < WMI; ++mi)
#pragma unroll
        for (int ni = 0; ni < 4; ++ni) acc[mi][ni] = {0.f, 0.f, 0.f, 0.f};

    for (int k0 = koff; k0 < koff + Klen; k0 += 64) {
        __syncthreads();
#pragma unroll
        for (int i = 0; i < (BM * 8) / 256; ++i) {
            const int c = tid + 256 * i;
            const int row = c >> 3, g = c & 7;
            const int dst = row * 64 + ((g ^ (row & 7)) * 8);
            const size_t src = (size_t)(bm + row) * K + k0 + g * 8;
            *(half8v*)&AsH[dst] = *(const half8v*)(AH + src);
            *(half8v*)&AsL[dst] = *(const half8v*)(AL + src);
        }
#pragma unroll
        for (int i = 0; i < 4; ++i) {
            const int c = tid + 256 * i;
            const int row = c >> 3, g = c & 7;
            const int dst = row * 64 + ((g ^ (row & 7)) * 8);
            const size_t src = (size_t)(bn + row) * K + k0 + g * 8;
            *(half8v*)&Bs[dst] = *(const half8v*)(BH + src);
        }
        __syncthreads();

#pragma unroll
        for (int kk = 0; kk < 2; ++kk) {
            half8v ah[WMI], al[WMI], bh[4];
#pragma unroll
            for (int mi = 0; mi < WMI; ++mi) {
                const int r = (wm * WMI + mi) * 16 + l16;
                const int off = r * 64 + (((kk * 4 + kq) ^ (r & 7)) * 8);
                ah[mi] = *(const half8v*)&AsH[off];
                al[mi] = *(const half8v*)&AsL[off];
            }
#pragma unroll
            for (int ni = 0; ni < 4; ++ni) {
                const int r = wn * 64 + ni * 16 + l16;
                const int off = r * 64 + (((kk * 4 + kq) ^ (r & 7)) * 8);
                bh[ni] = *(const half8v*)&Bs[off];
            }
#pragma unroll
            for (int mi = 0; mi < WMI; ++mi)
#pragma unroll
                for (int ni = 0; ni < 4; ++ni) {
                    acc[mi][ni] = __builtin_amdgcn_mfma_f32_16x16x32_f16(ah[mi], bh[ni], acc[mi][ni], 0, 0, 0);
                    acc[mi][ni] = __builtin_amdgcn_mfma_f32_16x16x32_f16(al[mi], bh[ni], acc[mi][ni], 0, 0, 0);
                }
        }
    }

#pragma unroll
    for (int mi = 0; mi < WMI; ++mi)
#pragma unroll
        for (int ni = 0; ni < 4; ++ni) {
            const int col = bn + wn * 64 + ni * 16 + l16;
#pragma unroll
            for (int r = 0; r < 4; ++r) {
                const int row = bm + (wm * WMI + mi) * 16 + kq * 4 + r;
                C[(size_t)row * N + col] = acc[mi][ni][r];
            }
        }
}

// ---------------------------------------------------------------------------
// Sum KS6 split-K partials into out (GEMM6).
// ---------------------------------------------------------------------------
__global__ __launch_bounds__(256) void reduce6(
    const float* __restrict__ part, float* __restrict__ out)
{
    const size_t i = ((size_t)blockIdx.x * 256 + threadIdx.x) * 4;
    float4 s = make_float4(0.f, 0.f, 0.f, 0.f);
#pragma unroll
    for (int z = 0; z < KS6; ++z) {
        const float4 p = *(const float4*)(part + (size_t)z * L_SEQ * DMODEL + i);
        s.x += p.x; s.y += p.y; s.z += p.z; s.w += p.w;
    }
    *(float4*)(out + i) = s;
}

// ---------------------------------------------------------------------------
// GEMM3 split-K with FUSED conv+SiLU A-staging (u never materialized).
// ---------------------------------------------------------------------------
__global__ __launch_bounds__(256) void gemm3_conv(
    const float* __restrict__ xz, const float* __restrict__ conv_w,
    const float* __restrict__ conv_b, const _Float16* __restrict__ BH,
    float* __restrict__ part)
{
    __shared__ __align__(16) _Float16 AsH[64 * 128];
    __shared__ __align__(16) _Float16 AsL[64 * 128];
    __shared__ __align__(16) _Float16 Bs[96 * 128];
    __shared__ float4 scw[128];
    __shared__ float scb[128];

    const int tid = threadIdx.x;
    const int lane = tid & 63;
    const int wave = tid >> 6;
    const int wm = wave & 1, wn = wave >> 1;
    const int ks = blockIdx.x;
    const int bm = blockIdx.y * 64;
    const int kbase = ks * (DINNER / KS3);
    const int l16 = lane & 15;
    const int kq = lane >> 4;

    if (tid < 128) {
        scw[tid] = *(const float4*)(conv_w + (size_t)(kbase + tid) * DCONV);
        scb[tid] = conv_b[kbase + tid];
    }
    __syncthreads();

    {
        const int row = tid >> 2;
        const int dseg = (tid & 3) * 32;
        float ua[32];
#pragma unroll
        for (int jj = 0; jj < 32; ++jj) ua[jj] = scb[dseg + jj];
#pragma unroll
        for (int j = 0; j < DCONV; ++j) {
            const int t = bm + row - (DCONV - 1) + j;
            if (t >= 0) {
#pragma unroll
                for (int q = 0; q < 8; ++q) {
                    const float4 xv = *(const float4*)(xz + (size_t)t * (2 * DINNER) + kbase + dseg + q * 4);
                    const float xe[4] = {xv.x, xv.y, xv.z, xv.w};
#pragma unroll
                    for (int e = 0; e < 4; ++e) {
                        const float w = ((const float*)&scw[dseg + q * 4 + e])[j];
                        ua[q * 4 + e] = fmaf(xe[e], w, ua[q * 4 + e]);
                    }
                }
            }
        }
#pragma unroll
        for (int q = 0; q < 4; ++q) {
            half8v h, l;
#pragma unroll
            for (int e = 0; e < 8; ++e) {
                const float a = ua[q * 8 + e];
                const float s = a / (1.f + __expf(-a));
                const H2 sp = splitf16(s);
                h[e] = sp.h;
                l[e] = sp.l;
            }
            const int g = (dseg >> 3) + q;
            const int dst = row * 128 + ((g ^ (row & 15)) * 8);
            *(half8v*)&AsH[dst] = h;
            *(half8v*)&AsL[dst] = l;
        }
    }
#pragma unroll
    for (int i = 0; i < 6; ++i) {
        const int lin = tid + 256 * i;
        const int row = lin >> 4, g = lin & 15;
        const int dst = row * 128 + ((g ^ (row & 15)) * 8);
        *(half8v*)&Bs[dst] = *(const half8v*)(BH + (size_t)row * DINNER + kbase + g * 8);
    }
    __syncthreads();

    f32x4 acc[2][3];
#pragma unroll
    for (int mi = 0; mi < 2; ++mi)
#pragma unroll
        for (int ni = 0; ni < 3; ++ni) acc[mi][ni] = {0.f, 0.f, 0.f, 0.f};

#pragma unroll
    for (int kk = 0; kk < 4; ++kk) {
        half8v ah[2], al[2], bh[3];
#pragma unroll
        for (int mi = 0; mi < 2; ++mi) {
            const int r = wm * 32 + mi * 16 + l16;
            const int off = r * 128 + (((kk * 4 + kq) ^ (r & 15)) * 8);
            ah[mi] = *(const half8v*)&AsH[off];
            al[mi] = *(const half8v*)&AsL[off];
        }
#pragma unroll
        for (int ni = 0; ni < 3; ++ni) {
            const int r = wn * 48 + ni * 16 + l16;
            const int off = r * 128 + (((kk * 4 + kq) ^ (r & 15)) * 8);
            bh[ni] = *(const half8v*)&Bs[off];
        }
#pragma unroll
        for (int mi = 0; mi < 2; ++mi)
#pragma unroll
            for (int ni = 0; ni < 3; ++ni) {
                acc[mi][ni] = __builtin_amdgcn_mfma_f32_16x16x32_f16(ah[mi], bh[ni], acc[mi][ni], 0, 0, 0);
                acc[mi][ni] = __builtin_amdgcn_mfma_f32_16x16x32_f16(al[mi], bh[ni], acc[mi][ni], 0, 0, 0);
            }
    }

#pragma unroll
    for (int mi = 0; mi < 2; ++mi)
#pragma unroll
        for (int ni = 0; ni < 3; ++ni) {
            const int col = wn * 48 + ni * 16 + l16;
#pragma unroll
            for (int r = 0; r < 4; ++r) {
                const int row = bm + wm * 32 + mi * 16 + kq * 4 + r;
                part[((size_t)ks * L_SEQ + row) * NXDBL + col] = acc[mi][ni][r];
            }
        }
}

// ---------------------------------------------------------------------------
// Fused reduce + delta: sums the KS3 dlt partials in LDS, computes
// delta = softplus(dlt @ W_dt + b_dt); y==0 blocks also write B/C of x_dbl.
// ---------------------------------------------------------------------------
__global__ __launch_bounds__(256) void delta_bc(
    const float* __restrict__ part, const float* __restrict__ W_dt,
    const float* __restrict__ b_dt, float* __restrict__ delta,
    float* __restrict__ x_dbl)
{
    __shared__ float dl[16][64];
    const int tid = threadIdx.x;
    const int t0 = blockIdx.x * 16;
    const int d0 = blockIdx.y * 512;

    {
        const int t = tid >> 4, k4 = (tid & 15) * 4;
        float4 s = make_float4(0.f, 0.f, 0.f, 0.f);
#pragma unroll 4
        for (int ks = 0; ks < KS3; ++ks) {
            const float4 p = *(const float4*)(part + ((size_t)ks * L_SEQ + t0 + t) * NXDBL + k4);
            s.x += p.x; s.y += p.y; s.z += p.z; s.w += p.w;
        }
        *(float4*)&dl[t][k4] = s;
    }
    if (blockIdx.y == 0 && tid < 128) {
        const int t = tid >> 3, c4 = (tid & 7) * 4;
        float4 s = make_float4(0.f, 0.f, 0.f, 0.f);
#pragma unroll 4
        for (int ks = 0; ks < KS3; ++ks) {
            const float4 p = *(const float4*)(part + ((size_t)ks * L_SEQ + t0 + t) * NXDBL + DTRANK + c4);
            s.x += p.x; s.y += p.y; s.z += p.z; s.w += p.w;
        }
        *(float4*)(x_dbl + (size_t)(t0 + t) * NXDBL + DTRANK + c4) = s;
    }
    __syncthreads();

    const int d = d0 + tid;
    float acc0[16], acc1[16];
    const float bb0 = b_dt[d], bb1 = b_dt[d + 256];
#pragma unroll
    for (int t = 0; t < 16; ++t) { acc0[t] = bb0; acc1[t] = bb1; }

    for (int k = 0; k < DTRANK; ++k) {
        const float w0 = W_dt[(size_t)k * DINNER + d];
        const float w1 = W_dt[(size_t)k * DINNER + d + 256];
#pragma unroll
        for (int t = 0; t < 16; ++t) {
            const float dv = dl[t][k];
            acc0[t] = fmaf(dv, w0, acc0[t]);
            acc1[t] = fmaf(dv, w1, acc1[t]);
        }
    }
#pragma unroll
    for (int t = 0; t < 16; ++t) {
        const float x0 = acc0[t], x1 = acc1[t];
        delta[(size_t)(t0 + t) * DINNER + d]       = (x0 > 20.f) ? x0 : log1pf(__expf(x0));
        delta[(size_t)(t0 + t) * DINNER + d + 256] = (x1 > 20.f) ? x1 : log1pf(__expf(x1));
    }
}

// ---------------------------------------------------------------------------
// Scan phase 1: lane = channel d; u computed inline from xz (rolling conv).
// ---------------------------------------------------------------------------
__global__ __launch_bounds__(256) void scan_phase1(
    const float* __restrict__ xz, const float* __restrict__ delta,
    const float* __restrict__ x_dbl, const float* __restrict__ A_log,
    const float* __restrict__ conv_w, const float* __restrict__ conv_b,
    float* __restrict__ aprod, float* __restrict__ hacc)
{
    __shared__ float sB[TC][16];

    const int tid = threadIdx.x;
    const int d = blockIdx.x * 256 + tid;
    const int ch = blockIdx.y;
    const int t0 = ch * TC;

    float A2[16];
#pragma unroll
    for (int j = 0; j < 4; ++j) {
        const float4 a4 = *(const float4*)(A_log + (size_t)d * DSTATE + j * 4);
        A2[4 * j + 0] = -__expf(a4.x) * LOG2E;
        A2[4 * j + 1] = -__expf(a4.y) * LOG2E;
        A2[4 * j + 2] = -__expf(a4.z) * LOG2E;
        A2[4 * j + 3] = -__expf(a4.w) * LOG2E;
    }
    const float4 cw = *(const float4*)(conv_w + (size_t)d * DCONV);
    const float cb = conv_b[d];

    for (int i = tid; i < TC * 16; i += 256) {
        const int tt = i >> 4, q = i & 15;
        sB[tt][q] = x_dbl[(size_t)(t0 + tt) * NXDBL + DTRANK + q];
    }
    __syncthreads();

    float xw0 = (t0 >= 3) ? xz[(size_t)(t0 - 3) * (2 * DINNER) + d] : 0.f;
    float xw1 = (t0 >= 2) ? xz[(size_t)(t0 - 2) * (2 * DINNER) + d] : 0.f;
    float xw2 = (t0 >= 1) ? xz[(size_t)(t0 - 1) * (2 * DINNER) + d] : 0.f;

    float h[16];
#pragma unroll
    for (int n = 0; n < 16; ++n) h[n] = 0.f;
    float S = 0.f;

    for (int tt = 0; tt < TC; ++tt) {
        const int t = t0 + tt;
        const float xc = xz[(size_t)t * (2 * DINNER) + d];
        float a = cb;
        a = fmaf(xw0, cw.x, a);
        a = fmaf(xw1, cw.y, a);
        a = fmaf(xw2, cw.z, a);
        a = fmaf(xc, cw.w, a);
        const float uu = a / (1.f + __expf(-a));
        xw0 = xw1; xw1 = xw2; xw2 = xc;

        const float dt = delta[(size_t)t * DINNER + d];
        const float du = dt * uu;
        S += dt;
        float4 b[4];
#pragma unroll
        for (int j = 0; j < 4; ++j) b[j] = *(const float4*)&sB[tt][j * 4];
        const float* bp = (const float*)b;
#pragma unroll
        for (int n = 0; n < 16; ++n) {
            const float av = exp2f(dt * A2[n]);
            h[n] = fmaf(av, h[n], du * bp[n]);
        }
    }

    const size_t base = ((size_t)ch * DINNER + d) * DSTATE;
#pragma unroll
    for (int j = 0; j < 4; ++j) {
        float4 av, hv;
        av.x = exp2f(S * A2[4 * j + 0]);
        av.y = exp2f(S * A2[4 * j + 1]);
        av.z = exp2f(S * A2[4 * j + 2]);
        av.w = exp2f(S * A2[4 * j + 3]);
        hv.x = h[4 * j + 0]; hv.y = h[4 * j + 1];
        hv.z = h[4 * j + 2]; hv.w = h[4 * j + 3];
        *(float4*)(aprod + base + j * 4) = av;
        *(float4*)(hacc + base + j * 4) = hv;
    }
}

// ---------------------------------------------------------------------------
// Phase 2: exclusive scan over chunk summaries (hacc -> hinit in place).
// ---------------------------------------------------------------------------
__global__ __launch_bounds__(256) void scan_phase2(
    const float* __restrict__ aprod, float* __restrict__ hacc)
{
    const int i = blockIdx.x * 256 + threadIdx.x;
    float h0 = 0.f;
#pragma unroll 4
    for (int c = 0; c < CCH; ++c) {
        const size_t idx = (size_t)c * DINNER * DSTATE + i;
        const float a  = aprod[idx];
        const float hc = hacc[idx];
        hacc[idx] = h0;
        h0 = fmaf(a, h0, hc);
    }
}

// ---------------------------------------------------------------------------
// Phase 3: replay from corrected init with inline conv; gate; write g fp16.
// ---------------------------------------------------------------------------
__global__ __launch_bounds__(256) void scan_phase3(
    const float* __restrict__ xz, const float* __restrict__ delta,
    const float* __restrict__ x_dbl, const float* __restrict__ A_log,
    const float* __restrict__ conv_w, const float* __restrict__ conv_b,
    const float* __restrict__ D_param, const float* __restrict__ hinit,
    _Float16* __restrict__ gH, _Float16* __restrict__ gL)
{
    __shared__ float sBC[TC][32];

    const int tid = threadIdx.x;
    const int d = blockIdx.x * 256 + tid;
    const int ch = blockIdx.y;
    const int t0 = ch * TC;

    float A2[16];
#pragma unroll
    for (int j = 0; j < 4; ++j) {
        const float4 a4 = *(const float4*)(A_log + (size_t)d * DSTATE + j * 4);
        A2[4 * j + 0] = -__expf(a4.x) * LOG2E;
        A2[4 * j + 1] = -__expf(a4.y) * LOG2E;
        A2[4 * j + 2] = -__expf(a4.z) * LOG2E;
        A2[4 * j + 3] = -__expf(a4.w) * LOG2E;
    }
    const float4 cw = *(const float4*)(conv_w + (size_t)d * DCONV);
    const float cb = conv_b[d];
    const float Dp = D_param[d];

    float h[16];
    {
        const size_t base = ((size_t)ch * DINNER + d) * DSTATE;
#pragma unroll
        for (int j = 0; j < 4; ++j) {
            const float4 hv = *(const float4*)(hinit + base + j * 4);
            h[4 * j + 0] = hv.x; h[4 * j + 1] = hv.y;
            h[4 * j + 2] = hv.z; h[4 * j + 3] = hv.w;
        }
    }

    for (int i = tid; i < TC * 32; i += 256) {
        const int tt = i >> 5, q = i & 31;
        sBC[tt][q] = x_dbl[(size_t)(t0 + tt) * NXDBL + DTRANK + q];
    }
    __syncthreads();

    float xw0 = (t0 >= 3) ? xz[(size_t)(t0 - 3) * (2 * DINNER) + d] : 0.f;
    float xw1 = (t0 >= 2) ? xz[(size_t)(t0 - 2) * (2 * DINNER) + d] : 0.f;
    float xw2 = (t0 >= 1) ? xz[(size_t)(t0 - 1) * (2 * DINNER) + d] : 0.f;

    for (int tt = 0; tt < TC; ++tt) {
        const int t = t0 + tt;
        const float xc = xz[(size_t)t * (2 * DINNER) + d];
        const float z  = xz[(size_t)t * (2 * DINNER) + DINNER + d];
        float a = cb;
        a = fmaf(xw0, cw.x, a);
        a = fmaf(xw1, cw.y, a);
        a = fmaf(xw2, cw.z, a);
        a = fmaf(xc, cw.w, a);
        const float uu = a / (1.f + __expf(-a));
        xw0 = xw1; xw1 = xw2; xw2 = xc;

        const float dt = delta[(size_t)t * DINNER + d];
        const float du = dt * uu;
        float4 b[4], c[4];
#pragma unroll
        for (int j = 0; j < 4; ++j) {
            b[j] = *(const float4*)&sBC[tt][j * 4];
            c[j] = *(const float4*)&sBC[tt][16 + j * 4];
        }
        const float* bp = (const float*)b;
        const float* cp = (const float*)c;
        float y = Dp * uu;
#pragma unroll
        for (int n = 0; n < 16; ++n) {
            const float av = exp2f(dt * A2[n]);
            h[n] = fmaf(av, h[n], du * bp[n]);
            y = fmaf(h[n], cp[n], y);
        }
        const float gate = z / (1.f + __expf(-z));
        const float gv = y * gate;
        const size_t idx = (size_t)t * DINNER + d;
        const H2 gs = splitf16(gv);
        gH[idx] = gs.h;
        gL[idx] = gs.l;
    }
}

// ---------------------------------------------------------------------------
extern "C" void kernel_launch(void* const* d_in, const int* in_sizes, int n_in,
                              void* d_out, int out_size, void* d_ws, size_t ws_size,
                              hipStream_t stream)
{
    const float* x      = (const float*)d_in[0];
    const float* W_in   = (const float*)d_in[1];
    const float* conv_w = (const float*)d_in[2];
    const float* conv_b = (const float*)d_in[3];
    const float* W_x    = (const float*)d_in[4];
    const float* W_dt   = (const float*)d_in[5];
    const float* b_dt   = (const float*)d_in[6];
    const float* A_log  = (const float*)d_in[7];
    const float* D_par  = (const float*)d_in[8];
    const float* W_out  = (const float*)d_in[9];
    float* out = (float*)d_out;

    float* ws    = (float*)d_ws;
    float* xz    = ws;                                    // 8M f32 (32 MB)
    float* part  = xz + (size_t)L_SEQ * 2 * DINNER;       // 16*2048*96 f32 (12.6 MB)
    float* x_dbl = part + (size_t)L_SEQ * DINNER;         // 2048*96 f32
    float* delta = x_dbl + (size_t)L_SEQ * NXDBL;         // 4M f32 (16 MB)
    float* aprod = delta + (size_t)L_SEQ * DINNER;        // 2M f32 (8 MB)
    float* hacc  = aprod + (size_t)CCH * DINNER * DSTATE; // 2M f32 (8 MB)
    _Float16* WinT  = (_Float16*)(hacc + (size_t)CCH * DINNER * DSTATE); // 8 MB
    _Float16* WoutT = WinT + (size_t)(2 * DINNER) * DMODEL;              // 4 MB
    _Float16* WxT   = WoutT + (size_t)DMODEL * DINNER;                   // 0.4 MB

    // Aliases (lifetimes verified):
    _Float16* xH = (_Float16*)delta;          // used prep->G1; delta written step 4
    _Float16* xL = xH + (size_t)L_SEQ * DMODEL;
    _Float16* gH = WinT;                      // WinT dead after G1
    _Float16* gL = (_Float16*)aprod;          // aprod dead after phase2
    float* part6 = xz;                        // xz dead after phase3; 32 MB = KS6 x 8 MB

    // 1) fused prep
    prep_all<<<dim3(8384), 256, 0, stream>>>(W_in, W_out, W_x, x, WinT, WoutT, WxT, xH, xL);
    // 2) xz = x @ W_in  (BM=64 tile -> 1024 blocks = 4/CU)
    gemm_pre<2><<<dim3(2 * DINNER / 128, L_SEQ / 64, 1), 256, 0, stream>>>(
        xH, xL, WinT, xz, L_SEQ, 2 * DINNER, DMODEL, DMODEL);
    // 3) part = conv+silu(xz) @ W_x (fused, split-K)
    gemm3_conv<<<dim3(KS3, L_SEQ / 64), 256, 0, stream>>>(xz, conv_w, conv_b, WxT, part);
    // 4) delta + B/C reduction (fused)
    delta_bc<<<dim3(L_SEQ / 16, 4), 256, 0, stream>>>(part, W_dt, b_dt, delta, x_dbl);
    // 5) parallel scan (conv inline)
    scan_phase1<<<dim3(DINNER / 256, CCH), 256, 0, stream>>>(xz, delta, x_dbl, A_log, conv_w, conv_b, aprod, hacc);
    scan_phase2<<<dim3(DINNER * DSTATE / 256), 256, 0, stream>>>(aprod, hacc);
    scan_phase3<<<dim3(DINNER / 256, CCH), 256, 0, stream>>>(xz, delta, x_dbl, A_log, conv_w, conv_b, D_par, hacc, gH, gL);
    // 6) out = g @ W_out, split-K x4 (1024 blocks = 4/CU) + reduce
    gemm_pre<2><<<dim3(DMODEL / 128, L_SEQ / 64, KS6), 256, 0, stream>>>(
        gH, gL, WoutT, part6, L_SEQ, DMODEL, DINNER, DINNER / KS6);
    reduce6<<<dim3(L_SEQ * DMODEL / 4 / 256), 256, 0, stream>>>(part6, out);
}